// Round 5
// baseline (13784.575 us; speedup 1.0000x reference)
//
#include <hip/hip_runtime.h>

// PartCodeTransformer forward on MI355X (gfx950).
// I/O is fp32 (per reference dtypes); internal compute bf16 MFMA + fp32 accum/residual.
// GEMM: m97-structure 128x128 tile, BK=32, global_load_lds(16B), mfma_f32_16x16x32_bf16.
// Attention: flash-style, 64 Q-rows/block, online softmax fp32.
// Big scratch (QKV / FF-mid, 32 MiB bf16) lives in d_out's h-region (64 MiB fp32).

typedef unsigned short u16;
typedef unsigned int u32;
typedef __attribute__((ext_vector_type(8))) short bf16x8;
typedef __attribute__((ext_vector_type(8))) unsigned short us8;
typedef __attribute__((ext_vector_type(4))) float f32x4;

__device__ __forceinline__ float bf2f(u16 s) {
  union { u32 u; float f; } c; c.u = ((u32)s) << 16; return c.f;
}
__device__ __forceinline__ u16 f2bf(float f) {
  union { float f; u32 u; } c; c.f = f;
  u32 u = c.u;
  return (u16)((u + 0x7fffu + ((u >> 16) & 1u)) >> 16);  // RNE
}
__device__ __forceinline__ float gelu_f(float v) {
  return 0.5f * v * (1.0f + erff(v * 0.7071067811865475f));
}
__device__ __forceinline__ void gl2lds16(const u16* g, u16* l) {
  __builtin_amdgcn_global_load_lds((const __attribute__((address_space(1))) void*)g,
                                   (__attribute__((address_space(3))) void*)l, 16, 0, 0);
}
__device__ __forceinline__ f32x4 mfma16(bf16x8 a, bf16x8 b, f32x4 c) {
  return __builtin_amdgcn_mfma_f32_16x16x32_bf16(a, b, c, 0, 0, 0);
}

// ---------------- A[M,K](lda) x Bt[N,K](ldb) GEMM, 128x128 tile, bf16 operands ----------------
// EPI: 0 f32=v ; 1 bf16=v ; 2 f32+=v ; 3 bf16=gelu(v) ; 4 bf16+=v
template <int EPI>
__global__ __launch_bounds__(256)
void gemm_bt(const u16* __restrict__ A, const u16* __restrict__ Bt,
             const float* __restrict__ bias, float* __restrict__ Cf,
             u16* __restrict__ Cb, int K, int lda, int ldb, int ldc)
{
  __shared__ __align__(16) u16 As[128 * 32];
  __shared__ __align__(16) u16 Bs[128 * 32];
  const int tid = threadIdx.x;
  const int lane = tid & 63, wid = tid >> 6;
  const int wm = wid >> 1, wn = wid & 1;
  const long m0 = (long)blockIdx.y * 128, n0 = (long)blockIdx.x * 128;

  const int c0 = tid, c1 = tid + 256;
  const u16* aS0 = A + (m0 + (c0 >> 2)) * (long)lda + (c0 & 3) * 8;
  const u16* aS1 = A + (m0 + (c1 >> 2)) * (long)lda + (c1 & 3) * 8;
  const u16* bS0 = Bt + (n0 + (c0 >> 2)) * (long)ldb + (c0 & 3) * 8;
  const u16* bS1 = Bt + (n0 + (c1 >> 2)) * (long)ldb + (c1 & 3) * 8;

  f32x4 acc[4][4] = {};
  const int aro = (wm * 64 + (lane & 15)) * 32 + (lane >> 4) * 8;
  const int bro = (wn * 64 + (lane & 15)) * 32 + (lane >> 4) * 8;

  for (int k0 = 0; k0 < K; k0 += 32) {
    gl2lds16(aS0 + k0, As + c0 * 8);
    gl2lds16(aS1 + k0, As + c1 * 8);
    gl2lds16(bS0 + k0, Bs + c0 * 8);
    gl2lds16(bS1 + k0, Bs + c1 * 8);
    __syncthreads();
    bf16x8 af[4], bfr[4];
#pragma unroll
    for (int i = 0; i < 4; ++i) af[i] = *(const bf16x8*)(As + aro + i * 16 * 32);
#pragma unroll
    for (int j = 0; j < 4; ++j) bfr[j] = *(const bf16x8*)(Bs + bro + j * 16 * 32);
#pragma unroll
    for (int i = 0; i < 4; ++i)
#pragma unroll
      for (int j = 0; j < 4; ++j)
        acc[i][j] = mfma16(af[i], bfr[j], acc[i][j]);
    __syncthreads();
  }
  const int rg = (lane >> 4) * 4, cl = lane & 15;
#pragma unroll
  for (int i = 0; i < 4; ++i) {
#pragma unroll
    for (int j = 0; j < 4; ++j) {
      const long row = m0 + wm * 64 + i * 16 + rg;
      const long col = n0 + wn * 64 + j * 16 + cl;
      const float bv = bias ? bias[col] : 0.0f;
#pragma unroll
      for (int r = 0; r < 4; ++r) {
        float v = acc[i][j][r] + bv;
        long idx = (row + r) * ldc + col;
        if (EPI == 0) Cf[idx] = v;
        else if (EPI == 1) Cb[idx] = f2bf(v);
        else if (EPI == 2) Cf[idx] += v;
        else if (EPI == 3) Cb[idx] = f2bf(gelu_f(v));
        else Cb[idx] = f2bf(bf2f(Cb[idx]) + v);
      }
    }
  }
}

// ---------------- flash attention on 8 batches: qkv[8*1024,1536] bf16 ----------------
__global__ __launch_bounds__(256)
void attn_k(const u16* __restrict__ qkv, u16* __restrict__ o)
{
  __shared__ __align__(16) u16 Qs[64 * 64];
  __shared__ __align__(16) u16 Ks[64 * 64];
  __shared__ __align__(16) u16 Vts[64 * 64];   // [ch][key]
  __shared__ __align__(16) u16 Ps[4][16 * 64]; // per wave [qrow16][key64]
  const int tid = threadIdx.x, lane = tid & 63, wid = tid >> 6;
  const int qt = blockIdx.x, hh = blockIdx.y, b = blockIdx.z;
  const long rowbase = (long)b * 1024;
  const int g = lane >> 4, cl = lane & 15;
  {
    int c = tid;
    gl2lds16(qkv + (rowbase + qt * 64 + (c >> 3)) * 1536 + hh * 192 + (c & 7) * 8, Qs + c * 8);
    c = tid + 256;
    gl2lds16(qkv + (rowbase + qt * 64 + (c >> 3)) * 1536 + hh * 192 + (c & 7) * 8, Qs + c * 8);
  }
  float mrow[4] = {-3.0e38f, -3.0e38f, -3.0e38f, -3.0e38f};
  float lrow[4] = {0.f, 0.f, 0.f, 0.f};
  f32x4 oacc[4] = {};
  for (int kt = 0; kt < 16; ++kt) {
    {
      int c = tid;
      gl2lds16(qkv + (rowbase + kt * 64 + (c >> 3)) * 1536 + hh * 192 + 64 + (c & 7) * 8, Ks + c * 8);
      int c2 = tid + 256;
      gl2lds16(qkv + (rowbase + kt * 64 + (c2 >> 3)) * 1536 + hh * 192 + 64 + (c2 & 7) * 8, Ks + c2 * 8);
#pragma unroll
      for (int cc = tid; cc < 512; cc += 256) {  // V transpose into LDS
        int key = cc >> 3, ch0 = (cc & 7) * 8;
        uint4 vv = *(const uint4*)(qkv + (rowbase + kt * 64 + key) * 1536 + hh * 192 + 128 + ch0);
        const u16* pv = (const u16*)&vv;
#pragma unroll
        for (int j = 0; j < 8; ++j) Vts[(ch0 + j) * 64 + key] = pv[j];
      }
    }
    __syncthreads();
    bf16x8 aq[2];
#pragma unroll
    for (int kb = 0; kb < 2; ++kb)
      aq[kb] = *(const bf16x8*)(Qs + (wid * 16 + cl) * 64 + kb * 32 + g * 8);
    f32x4 s[4] = {};
#pragma unroll
    for (int j = 0; j < 4; ++j)
#pragma unroll
      for (int kb = 0; kb < 2; ++kb) {
        bf16x8 bk = *(const bf16x8*)(Ks + (j * 16 + cl) * 64 + kb * 32 + g * 8);
        s[j] = mfma16(aq[kb], bk, s[j]);
      }
    float pv_[4][4], alpha[4];
#pragma unroll
    for (int r = 0; r < 4; ++r) {
      float mx = fmaxf(fmaxf(s[0][r], s[1][r]), fmaxf(s[2][r], s[3][r])) * 0.125f;
#pragma unroll
      for (int off = 1; off < 16; off <<= 1) mx = fmaxf(mx, __shfl_xor(mx, off, 64));
      float mnew = fmaxf(mrow[r], mx);
      alpha[r] = __expf(mrow[r] - mnew);
      mrow[r] = mnew;
      float ts = 0.f;
#pragma unroll
      for (int j = 0; j < 4; ++j) {
        float p = __expf(s[j][r] * 0.125f - mnew);
        pv_[j][r] = p; ts += p;
      }
#pragma unroll
      for (int off = 1; off < 16; off <<= 1) ts += __shfl_xor(ts, off, 64);
      lrow[r] = lrow[r] * alpha[r] + ts;
    }
#pragma unroll
    for (int cb = 0; cb < 4; ++cb) {
      f32x4 t = oacc[cb];
      t[0] *= alpha[0]; t[1] *= alpha[1]; t[2] *= alpha[2]; t[3] *= alpha[3];
      oacc[cb] = t;
    }
#pragma unroll
    for (int j = 0; j < 4; ++j)
#pragma unroll
      for (int r = 0; r < 4; ++r)
        Ps[wid][(g * 4 + r) * 64 + j * 16 + cl] = f2bf(pv_[j][r]);
    __syncthreads();
    bf16x8 pa[2];
#pragma unroll
    for (int kb = 0; kb < 2; ++kb)
      pa[kb] = *(const bf16x8*)(&Ps[wid][cl * 64 + kb * 32 + g * 8]);
#pragma unroll
    for (int kb = 0; kb < 2; ++kb)
#pragma unroll
      for (int cb = 0; cb < 4; ++cb) {
        bf16x8 vb = *(const bf16x8*)(Vts + (cb * 16 + cl) * 64 + kb * 32 + g * 8);
        oacc[cb] = mfma16(pa[kb], vb, oacc[cb]);
      }
    __syncthreads();
  }
#pragma unroll
  for (int cb = 0; cb < 4; ++cb)
#pragma unroll
    for (int r = 0; r < 4; ++r) {
      long row = rowbase + qt * 64 + wid * 16 + g * 4 + r;
      o[row * 512 + hh * 64 + cb * 16 + cl] = f2bf(oacc[cb][r] / lrow[r]);
    }
}

// ---------------- LayerNorm, one wave per 512-row. MODE 0: f32->f32, 1: f32->bf16, 2: bf16->bf16
template <int MODE>
__global__ __launch_bounds__(256)
void ln_k(const void* __restrict__ in_, const float* __restrict__ gg,
          const float* __restrict__ bb, void* __restrict__ out_)
{
  const long row = (long)blockIdx.x * 4 + (threadIdx.x >> 6);
  const int lane = threadIdx.x & 63;
  float x[8];
  if (MODE < 2) {
    const float* p = (const float*)in_ + row * 512 + lane * 8;
    *(float4*)(x) = *(const float4*)(p);
    *(float4*)(x + 4) = *(const float4*)(p + 4);
  } else {
    us8 v = *(const us8*)((const u16*)in_ + row * 512 + lane * 8);
#pragma unroll
    for (int j = 0; j < 8; ++j) x[j] = bf2f(v[j]);
  }
  float s = 0.f;
#pragma unroll
  for (int j = 0; j < 8; ++j) s += x[j];
#pragma unroll
  for (int off = 1; off < 64; off <<= 1) s += __shfl_xor(s, off, 64);
  const float mean = s * (1.0f / 512.0f);
  float vs = 0.f;
#pragma unroll
  for (int j = 0; j < 8; ++j) { float d = x[j] - mean; vs += d * d; }
#pragma unroll
  for (int off = 1; off < 64; off <<= 1) vs += __shfl_xor(vs, off, 64);
  const float rstd = rsqrtf(vs * (1.0f / 512.0f) + 1e-5f);
  if (MODE == 0) {
    float y[8];
#pragma unroll
    for (int j = 0; j < 8; ++j)
      y[j] = (x[j] - mean) * rstd * gg[lane * 8 + j] + bb[lane * 8 + j];
    float* q = (float*)out_ + row * 512 + lane * 8;
    *(float4*)(q) = *(const float4*)(y);
    *(float4*)(q + 4) = *(const float4*)(y + 4);
  } else {
    us8 ov;
#pragma unroll
    for (int j = 0; j < 8; ++j)
      ov[j] = f2bf((x[j] - mean) * rstd * gg[lane * 8 + j] + bb[lane * 8 + j]);
    *(us8*)((u16*)out_ + row * 512 + lane * 8) = ov;
  }
}

// ---------------- input embed: h = E[t] + sum_9 scalars*w_in rows + b_in (all fp32) ----------------
template <int RESB>
__global__ __launch_bounds__(256)
void embed_k(const float* __restrict__ x, const float* __restrict__ par,
             const float* __restrict__ E, const float* __restrict__ w_in,
             const float* __restrict__ b_in, void* __restrict__ h)
{
  const long bt = blockIdx.x;
  const int b = (int)(bt >> 10), t = (int)(bt & 1023);
  float xs[9];
#pragma unroll
  for (int c = 0; c < 3; ++c) xs[c] = x[((long)b * 3 + c) * 1024 + t];
#pragma unroll
  for (int c = 0; c < 6; ++c) xs[3 + c] = par[((long)b * 6 + c) * 1024 + t];
  for (int w = threadIdx.x; w < 512; w += 256) {
    float a = E[(long)t * 512 + w] + b_in[w];
#pragma unroll
    for (int c = 0; c < 9; ++c) a += xs[c] * w_in[c * 512 + w];
    if (RESB) ((u16*)h)[bt * 512 + w] = f2bf(a);
    else ((float*)h)[bt * 512 + w] = a;
  }
}

// ---------------- fp32 -> bf16 transpose [R,C] -> [C,R] ----------------
__global__ __launch_bounds__(256)
void tr_k(const float* __restrict__ in, u16* __restrict__ out, int R, int C)
{
  __shared__ u16 tile[32][33];
  const int r0 = blockIdx.y * 32, c0 = blockIdx.x * 32;
  const int tx = threadIdx.x & 31, ty = threadIdx.x >> 5;
  for (int rr = ty; rr < 32; rr += 8) tile[rr][tx] = f2bf(in[(long)(r0 + rr) * C + c0 + tx]);
  __syncthreads();
  for (int rr = ty; rr < 32; rr += 8) out[(long)(c0 + rr) * R + r0 + tx] = tile[tx][rr];
}

// ---------------- fp32 -> bf16 cast ----------------
__global__ __launch_bounds__(256)
void cast_k(const float* __restrict__ in, u16* __restrict__ out, long n)
{
  long i = ((long)blockIdx.x * 256 + threadIdx.x) * 4;
  if (i + 3 < n) {
    float4 v = *(const float4*)(in + i);
    out[i] = f2bf(v.x); out[i + 1] = f2bf(v.y); out[i + 2] = f2bf(v.z); out[i + 3] = f2bf(v.w);
  }
}

// ---------------- masked max-pool over t ----------------
template <int RESB>
__global__ __launch_bounds__(256)
void pool_k(const void* __restrict__ hm, const float* __restrict__ mask, float* __restrict__ pooled)
{
  const int b = blockIdx.y;
  const int w = blockIdx.x * 256 + threadIdx.x;
  float acc = -3.0e38f;
  for (int t = 0; t < 1024; ++t) {
    const long off = ((long)b * 1024 + t) * 512 + w;
    float hv = RESB ? bf2f(((const u16*)hm)[off]) : ((const float*)hm)[off];
    float mv = mask[b * 1024 + t];
    acc = fmaxf(acc, hv * mv + (1.0f - mv) * (-100000.0f));
  }
  pooled[b * 512 + w] = acc;
}

// ---------------- masked transpose to output h [B,512,T] fp32 ----------------
template <int RESB>
__global__ __launch_bounds__(256)
void tout_k(const void* __restrict__ hm, const float* __restrict__ mask, float* __restrict__ outh)
{
  __shared__ float tile[64][65];
  const int t0 = blockIdx.x * 64, w0 = blockIdx.y * 64, b = blockIdx.z;
  const int tx = threadIdx.x & 63, ty = threadIdx.x >> 6;
  for (int i = ty; i < 64; i += 4) {
    const long off = ((long)b * 1024 + t0 + i) * 512 + w0 + tx;
    tile[i][tx] = RESB ? bf2f(((const u16*)hm)[off]) : ((const float*)hm)[off];
  }
  __syncthreads();
  const float mv = mask[b * 1024 + t0 + tx];
  for (int i = ty; i < 64; i += 4)
    outh[((long)b * 512 + w0 + i) * 1024 + t0 + tx] = tile[tx][i] * mv;
}

// ---------------- tiny aggregator matmuls (fp32 weights) ----------------
__global__ __launch_bounds__(256)
void agg1_k(const float* __restrict__ pooled, const float* __restrict__ wf,
            const float* __restrict__ bf_, float* __restrict__ z1)
{
  const int b = blockIdx.y;
  const int n = blockIdx.x * 256 + threadIdx.x;
  float acc = 0.f;
  for (int k = 0; k < 512; ++k) acc += pooled[b * 512 + k] * wf[(long)k * 2048 + n];
  z1[(long)b * 2048 + n] = gelu_f(acc + bf_[n]);
}
__global__ __launch_bounds__(256)
void agg2_k(const float* __restrict__ z1, const float* __restrict__ wp,
            const float* __restrict__ bp, float* __restrict__ zo)
{
  const int b = blockIdx.y;
  const int n = blockIdx.x * 256 + threadIdx.x;
  float acc = 0.f;
  for (int k = 0; k < 2048; ++k) acc += z1[(long)b * 2048 + k] * wp[(long)k * 512 + n];
  zo[b * 512 + n] = acc + bp[n];
}

extern "C" void kernel_launch(void* const* d_in, const int* in_sizes, int n_in,
                              void* d_out, int out_size, void* d_ws, size_t ws_size,
                              hipStream_t stream)
{
  (void)in_sizes; (void)n_in; (void)out_size;
  const float* x        = (const float*)d_in[0];
  const float* params   = (const float*)d_in[1];
  const float* mask     = (const float*)d_in[2];
  const float* class_emb= (const float*)d_in[3];
  const float* w_in     = (const float*)d_in[4];
  const float* b_in     = (const float*)d_in[5];
  const float* ln_pre_g = (const float*)d_in[6];
  const float* ln_pre_b = (const float*)d_in[7];
  const float* qkv_w    = (const float*)d_in[8];
  const float* qkv_b    = (const float*)d_in[9];
  const float* attn_pw  = (const float*)d_in[10];
  const float* attn_pb  = (const float*)d_in[11];
  const float* ln1_g    = (const float*)d_in[12];
  const float* ln1_b    = (const float*)d_in[13];
  const float* fc_w     = (const float*)d_in[14];
  const float* fc_b     = (const float*)d_in[15];
  const float* fcp_w    = (const float*)d_in[16];
  const float* fcp_b    = (const float*)d_in[17];
  const float* ln2_g    = (const float*)d_in[18];
  const float* ln2_b    = (const float*)d_in[19];
  const float* ln_post_g= (const float*)d_in[20];
  const float* ln_post_b= (const float*)d_in[21];
  const float* w_out    = (const float*)d_in[22];
  const float* b_out    = (const float*)d_in[23];
  const float* agg_fc_w = (const float*)d_in[24];
  const float* agg_fc_b = (const float*)d_in[25];
  const float* agg_pw   = (const float*)d_in[26];
  const float* agg_pb   = (const float*)d_in[27];

  float* out_f = (float*)d_out;          // z: [0, 16384) ; h: [16384, 16384+16777216)
  float* out_h = out_f + 16384;
  // bf16 scratch (QKV / FF-mid): 8192*2048 u16 = 32 MiB, inside the 64 MiB fp32 h-region.
  u16* sc = (u16*)out_h;

  // Residual precision chosen by actual workspace size (deterministic per session).
  const int RESB = (ws_size >= (size_t)88 * 1024 * 1024) ? 0 : 1;

  char* ws = (char*)d_ws;
  void* h = (void*)ws;          ws += (size_t)32768 * 512 * (RESB ? 2 : 4);  // residual (64 or 32 MiB)
  u16* hnq = (u16*)ws;          ws += (size_t)8192 * 512 * 2;                // per-quarter LN/attn buf (8 MiB)
  float* E = (float*)ws;        ws += (size_t)1024 * 512 * 4;                // class-emb proj (2 MiB)
  u16* ce_b = (u16*)ws;         ws += (size_t)1024 * 1024 * 2;               // class_emb bf16 (2 MiB)
  u16* wt_qkv = (u16*)ws;       ws += (size_t)1536 * 512 * 2;
  u16* wt_pw  = (u16*)ws;       ws += (size_t)512 * 512 * 2;
  u16* wt_fc  = (u16*)ws;       ws += (size_t)2048 * 512 * 2;
  u16* wt_fcp = (u16*)ws;       ws += (size_t)512 * 2048 * 2;
  u16* w_in_t = (u16*)ws;       ws += (size_t)512 * 1024 * 2;
  u16* w_out_t= (u16*)ws;       ws += (size_t)512 * 512 * 2;
  float* pooled = (float*)ws;   ws += (size_t)32 * 512 * 4;
  float* z1     = (float*)ws;   ws += (size_t)32 * 2048 * 4;

  float* hf = (float*)h;
  u16*   hb = (u16*)h;

  // one-time converts + class-emb projection + embed + ln_pre
  cast_k<<<1024, 256, 0, stream>>>(class_emb, ce_b, 1024 * 1024);
  tr_k<<<dim3(16, 32), 256, 0, stream>>>(w_in + 9 * 512, w_in_t, 1024, 512);
  tr_k<<<dim3(16, 16), 256, 0, stream>>>(w_out, w_out_t, 512, 512);
  gemm_bt<0><<<dim3(4, 8), 256, 0, stream>>>(ce_b, w_in_t, nullptr, E, nullptr,
                                             1024, 1024, 1024, 512);
  if (RESB) {
    embed_k<1><<<32768, 256, 0, stream>>>(x, params, E, w_in, b_in, h);
    ln_k<2><<<8192, 256, 0, stream>>>(h, ln_pre_g, ln_pre_b, h);
  } else {
    embed_k<0><<<32768, 256, 0, stream>>>(x, params, E, w_in, b_in, h);
    ln_k<0><<<8192, 256, 0, stream>>>(h, ln_pre_g, ln_pre_b, h);
  }

  for (int l = 0; l < 12; ++l) {
    tr_k<<<dim3(48, 16), 256, 0, stream>>>(qkv_w + (size_t)l * 512 * 1536, wt_qkv, 512, 1536);
    tr_k<<<dim3(16, 16), 256, 0, stream>>>(attn_pw + (size_t)l * 512 * 512, wt_pw, 512, 512);
    tr_k<<<dim3(64, 16), 256, 0, stream>>>(fc_w + (size_t)l * 512 * 2048, wt_fc, 512, 2048);
    tr_k<<<dim3(16, 64), 256, 0, stream>>>(fcp_w + (size_t)l * 2048 * 512, wt_fcp, 2048, 512);

    for (int q = 0; q < 4; ++q) {
      const size_t ro = (size_t)q * 8192;
      if (RESB) ln_k<2><<<2048, 256, 0, stream>>>(hb + ro * 512, ln1_g + l * 512, ln1_b + l * 512, hnq);
      else      ln_k<1><<<2048, 256, 0, stream>>>(hf + ro * 512, ln1_g + l * 512, ln1_b + l * 512, hnq);
      gemm_bt<1><<<dim3(12, 64), 256, 0, stream>>>(hnq, wt_qkv, qkv_b + l * 1536,
                                                   nullptr, sc, 512, 512, 512, 1536);
      attn_k<<<dim3(16, 8, 8), 256, 0, stream>>>(sc, hnq);
      if (RESB) gemm_bt<4><<<dim3(4, 64), 256, 0, stream>>>(hnq, wt_pw, attn_pb + l * 512,
                                                            nullptr, hb + ro * 512, 512, 512, 512, 512);
      else      gemm_bt<2><<<dim3(4, 64), 256, 0, stream>>>(hnq, wt_pw, attn_pb + l * 512,
                                                            hf + ro * 512, nullptr, 512, 512, 512, 512);
    }
    for (int q = 0; q < 4; ++q) {
      const size_t ro = (size_t)q * 8192;
      if (RESB) ln_k<2><<<2048, 256, 0, stream>>>(hb + ro * 512, ln2_g + l * 512, ln2_b + l * 512, hnq);
      else      ln_k<1><<<2048, 256, 0, stream>>>(hf + ro * 512, ln2_g + l * 512, ln2_b + l * 512, hnq);
      gemm_bt<3><<<dim3(16, 64), 256, 0, stream>>>(hnq, wt_fc, fc_b + l * 2048,
                                                   nullptr, sc, 512, 512, 512, 2048);
      if (RESB) gemm_bt<4><<<dim3(4, 64), 256, 0, stream>>>(sc, wt_fcp, fcp_b + l * 512,
                                                            nullptr, hb + ro * 512, 2048, 2048, 2048, 512);
      else      gemm_bt<2><<<dim3(4, 64), 256, 0, stream>>>(sc, wt_fcp, fcp_b + l * 512,
                                                            hf + ro * 512, nullptr, 2048, 2048, 2048, 512);
    }
  }

  // final LN + out-proj (residual becomes final h), then pool/agg, then h output
  for (int q = 0; q < 4; ++q) {
    const size_t ro = (size_t)q * 8192;
    if (RESB) {
      ln_k<2><<<2048, 256, 0, stream>>>(hb + ro * 512, ln_post_g, ln_post_b, hnq);
      gemm_bt<1><<<dim3(4, 64), 256, 0, stream>>>(hnq, w_out_t, b_out,
                                                  nullptr, hb + ro * 512, 512, 512, 512, 512);
    } else {
      ln_k<1><<<2048, 256, 0, stream>>>(hf + ro * 512, ln_post_g, ln_post_b, hnq);
      gemm_bt<0><<<dim3(4, 64), 256, 0, stream>>>(hnq, w_out_t, b_out,
                                                  hf + ro * 512, nullptr, 512, 512, 512, 512);
    }
  }
  if (RESB) {
    pool_k<1><<<dim3(2, 32), 256, 0, stream>>>(h, mask, pooled);
    agg1_k<<<dim3(8, 32), 256, 0, stream>>>(pooled, agg_fc_w, agg_fc_b, z1);
    agg2_k<<<dim3(2, 32), 256, 0, stream>>>(z1, agg_pw, agg_pb, out_f);
    tout_k<1><<<dim3(16, 8, 32), 256, 0, stream>>>(h, mask, out_h);
  } else {
    pool_k<0><<<dim3(2, 32), 256, 0, stream>>>(h, mask, pooled);
    agg1_k<<<dim3(8, 32), 256, 0, stream>>>(pooled, agg_fc_w, agg_fc_b, z1);
    agg2_k<<<dim3(2, 32), 256, 0, stream>>>(z1, agg_pw, agg_pb, out_f);
    tout_k<0><<<dim3(16, 8, 32), 256, 0, stream>>>(h, mask, out_h);
  }
}

// Round 6
// 11000.426 us; speedup vs baseline: 1.2531x; 1.2531x over previous
//
#include <hip/hip_runtime.h>

// PartCodeTransformer forward on MI355X (gfx950).
// I/O fp32; internal bf16 MFMA + fp32 accum/residual.
// GEMM: m97-structure 128x128 tile, BK=32, global_load_lds(16B), mfma_f32_16x16x32_bf16.
// Attention: flash-style, 64 Q-rows/block, online softmax fp32.
// Round 6: batch-halves/full-batch launch structure (occupancy + launch count), fp32 residual.

typedef unsigned short u16;
typedef unsigned int u32;
typedef __attribute__((ext_vector_type(8))) short bf16x8;
typedef __attribute__((ext_vector_type(8))) unsigned short us8;
typedef __attribute__((ext_vector_type(4))) float f32x4;

__device__ __forceinline__ float bf2f(u16 s) {
  union { u32 u; float f; } c; c.u = ((u32)s) << 16; return c.f;
}
__device__ __forceinline__ u16 f2bf(float f) {
  union { float f; u32 u; } c; c.f = f;
  u32 u = c.u;
  return (u16)((u + 0x7fffu + ((u >> 16) & 1u)) >> 16);  // RNE
}
__device__ __forceinline__ float gelu_f(float v) {
  return 0.5f * v * (1.0f + erff(v * 0.7071067811865475f));
}
__device__ __forceinline__ void gl2lds16(const u16* g, u16* l) {
  __builtin_amdgcn_global_load_lds((const __attribute__((address_space(1))) void*)g,
                                   (__attribute__((address_space(3))) void*)l, 16, 0, 0);
}
__device__ __forceinline__ f32x4 mfma16(bf16x8 a, bf16x8 b, f32x4 c) {
  return __builtin_amdgcn_mfma_f32_16x16x32_bf16(a, b, c, 0, 0, 0);
}

// ---------------- A[M,K](lda) x Bt[N,K](ldb) GEMM, 128x128 tile, bf16 operands ----------------
// EPI: 0 f32=v ; 1 bf16=v ; 2 f32+=v ; 3 bf16=gelu(v)
template <int EPI>
__global__ __launch_bounds__(256)
void gemm_bt(const u16* __restrict__ A, const u16* __restrict__ Bt,
             const float* __restrict__ bias, float* __restrict__ Cf,
             u16* __restrict__ Cb, int K, int lda, int ldb, int ldc)
{
  __shared__ __align__(16) u16 As[128 * 32];
  __shared__ __align__(16) u16 Bs[128 * 32];
  const int tid = threadIdx.x;
  const int lane = tid & 63, wid = tid >> 6;
  const int wm = wid >> 1, wn = wid & 1;
  const long m0 = (long)blockIdx.y * 128, n0 = (long)blockIdx.x * 128;

  const int c0 = tid, c1 = tid + 256;
  const u16* aS0 = A + (m0 + (c0 >> 2)) * (long)lda + (c0 & 3) * 8;
  const u16* aS1 = A + (m0 + (c1 >> 2)) * (long)lda + (c1 & 3) * 8;
  const u16* bS0 = Bt + (n0 + (c0 >> 2)) * (long)ldb + (c0 & 3) * 8;
  const u16* bS1 = Bt + (n0 + (c1 >> 2)) * (long)ldb + (c1 & 3) * 8;

  f32x4 acc[4][4] = {};
  const int aro = (wm * 64 + (lane & 15)) * 32 + (lane >> 4) * 8;
  const int bro = (wn * 64 + (lane & 15)) * 32 + (lane >> 4) * 8;

  for (int k0 = 0; k0 < K; k0 += 32) {
    gl2lds16(aS0 + k0, As + c0 * 8);
    gl2lds16(aS1 + k0, As + c1 * 8);
    gl2lds16(bS0 + k0, Bs + c0 * 8);
    gl2lds16(bS1 + k0, Bs + c1 * 8);
    __syncthreads();
    bf16x8 af[4], bfr[4];
#pragma unroll
    for (int i = 0; i < 4; ++i) af[i] = *(const bf16x8*)(As + aro + i * 16 * 32);
#pragma unroll
    for (int j = 0; j < 4; ++j) bfr[j] = *(const bf16x8*)(Bs + bro + j * 16 * 32);
#pragma unroll
    for (int i = 0; i < 4; ++i)
#pragma unroll
      for (int j = 0; j < 4; ++j)
        acc[i][j] = mfma16(af[i], bfr[j], acc[i][j]);
    __syncthreads();
  }
  const int rg = (lane >> 4) * 4, cl = lane & 15;
#pragma unroll
  for (int i = 0; i < 4; ++i) {
#pragma unroll
    for (int j = 0; j < 4; ++j) {
      const long row = m0 + wm * 64 + i * 16 + rg;
      const long col = n0 + wn * 64 + j * 16 + cl;
      const float bv = bias ? bias[col] : 0.0f;
#pragma unroll
      for (int r = 0; r < 4; ++r) {
        float v = acc[i][j][r] + bv;
        long idx = (row + r) * ldc + col;
        if (EPI == 0) Cf[idx] = v;
        else if (EPI == 1) Cb[idx] = f2bf(v);
        else if (EPI == 2) Cf[idx] += v;
        else Cb[idx] = f2bf(gelu_f(v));
      }
    }
  }
}

// ---------------- flash attention: qkv[NB*1024,1536] bf16, blockIdx.z = batch ----------------
__global__ __launch_bounds__(256)
void attn_k(const u16* __restrict__ qkv, u16* __restrict__ o)
{
  __shared__ __align__(16) u16 Qs[64 * 64];
  __shared__ __align__(16) u16 Ks[64 * 64];
  __shared__ __align__(16) u16 Vts[64 * 64];   // [ch][key]
  __shared__ __align__(16) u16 Ps[4][16 * 64]; // per wave [qrow16][key64]
  const int tid = threadIdx.x, lane = tid & 63, wid = tid >> 6;
  const int qt = blockIdx.x, hh = blockIdx.y, b = blockIdx.z;
  const long rowbase = (long)b * 1024;
  const int g = lane >> 4, cl = lane & 15;
  {
    int c = tid;
    gl2lds16(qkv + (rowbase + qt * 64 + (c >> 3)) * 1536 + hh * 192 + (c & 7) * 8, Qs + c * 8);
    c = tid + 256;
    gl2lds16(qkv + (rowbase + qt * 64 + (c >> 3)) * 1536 + hh * 192 + (c & 7) * 8, Qs + c * 8);
  }
  float mrow[4] = {-3.0e38f, -3.0e38f, -3.0e38f, -3.0e38f};
  float lrow[4] = {0.f, 0.f, 0.f, 0.f};
  f32x4 oacc[4] = {};
  for (int kt = 0; kt < 16; ++kt) {
    {
      int c = tid;
      gl2lds16(qkv + (rowbase + kt * 64 + (c >> 3)) * 1536 + hh * 192 + 64 + (c & 7) * 8, Ks + c * 8);
      int c2 = tid + 256;
      gl2lds16(qkv + (rowbase + kt * 64 + (c2 >> 3)) * 1536 + hh * 192 + 64 + (c2 & 7) * 8, Ks + c2 * 8);
#pragma unroll
      for (int cc = tid; cc < 512; cc += 256) {  // V transpose into LDS
        int key = cc >> 3, ch0 = (cc & 7) * 8;
        uint4 vv = *(const uint4*)(qkv + (rowbase + kt * 64 + key) * 1536 + hh * 192 + 128 + ch0);
        const u16* pv = (const u16*)&vv;
#pragma unroll
        for (int j = 0; j < 8; ++j) Vts[(ch0 + j) * 64 + key] = pv[j];
      }
    }
    __syncthreads();
    bf16x8 aq[2];
#pragma unroll
    for (int kb = 0; kb < 2; ++kb)
      aq[kb] = *(const bf16x8*)(Qs + (wid * 16 + cl) * 64 + kb * 32 + g * 8);
    f32x4 s[4] = {};
#pragma unroll
    for (int j = 0; j < 4; ++j)
#pragma unroll
      for (int kb = 0; kb < 2; ++kb) {
        bf16x8 bk = *(const bf16x8*)(Ks + (j * 16 + cl) * 64 + kb * 32 + g * 8);
        s[j] = mfma16(aq[kb], bk, s[j]);
      }
    float pv_[4][4], alpha[4];
#pragma unroll
    for (int r = 0; r < 4; ++r) {
      float mx = fmaxf(fmaxf(s[0][r], s[1][r]), fmaxf(s[2][r], s[3][r])) * 0.125f;
#pragma unroll
      for (int off = 1; off < 16; off <<= 1) mx = fmaxf(mx, __shfl_xor(mx, off, 64));
      float mnew = fmaxf(mrow[r], mx);
      alpha[r] = __expf(mrow[r] - mnew);
      mrow[r] = mnew;
      float ts = 0.f;
#pragma unroll
      for (int j = 0; j < 4; ++j) {
        float p = __expf(s[j][r] * 0.125f - mnew);
        pv_[j][r] = p; ts += p;
      }
#pragma unroll
      for (int off = 1; off < 16; off <<= 1) ts += __shfl_xor(ts, off, 64);
      lrow[r] = lrow[r] * alpha[r] + ts;
    }
#pragma unroll
    for (int cb = 0; cb < 4; ++cb) {
      f32x4 t = oacc[cb];
      t[0] *= alpha[0]; t[1] *= alpha[1]; t[2] *= alpha[2]; t[3] *= alpha[3];
      oacc[cb] = t;
    }
#pragma unroll
    for (int j = 0; j < 4; ++j)
#pragma unroll
      for (int r = 0; r < 4; ++r)
        Ps[wid][(g * 4 + r) * 64 + j * 16 + cl] = f2bf(pv_[j][r]);
    __syncthreads();
    bf16x8 pa[2];
#pragma unroll
    for (int kb = 0; kb < 2; ++kb)
      pa[kb] = *(const bf16x8*)(&Ps[wid][cl * 64 + kb * 32 + g * 8]);
#pragma unroll
    for (int kb = 0; kb < 2; ++kb)
#pragma unroll
      for (int cb = 0; cb < 4; ++cb) {
        bf16x8 vb = *(const bf16x8*)(Vts + (cb * 16 + cl) * 64 + kb * 32 + g * 8);
        oacc[cb] = mfma16(pa[kb], vb, oacc[cb]);
      }
    __syncthreads();
  }
#pragma unroll
  for (int cb = 0; cb < 4; ++cb)
#pragma unroll
    for (int r = 0; r < 4; ++r) {
      long row = rowbase + qt * 64 + wid * 16 + g * 4 + r;
      o[row * 512 + hh * 64 + cb * 16 + cl] = f2bf(oacc[cb][r] / lrow[r]);
    }
}

// ---------------- LayerNorm, one wave per 512-row. MODE 0: f32->f32, 1: f32->bf16
template <int MODE>
__global__ __launch_bounds__(256)
void ln_k(const float* __restrict__ in_, const float* __restrict__ gg,
          const float* __restrict__ bb, void* __restrict__ out_)
{
  const long row = (long)blockIdx.x * 4 + (threadIdx.x >> 6);
  const int lane = threadIdx.x & 63;
  float x[8];
  const float* p = in_ + row * 512 + lane * 8;
  *(float4*)(x) = *(const float4*)(p);
  *(float4*)(x + 4) = *(const float4*)(p + 4);
  float s = 0.f;
#pragma unroll
  for (int j = 0; j < 8; ++j) s += x[j];
#pragma unroll
  for (int off = 1; off < 64; off <<= 1) s += __shfl_xor(s, off, 64);
  const float mean = s * (1.0f / 512.0f);
  float vs = 0.f;
#pragma unroll
  for (int j = 0; j < 8; ++j) { float d = x[j] - mean; vs += d * d; }
#pragma unroll
  for (int off = 1; off < 64; off <<= 1) vs += __shfl_xor(vs, off, 64);
  const float rstd = rsqrtf(vs * (1.0f / 512.0f) + 1e-5f);
  if (MODE == 0) {
    float y[8];
#pragma unroll
    for (int j = 0; j < 8; ++j)
      y[j] = (x[j] - mean) * rstd * gg[lane * 8 + j] + bb[lane * 8 + j];
    float* q = (float*)out_ + row * 512 + lane * 8;
    *(float4*)(q) = *(const float4*)(y);
    *(float4*)(q + 4) = *(const float4*)(y + 4);
  } else {
    us8 ov;
#pragma unroll
    for (int j = 0; j < 8; ++j)
      ov[j] = f2bf((x[j] - mean) * rstd * gg[lane * 8 + j] + bb[lane * 8 + j]);
    *(us8*)((u16*)out_ + row * 512 + lane * 8) = ov;
  }
}

// ---------------- input embed: h = E[t] + sum_9 scalars*w_in rows + b_in (fp32) ----------------
__global__ __launch_bounds__(256)
void embed_k(const float* __restrict__ x, const float* __restrict__ par,
             const float* __restrict__ E, const float* __restrict__ w_in,
             const float* __restrict__ b_in, float* __restrict__ h)
{
  const long bt = blockIdx.x;
  const int b = (int)(bt >> 10), t = (int)(bt & 1023);
  float xs[9];
#pragma unroll
  for (int c = 0; c < 3; ++c) xs[c] = x[((long)b * 3 + c) * 1024 + t];
#pragma unroll
  for (int c = 0; c < 6; ++c) xs[3 + c] = par[((long)b * 6 + c) * 1024 + t];
  for (int w = threadIdx.x; w < 512; w += 256) {
    float a = E[(long)t * 512 + w] + b_in[w];
#pragma unroll
    for (int c = 0; c < 9; ++c) a += xs[c] * w_in[c * 512 + w];
    h[bt * 512 + w] = a;
  }
}

// ---------------- fp32 -> bf16 transpose [R,C] -> [C,R] ----------------
__global__ __launch_bounds__(256)
void tr_k(const float* __restrict__ in, u16* __restrict__ out, int R, int C)
{
  __shared__ u16 tile[32][33];
  const int r0 = blockIdx.y * 32, c0 = blockIdx.x * 32;
  const int tx = threadIdx.x & 31, ty = threadIdx.x >> 5;
  for (int rr = ty; rr < 32; rr += 8) tile[rr][tx] = f2bf(in[(long)(r0 + rr) * C + c0 + tx]);
  __syncthreads();
  for (int rr = ty; rr < 32; rr += 8) out[(long)(c0 + rr) * R + r0 + tx] = tile[tx][rr];
}

// ---------------- fp32 -> bf16 cast ----------------
__global__ __launch_bounds__(256)
void cast_k(const float* __restrict__ in, u16* __restrict__ out, long n)
{
  long i = ((long)blockIdx.x * 256 + threadIdx.x) * 4;
  if (i + 3 < n) {
    float4 v = *(const float4*)(in + i);
    out[i] = f2bf(v.x); out[i + 1] = f2bf(v.y); out[i + 2] = f2bf(v.z); out[i + 3] = f2bf(v.w);
  }
}

// ---------------- masked max-pool over t ----------------
__global__ __launch_bounds__(256)
void pool_k(const float* __restrict__ hm, const float* __restrict__ mask, float* __restrict__ pooled)
{
  const int b = blockIdx.y;
  const int w = blockIdx.x * 256 + threadIdx.x;
  const float* p = hm + ((long)b * 1024) * 512 + w;
  float acc = -3.0e38f;
  for (int t = 0; t < 1024; ++t) {
    float mv = mask[b * 1024 + t];
    acc = fmaxf(acc, p[(long)t * 512] * mv + (1.0f - mv) * (-100000.0f));
  }
  pooled[b * 512 + w] = acc;
}

// ---------------- masked transpose to output h [B,512,T] fp32 ----------------
__global__ __launch_bounds__(256)
void tout_k(const float* __restrict__ hm, const float* __restrict__ mask, float* __restrict__ outh)
{
  __shared__ float tile[64][65];
  const int t0 = blockIdx.x * 64, w0 = blockIdx.y * 64, b = blockIdx.z;
  const int tx = threadIdx.x & 63, ty = threadIdx.x >> 6;
  for (int i = ty; i < 64; i += 4)
    tile[i][tx] = hm[((long)b * 1024 + t0 + i) * 512 + w0 + tx];
  __syncthreads();
  const float mv = mask[b * 1024 + t0 + tx];
  for (int i = ty; i < 64; i += 4)
    outh[((long)b * 512 + w0 + i) * 1024 + t0 + tx] = tile[tx][i] * mv;
}

// ---------------- tiny aggregator matmuls (fp32 weights) ----------------
__global__ __launch_bounds__(256)
void agg1_k(const float* __restrict__ pooled, const float* __restrict__ wf,
            const float* __restrict__ bf_, float* __restrict__ z1)
{
  const int b = blockIdx.y;
  const int n = blockIdx.x * 256 + threadIdx.x;
  float acc = 0.f;
  for (int k = 0; k < 512; ++k) acc += pooled[b * 512 + k] * wf[(long)k * 2048 + n];
  z1[(long)b * 2048 + n] = gelu_f(acc + bf_[n]);
}
__global__ __launch_bounds__(256)
void agg2_k(const float* __restrict__ z1, const float* __restrict__ wp,
            const float* __restrict__ bp, float* __restrict__ zo)
{
  const int b = blockIdx.y;
  const int n = blockIdx.x * 256 + threadIdx.x;
  float acc = 0.f;
  for (int k = 0; k < 2048; ++k) acc += z1[(long)b * 2048 + k] * wp[(long)k * 512 + n];
  zo[b * 512 + n] = acc + bp[n];
}

extern "C" void kernel_launch(void* const* d_in, const int* in_sizes, int n_in,
                              void* d_out, int out_size, void* d_ws, size_t ws_size,
                              hipStream_t stream)
{
  (void)in_sizes; (void)n_in; (void)out_size; (void)ws_size;
  const float* x        = (const float*)d_in[0];
  const float* params   = (const float*)d_in[1];
  const float* mask     = (const float*)d_in[2];
  const float* class_emb= (const float*)d_in[3];
  const float* w_in     = (const float*)d_in[4];
  const float* b_in     = (const float*)d_in[5];
  const float* ln_pre_g = (const float*)d_in[6];
  const float* ln_pre_b = (const float*)d_in[7];
  const float* qkv_w    = (const float*)d_in[8];
  const float* qkv_b    = (const float*)d_in[9];
  const float* attn_pw  = (const float*)d_in[10];
  const float* attn_pb  = (const float*)d_in[11];
  const float* ln1_g    = (const float*)d_in[12];
  const float* ln1_b    = (const float*)d_in[13];
  const float* fc_w     = (const float*)d_in[14];
  const float* fc_b     = (const float*)d_in[15];
  const float* fcp_w    = (const float*)d_in[16];
  const float* fcp_b    = (const float*)d_in[17];
  const float* ln2_g    = (const float*)d_in[18];
  const float* ln2_b    = (const float*)d_in[19];
  const float* ln_post_g= (const float*)d_in[20];
  const float* ln_post_b= (const float*)d_in[21];
  const float* w_out    = (const float*)d_in[22];
  const float* b_out    = (const float*)d_in[23];
  const float* agg_fc_w = (const float*)d_in[24];
  const float* agg_fc_b = (const float*)d_in[25];
  const float* agg_pw   = (const float*)d_in[26];
  const float* agg_pb   = (const float*)d_in[27];

  float* out_f = (float*)d_out;          // z: [0, 16384)
  float* out_h = out_f + 16384;          // h: 64 MiB fp32 region
  u16* sc = (u16*)out_h;                 // bf16 scratch: up to 16384x2048 (64 MiB)

  // ---- workspace layout (~108 MiB) ----
  char* ws = (char*)d_ws;
  float* hf = (float*)ws;       ws += (size_t)32768 * 512 * 4;   // residual fp32 (64 MiB)
  u16* hn = (u16*)ws;           ws += (size_t)32768 * 512 * 2;   // LN / attn-out bf16 (32 MiB)
  float* E = (float*)ws;        ws += (size_t)1024 * 512 * 4;    // class-emb proj (2 MiB)
  u16* ce_b = (u16*)ws;         ws += (size_t)1024 * 1024 * 2;   // class_emb bf16 (2 MiB)
  u16* wt_qkv = (u16*)ws;       ws += (size_t)1536 * 512 * 2;    // per-layer transposes (6.3 MiB)
  u16* wt_pw  = (u16*)ws;       ws += (size_t)512 * 512 * 2;
  u16* wt_fc  = (u16*)ws;       ws += (size_t)2048 * 512 * 2;
  u16* wt_fcp = (u16*)ws;       ws += (size_t)512 * 2048 * 2;
  u16* w_in_t = (u16*)ws;       ws += (size_t)512 * 1024 * 2;
  u16* w_out_t= (u16*)ws;       ws += (size_t)512 * 512 * 2;
  float* pooled = (float*)ws;   ws += (size_t)32 * 512 * 4;
  float* z1     = (float*)ws;   ws += (size_t)32 * 2048 * 4;

  // one-time converts + class-emb projection + embed + ln_pre
  cast_k<<<1024, 256, 0, stream>>>(class_emb, ce_b, 1024 * 1024);
  tr_k<<<dim3(16, 32), 256, 0, stream>>>(w_in + 9 * 512, w_in_t, 1024, 512);
  tr_k<<<dim3(16, 16), 256, 0, stream>>>(w_out, w_out_t, 512, 512);
  gemm_bt<0><<<dim3(4, 8), 256, 0, stream>>>(ce_b, w_in_t, nullptr, E, nullptr,
                                             1024, 1024, 1024, 512);
  embed_k<<<32768, 256, 0, stream>>>(x, params, E, w_in, b_in, hf);
  ln_k<0><<<8192, 256, 0, stream>>>(hf, ln_pre_g, ln_pre_b, hf);

  for (int l = 0; l < 12; ++l) {
    tr_k<<<dim3(48, 16), 256, 0, stream>>>(qkv_w + (size_t)l * 512 * 1536, wt_qkv, 512, 1536);
    tr_k<<<dim3(16, 16), 256, 0, stream>>>(attn_pw + (size_t)l * 512 * 512, wt_pw, 512, 512);
    tr_k<<<dim3(64, 16), 256, 0, stream>>>(fc_w + (size_t)l * 512 * 2048, wt_fc, 512, 2048);
    tr_k<<<dim3(16, 64), 256, 0, stream>>>(fcp_w + (size_t)l * 2048 * 512, wt_fcp, 2048, 512);

    // LN1 full batch -> hn (bf16)
    ln_k<1><<<8192, 256, 0, stream>>>(hf, ln1_g + l * 512, ln1_b + l * 512, hn);
    // QKV + attention per batch-half (M = 16384, 16 batches); attn-out overwrites hn half
    for (int half = 0; half < 2; ++half) {
      const size_t ro = (size_t)half * 16384;
      gemm_bt<1><<<dim3(12, 128), 256, 0, stream>>>(hn + ro * 512, wt_qkv, qkv_b + l * 1536,
                                                    nullptr, sc, 512, 512, 512, 1536);
      attn_k<<<dim3(16, 8, 16), 256, 0, stream>>>(sc, hn + ro * 512);
    }
    // attn projection full batch: h += hn @ pw^T + b
    gemm_bt<2><<<dim3(4, 256), 256, 0, stream>>>(hn, wt_pw, attn_pb + l * 512,
                                                 hf, nullptr, 512, 512, 512, 512);
    // LN2 full batch -> hn
    ln_k<1><<<8192, 256, 0, stream>>>(hf, ln2_g + l * 512, ln2_b + l * 512, hn);
    // FF per batch-half: mid [16384x2048] bf16 in sc (64 MiB)
    for (int half = 0; half < 2; ++half) {
      const size_t ro = (size_t)half * 16384;
      gemm_bt<3><<<dim3(16, 128), 256, 0, stream>>>(hn + ro * 512, wt_fc, fc_b + l * 2048,
                                                    nullptr, sc, 512, 512, 512, 2048);
      gemm_bt<2><<<dim3(4, 128), 256, 0, stream>>>(sc, wt_fcp, fcp_b + l * 512,
                                                   hf + ro * 512, nullptr, 2048, 2048, 2048, 512);
    }
  }

  // final LN + out-proj (residual becomes final h), then pool/agg, then h output
  ln_k<1><<<8192, 256, 0, stream>>>(hf, ln_post_g, ln_post_b, hn);
  gemm_bt<0><<<dim3(4, 256), 256, 0, stream>>>(hn, w_out_t, b_out, hf, nullptr,
                                               512, 512, 512, 512);
  pool_k<<<dim3(2, 32), 256, 0, stream>>>(hf, mask, pooled);
  agg1_k<<<dim3(8, 32), 256, 0, stream>>>(pooled, agg_fc_w, agg_fc_b, z1);
  agg2_k<<<dim3(2, 32), 256, 0, stream>>>(z1, agg_pw, agg_pb, out_f);
  tout_k<<<dim3(16, 8, 32), 256, 0, stream>>>(hf, mask, out_h);
}

// Round 7
// 9549.754 us; speedup vs baseline: 1.4434x; 1.1519x over previous
//
#include <hip/hip_runtime.h>

// PartCodeTransformer forward on MI355X (gfx950).
// I/O fp32; internal bf16 MFMA + fp32 accum/residual.
// GEMM: m97-structure 128x128 tile, BK=32, global_load_lds(16B), mfma_f32_16x16x32_bf16.
// Attention: flash-style, 64 Q-rows/block, online softmax fp32.
// Round 7: XOR-swizzled attention LDS (T2): f(row)=(row&7)^(row>>3) permutes 16B chunks
// within each 128B row. Q/K via pre-swizzled global source (global_load_lds dest linear);
// V/P swizzled on both write and read. Kills the 6.5e7/dispatch bank conflicts.

typedef unsigned short u16;
typedef unsigned int u32;
typedef __attribute__((ext_vector_type(8))) short bf16x8;
typedef __attribute__((ext_vector_type(8))) unsigned short us8;
typedef __attribute__((ext_vector_type(4))) float f32x4;

__device__ __forceinline__ float bf2f(u16 s) {
  union { u32 u; float f; } c; c.u = ((u32)s) << 16; return c.f;
}
__device__ __forceinline__ u16 f2bf(float f) {
  union { float f; u32 u; } c; c.f = f;
  u32 u = c.u;
  return (u16)((u + 0x7fffu + ((u >> 16) & 1u)) >> 16);  // RNE
}
__device__ __forceinline__ float gelu_f(float v) {
  return 0.5f * v * (1.0f + erff(v * 0.7071067811865475f));
}
__device__ __forceinline__ void gl2lds16(const u16* g, u16* l) {
  __builtin_amdgcn_global_load_lds((const __attribute__((address_space(1))) void*)g,
                                   (__attribute__((address_space(3))) void*)l, 16, 0, 0);
}
__device__ __forceinline__ f32x4 mfma16(bf16x8 a, bf16x8 b, f32x4 c) {
  return __builtin_amdgcn_mfma_f32_16x16x32_bf16(a, b, c, 0, 0, 0);
}
// chunk swizzle for 64-u16 (128B) rows: permute 16B chunks within the row
__device__ __forceinline__ int swz(int row) { return (row & 7) ^ (row >> 3); }

// ---------------- A[M,K](lda) x Bt[N,K](ldb) GEMM, 128x128 tile, bf16 operands ----------------
// EPI: 0 f32=v ; 1 bf16=v ; 2 f32+=v ; 3 bf16=gelu(v)
template <int EPI>
__global__ __launch_bounds__(256)
void gemm_bt(const u16* __restrict__ A, const u16* __restrict__ Bt,
             const float* __restrict__ bias, float* __restrict__ Cf,
             u16* __restrict__ Cb, int K, int lda, int ldb, int ldc)
{
  __shared__ __align__(16) u16 As[128 * 32];
  __shared__ __align__(16) u16 Bs[128 * 32];
  const int tid = threadIdx.x;
  const int lane = tid & 63, wid = tid >> 6;
  const int wm = wid >> 1, wn = wid & 1;
  const long m0 = (long)blockIdx.y * 128, n0 = (long)blockIdx.x * 128;

  const int c0 = tid, c1 = tid + 256;
  const u16* aS0 = A + (m0 + (c0 >> 2)) * (long)lda + (c0 & 3) * 8;
  const u16* aS1 = A + (m0 + (c1 >> 2)) * (long)lda + (c1 & 3) * 8;
  const u16* bS0 = Bt + (n0 + (c0 >> 2)) * (long)ldb + (c0 & 3) * 8;
  const u16* bS1 = Bt + (n0 + (c1 >> 2)) * (long)ldb + (c1 & 3) * 8;

  f32x4 acc[4][4] = {};
  const int aro = (wm * 64 + (lane & 15)) * 32 + (lane >> 4) * 8;
  const int bro = (wn * 64 + (lane & 15)) * 32 + (lane >> 4) * 8;

  for (int k0 = 0; k0 < K; k0 += 32) {
    gl2lds16(aS0 + k0, As + c0 * 8);
    gl2lds16(aS1 + k0, As + c1 * 8);
    gl2lds16(bS0 + k0, Bs + c0 * 8);
    gl2lds16(bS1 + k0, Bs + c1 * 8);
    __syncthreads();
    bf16x8 af[4], bfr[4];
#pragma unroll
    for (int i = 0; i < 4; ++i) af[i] = *(const bf16x8*)(As + aro + i * 16 * 32);
#pragma unroll
    for (int j = 0; j < 4; ++j) bfr[j] = *(const bf16x8*)(Bs + bro + j * 16 * 32);
#pragma unroll
    for (int i = 0; i < 4; ++i)
#pragma unroll
      for (int j = 0; j < 4; ++j)
        acc[i][j] = mfma16(af[i], bfr[j], acc[i][j]);
    __syncthreads();
  }
  const int rg = (lane >> 4) * 4, cl = lane & 15;
#pragma unroll
  for (int i = 0; i < 4; ++i) {
#pragma unroll
    for (int j = 0; j < 4; ++j) {
      const long row = m0 + wm * 64 + i * 16 + rg;
      const long col = n0 + wn * 64 + j * 16 + cl;
      const float bv = bias ? bias[col] : 0.0f;
#pragma unroll
      for (int r = 0; r < 4; ++r) {
        float v = acc[i][j][r] + bv;
        long idx = (row + r) * ldc + col;
        if (EPI == 0) Cf[idx] = v;
        else if (EPI == 1) Cb[idx] = f2bf(v);
        else if (EPI == 2) Cf[idx] += v;
        else Cb[idx] = f2bf(gelu_f(v));
      }
    }
  }
}

// ---------------- flash attention: qkv[NB*1024,1536] bf16, blockIdx.z = batch ----------------
__global__ __launch_bounds__(256)
void attn_k(const u16* __restrict__ qkv, u16* __restrict__ o)
{
  __shared__ __align__(16) u16 Qs[64 * 64];
  __shared__ __align__(16) u16 Ks[64 * 64];
  __shared__ __align__(16) u16 Vts[64 * 64];   // [ch][key], key-chunks swizzled by swz(ch)
  __shared__ __align__(16) u16 Ps[4][16 * 64]; // per wave [qrow16][key64], swizzled by swz(qrow)
  const int tid = threadIdx.x, lane = tid & 63, wid = tid >> 6;
  const int qt = blockIdx.x, hh = blockIdx.y, b = blockIdx.z;
  const long rowbase = (long)b * 1024;
  const int g = lane >> 4, cl = lane & 15;
  // Q stage: LDS linear, global source column pre-swizzled
#pragma unroll
  for (int it = 0; it < 2; ++it) {
    int c = tid + it * 256;
    int row = c >> 3, c8s = (c & 7) ^ swz(row);
    gl2lds16(qkv + (rowbase + qt * 64 + row) * 1536 + hh * 192 + c8s * 8, Qs + c * 8);
  }
  float mrow[4] = {-3.0e38f, -3.0e38f, -3.0e38f, -3.0e38f};
  float lrow[4] = {0.f, 0.f, 0.f, 0.f};
  f32x4 oacc[4] = {};
  const int Rq = wid * 16 + cl, sq = swz(Rq) << 3;   // Q read row / swizzle
  const int sp = swz(cl) << 3;                        // P read row = cl
  for (int kt = 0; kt < 16; ++kt) {
    {
#pragma unroll
      for (int it = 0; it < 2; ++it) {  // K stage, pre-swizzled source
        int c = tid + it * 256;
        int row = c >> 3, c8s = (c & 7) ^ swz(row);
        gl2lds16(qkv + (rowbase + kt * 64 + row) * 1536 + hh * 192 + 64 + c8s * 8, Ks + c * 8);
      }
#pragma unroll
      for (int cc = tid; cc < 512; cc += 256) {  // V transpose into LDS, swizzled write
        int key = cc >> 3, ch0 = (cc & 7) * 8;
        uint4 vv = *(const uint4*)(qkv + (rowbase + kt * 64 + key) * 1536 + hh * 192 + 128 + ch0);
        const u16* pv = (const u16*)&vv;
#pragma unroll
        for (int j = 0; j < 8; ++j) {
          int ch = ch0 + j;
          Vts[ch * 64 + (key ^ (swz(ch) << 3))] = pv[j];
        }
      }
    }
    __syncthreads();
    bf16x8 aq[2];
#pragma unroll
    for (int kb = 0; kb < 2; ++kb)
      aq[kb] = *(const bf16x8*)(Qs + Rq * 64 + ((kb * 32 + g * 8) ^ sq));
    f32x4 s[4] = {};
#pragma unroll
    for (int j = 0; j < 4; ++j) {
      const int Rk = j * 16 + cl, sk = swz(Rk) << 3;
#pragma unroll
      for (int kb = 0; kb < 2; ++kb) {
        bf16x8 bk = *(const bf16x8*)(Ks + Rk * 64 + ((kb * 32 + g * 8) ^ sk));
        s[j] = mfma16(aq[kb], bk, s[j]);
      }
    }
    float pv_[4][4], alpha[4];
#pragma unroll
    for (int r = 0; r < 4; ++r) {
      float mx = fmaxf(fmaxf(s[0][r], s[1][r]), fmaxf(s[2][r], s[3][r])) * 0.125f;
#pragma unroll
      for (int off = 1; off < 16; off <<= 1) mx = fmaxf(mx, __shfl_xor(mx, off, 64));
      float mnew = fmaxf(mrow[r], mx);
      alpha[r] = __expf(mrow[r] - mnew);
      mrow[r] = mnew;
      float ts = 0.f;
#pragma unroll
      for (int j = 0; j < 4; ++j) {
        float p = __expf(s[j][r] * 0.125f - mnew);
        pv_[j][r] = p; ts += p;
      }
#pragma unroll
      for (int off = 1; off < 16; off <<= 1) ts += __shfl_xor(ts, off, 64);
      lrow[r] = lrow[r] * alpha[r] + ts;
    }
#pragma unroll
    for (int cb = 0; cb < 4; ++cb) {
      f32x4 t = oacc[cb];
      t[0] *= alpha[0]; t[1] *= alpha[1]; t[2] *= alpha[2]; t[3] *= alpha[3];
      oacc[cb] = t;
    }
#pragma unroll
    for (int r = 0; r < 4; ++r) {
      const int pr = g * 4 + r, fp = swz(pr) << 3;
#pragma unroll
      for (int j = 0; j < 4; ++j)
        Ps[wid][pr * 64 + ((j * 16 + cl) ^ fp)] = f2bf(pv_[j][r]);
    }
    __syncthreads();  // order P/V stores vs fragment loads
    bf16x8 pa[2];
#pragma unroll
    for (int kb = 0; kb < 2; ++kb)
      pa[kb] = *(const bf16x8*)(&Ps[wid][cl * 64 + ((kb * 32 + g * 8) ^ sp)]);
#pragma unroll
    for (int kb = 0; kb < 2; ++kb)
#pragma unroll
      for (int cb = 0; cb < 4; ++cb) {
        const int ch = cb * 16 + cl;
        bf16x8 vb = *(const bf16x8*)(Vts + ch * 64 + ((kb * 32 + g * 8) ^ (swz(ch) << 3)));
        oacc[cb] = mfma16(pa[kb], vb, oacc[cb]);
      }
    __syncthreads();
  }
#pragma unroll
  for (int cb = 0; cb < 4; ++cb)
#pragma unroll
    for (int r = 0; r < 4; ++r) {
      long row = rowbase + qt * 64 + wid * 16 + g * 4 + r;
      o[row * 512 + hh * 64 + cb * 16 + cl] = f2bf(oacc[cb][r] / lrow[r]);
    }
}

// ---------------- LayerNorm, one wave per 512-row. MODE 0: f32->f32, 1: f32->bf16
template <int MODE>
__global__ __launch_bounds__(256)
void ln_k(const float* __restrict__ in_, const float* __restrict__ gg,
          const float* __restrict__ bb, void* __restrict__ out_)
{
  const long row = (long)blockIdx.x * 4 + (threadIdx.x >> 6);
  const int lane = threadIdx.x & 63;
  float x[8];
  const float* p = in_ + row * 512 + lane * 8;
  *(float4*)(x) = *(const float4*)(p);
  *(float4*)(x + 4) = *(const float4*)(p + 4);
  float s = 0.f;
#pragma unroll
  for (int j = 0; j < 8; ++j) s += x[j];
#pragma unroll
  for (int off = 1; off < 64; off <<= 1) s += __shfl_xor(s, off, 64);
  const float mean = s * (1.0f / 512.0f);
  float vs = 0.f;
#pragma unroll
  for (int j = 0; j < 8; ++j) { float d = x[j] - mean; vs += d * d; }
#pragma unroll
  for (int off = 1; off < 64; off <<= 1) vs += __shfl_xor(vs, off, 64);
  const float rstd = rsqrtf(vs * (1.0f / 512.0f) + 1e-5f);
  if (MODE == 0) {
    float y[8];
#pragma unroll
    for (int j = 0; j < 8; ++j)
      y[j] = (x[j] - mean) * rstd * gg[lane * 8 + j] + bb[lane * 8 + j];
    float* q = (float*)out_ + row * 512 + lane * 8;
    *(float4*)(q) = *(const float4*)(y);
    *(float4*)(q + 4) = *(const float4*)(y + 4);
  } else {
    us8 ov;
#pragma unroll
    for (int j = 0; j < 8; ++j)
      ov[j] = f2bf((x[j] - mean) * rstd * gg[lane * 8 + j] + bb[lane * 8 + j]);
    *(us8*)((u16*)out_ + row * 512 + lane * 8) = ov;
  }
}

// ---------------- input embed: h = E[t] + sum_9 scalars*w_in rows + b_in (fp32) ----------------
__global__ __launch_bounds__(256)
void embed_k(const float* __restrict__ x, const float* __restrict__ par,
             const float* __restrict__ E, const float* __restrict__ w_in,
             const float* __restrict__ b_in, float* __restrict__ h)
{
  const long bt = blockIdx.x;
  const int b = (int)(bt >> 10), t = (int)(bt & 1023);
  float xs[9];
#pragma unroll
  for (int c = 0; c < 3; ++c) xs[c] = x[((long)b * 3 + c) * 1024 + t];
#pragma unroll
  for (int c = 0; c < 6; ++c) xs[3 + c] = par[((long)b * 6 + c) * 1024 + t];
  for (int w = threadIdx.x; w < 512; w += 256) {
    float a = E[(long)t * 512 + w] + b_in[w];
#pragma unroll
    for (int c = 0; c < 9; ++c) a += xs[c] * w_in[c * 512 + w];
    h[bt * 512 + w] = a;
  }
}

// ---------------- fp32 -> bf16 transpose [R,C] -> [C,R] ----------------
__global__ __launch_bounds__(256)
void tr_k(const float* __restrict__ in, u16* __restrict__ out, int R, int C)
{
  __shared__ u16 tile[32][33];
  const int r0 = blockIdx.y * 32, c0 = blockIdx.x * 32;
  const int tx = threadIdx.x & 31, ty = threadIdx.x >> 5;
  for (int rr = ty; rr < 32; rr += 8) tile[rr][tx] = f2bf(in[(long)(r0 + rr) * C + c0 + tx]);
  __syncthreads();
  for (int rr = ty; rr < 32; rr += 8) out[(long)(c0 + rr) * R + r0 + tx] = tile[tx][rr];
}

// ---------------- fp32 -> bf16 cast ----------------
__global__ __launch_bounds__(256)
void cast_k(const float* __restrict__ in, u16* __restrict__ out, long n)
{
  long i = ((long)blockIdx.x * 256 + threadIdx.x) * 4;
  if (i + 3 < n) {
    float4 v = *(const float4*)(in + i);
    out[i] = f2bf(v.x); out[i + 1] = f2bf(v.y); out[i + 2] = f2bf(v.z); out[i + 3] = f2bf(v.w);
  }
}

// ---------------- masked max-pool over t ----------------
__global__ __launch_bounds__(256)
void pool_k(const float* __restrict__ hm, const float* __restrict__ mask, float* __restrict__ pooled)
{
  const int b = blockIdx.y;
  const int w = blockIdx.x * 256 + threadIdx.x;
  const float* p = hm + ((long)b * 1024) * 512 + w;
  float acc = -3.0e38f;
  for (int t = 0; t < 1024; ++t) {
    float mv = mask[b * 1024 + t];
    acc = fmaxf(acc, p[(long)t * 512] * mv + (1.0f - mv) * (-100000.0f));
  }
  pooled[b * 512 + w] = acc;
}

// ---------------- masked transpose to output h [B,512,T] fp32 ----------------
__global__ __launch_bounds__(256)
void tout_k(const float* __restrict__ hm, const float* __restrict__ mask, float* __restrict__ outh)
{
  __shared__ float tile[64][65];
  const int t0 = blockIdx.x * 64, w0 = blockIdx.y * 64, b = blockIdx.z;
  const int tx = threadIdx.x & 63, ty = threadIdx.x >> 6;
  for (int i = ty; i < 64; i += 4)
    tile[i][tx] = hm[((long)b * 1024 + t0 + i) * 512 + w0 + tx];
  __syncthreads();
  const float mv = mask[b * 1024 + t0 + tx];
  for (int i = ty; i < 64; i += 4)
    outh[((long)b * 512 + w0 + i) * 1024 + t0 + tx] = tile[tx][i] * mv;
}

// ---------------- tiny aggregator matmuls (fp32 weights) ----------------
__global__ __launch_bounds__(256)
void agg1_k(const float* __restrict__ pooled, const float* __restrict__ wf,
            const float* __restrict__ bf_, float* __restrict__ z1)
{
  const int b = blockIdx.y;
  const int n = blockIdx.x * 256 + threadIdx.x;
  float acc = 0.f;
  for (int k = 0; k < 512; ++k) acc += pooled[b * 512 + k] * wf[(long)k * 2048 + n];
  z1[(long)b * 2048 + n] = gelu_f(acc + bf_[n]);
}
__global__ __launch_bounds__(256)
void agg2_k(const float* __restrict__ z1, const float* __restrict__ wp,
            const float* __restrict__ bp, float* __restrict__ zo)
{
  const int b = blockIdx.y;
  const int n = blockIdx.x * 256 + threadIdx.x;
  float acc = 0.f;
  for (int k = 0; k < 2048; ++k) acc += z1[(long)b * 2048 + k] * wp[(long)k * 512 + n];
  zo[b * 512 + n] = acc + bp[n];
}

extern "C" void kernel_launch(void* const* d_in, const int* in_sizes, int n_in,
                              void* d_out, int out_size, void* d_ws, size_t ws_size,
                              hipStream_t stream)
{
  (void)in_sizes; (void)n_in; (void)out_size; (void)ws_size;
  const float* x        = (const float*)d_in[0];
  const float* params   = (const float*)d_in[1];
  const float* mask     = (const float*)d_in[2];
  const float* class_emb= (const float*)d_in[3];
  const float* w_in     = (const float*)d_in[4];
  const float* b_in     = (const float*)d_in[5];
  const float* ln_pre_g = (const float*)d_in[6];
  const float* ln_pre_b = (const float*)d_in[7];
  const float* qkv_w    = (const float*)d_in[8];
  const float* qkv_b    = (const float*)d_in[9];
  const float* attn_pw  = (const float*)d_in[10];
  const float* attn_pb  = (const float*)d_in[11];
  const float* ln1_g    = (const float*)d_in[12];
  const float* ln1_b    = (const float*)d_in[13];
  const float* fc_w     = (const float*)d_in[14];
  const float* fc_b     = (const float*)d_in[15];
  const float* fcp_w    = (const float*)d_in[16];
  const float* fcp_b    = (const float*)d_in[17];
  const float* ln2_g    = (const float*)d_in[18];
  const float* ln2_b    = (const float*)d_in[19];
  const float* ln_post_g= (const float*)d_in[20];
  const float* ln_post_b= (const float*)d_in[21];
  const float* w_out    = (const float*)d_in[22];
  const float* b_out    = (const float*)d_in[23];
  const float* agg_fc_w = (const float*)d_in[24];
  const float* agg_fc_b = (const float*)d_in[25];
  const float* agg_pw   = (const float*)d_in[26];
  const float* agg_pb   = (const float*)d_in[27];

  float* out_f = (float*)d_out;          // z: [0, 16384)
  float* out_h = out_f + 16384;          // h: 64 MiB fp32 region
  u16* sc = (u16*)out_h;                 // bf16 scratch: up to 16384x2048 (64 MiB)

  // ---- workspace layout (~108 MiB) ----
  char* ws = (char*)d_ws;
  float* hf = (float*)ws;       ws += (size_t)32768 * 512 * 4;   // residual fp32 (64 MiB)
  u16* hn = (u16*)ws;           ws += (size_t)32768 * 512 * 2;   // LN / attn-out bf16 (32 MiB)
  float* E = (float*)ws;        ws += (size_t)1024 * 512 * 4;    // class-emb proj (2 MiB)
  u16* ce_b = (u16*)ws;         ws += (size_t)1024 * 1024 * 2;   // class_emb bf16 (2 MiB)
  u16* wt_qkv = (u16*)ws;       ws += (size_t)1536 * 512 * 2;    // per-layer transposes (6.3 MiB)
  u16* wt_pw  = (u16*)ws;       ws += (size_t)512 * 512 * 2;
  u16* wt_fc  = (u16*)ws;       ws += (size_t)2048 * 512 * 2;
  u16* wt_fcp = (u16*)ws;       ws += (size_t)512 * 2048 * 2;
  u16* w_in_t = (u16*)ws;       ws += (size_t)512 * 1024 * 2;
  u16* w_out_t= (u16*)ws;       ws += (size_t)512 * 512 * 2;
  float* pooled = (float*)ws;   ws += (size_t)32 * 512 * 4;
  float* z1     = (float*)ws;   ws += (size_t)32 * 2048 * 4;

  // one-time converts + class-emb projection + embed + ln_pre
  cast_k<<<1024, 256, 0, stream>>>(class_emb, ce_b, 1024 * 1024);
  tr_k<<<dim3(16, 32), 256, 0, stream>>>(w_in + 9 * 512, w_in_t, 1024, 512);
  tr_k<<<dim3(16, 16), 256, 0, stream>>>(w_out, w_out_t, 512, 512);
  gemm_bt<0><<<dim3(4, 8), 256, 0, stream>>>(ce_b, w_in_t, nullptr, E, nullptr,
                                             1024, 1024, 1024, 512);
  embed_k<<<32768, 256, 0, stream>>>(x, params, E, w_in, b_in, hf);
  ln_k<0><<<8192, 256, 0, stream>>>(hf, ln_pre_g, ln_pre_b, hf);

  for (int l = 0; l < 12; ++l) {
    tr_k<<<dim3(48, 16), 256, 0, stream>>>(qkv_w + (size_t)l * 512 * 1536, wt_qkv, 512, 1536);
    tr_k<<<dim3(16, 16), 256, 0, stream>>>(attn_pw + (size_t)l * 512 * 512, wt_pw, 512, 512);
    tr_k<<<dim3(64, 16), 256, 0, stream>>>(fc_w + (size_t)l * 512 * 2048, wt_fc, 512, 2048);
    tr_k<<<dim3(16, 64), 256, 0, stream>>>(fcp_w + (size_t)l * 2048 * 512, wt_fcp, 2048, 512);

    // LN1 full batch -> hn (bf16)
    ln_k<1><<<8192, 256, 0, stream>>>(hf, ln1_g + l * 512, ln1_b + l * 512, hn);
    // QKV + attention per batch-half (M = 16384, 16 batches); attn-out overwrites hn half
    for (int half = 0; half < 2; ++half) {
      const size_t ro = (size_t)half * 16384;
      gemm_bt<1><<<dim3(12, 128), 256, 0, stream>>>(hn + ro * 512, wt_qkv, qkv_b + l * 1536,
                                                    nullptr, sc, 512, 512, 512, 1536);
      attn_k<<<dim3(16, 8, 16), 256, 0, stream>>>(sc, hn + ro * 512);
    }
    // attn projection full batch: h += hn @ pw^T + b
    gemm_bt<2><<<dim3(4, 256), 256, 0, stream>>>(hn, wt_pw, attn_pb + l * 512,
                                                 hf, nullptr, 512, 512, 512, 512);
    // LN2 full batch -> hn
    ln_k<1><<<8192, 256, 0, stream>>>(hf, ln2_g + l * 512, ln2_b + l * 512, hn);
    // FF per batch-half: mid [16384x2048] bf16 in sc (64 MiB)
    for (int half = 0; half < 2; ++half) {
      const size_t ro = (size_t)half * 16384;
      gemm_bt<3><<<dim3(16, 128), 256, 0, stream>>>(hn + ro * 512, wt_fc, fc_b + l * 2048,
                                                    nullptr, sc, 512, 512, 512, 2048);
      gemm_bt<2><<<dim3(4, 128), 256, 0, stream>>>(sc, wt_fcp, fcp_b + l * 512,
                                                   hf + ro * 512, nullptr, 2048, 2048, 2048, 512);
    }
  }

  // final LN + out-proj (residual becomes final h), then pool/agg, then h output
  ln_k<1><<<8192, 256, 0, stream>>>(hf, ln_post_g, ln_post_b, hn);
  gemm_bt<0><<<dim3(4, 256), 256, 0, stream>>>(hn, w_out_t, b_out, hf, nullptr,
                                               512, 512, 512, 512);
  pool_k<<<dim3(2, 32), 256, 0, stream>>>(hf, mask, pooled);
  agg1_k<<<dim3(8, 32), 256, 0, stream>>>(pooled, agg_fc_w, agg_fc_b, z1);
  agg2_k<<<dim3(2, 32), 256, 0, stream>>>(z1, agg_pw, agg_pb, out_f);
  tout_k<<<dim3(16, 8, 32), 256, 0, stream>>>(hf, mask, out_h);
}

// Round 8
// 9194.499 us; speedup vs baseline: 1.4992x; 1.0386x over previous
//
#include <hip/hip_runtime.h>

// PartCodeTransformer forward on MI355X (gfx950).
// I/O fp32; internal bf16 MFMA + fp32 accum/residual.
// GEMM: m97-structure 128x128 tile, BK=32, global_load_lds(16B), mfma_f32_16x16x32_bf16.
// Attention: flash-style, 64 Q-rows/block, online softmax fp32, XOR-swizzled LDS (T2).
// Round 8: V^T pre-transposed per half (vtr_k) -> attn stages V via global_load_lds
// (no in-kernel scalar transpose); pool_k split into coalesced two-stage reduction.

typedef unsigned short u16;
typedef unsigned int u32;
typedef __attribute__((ext_vector_type(8))) short bf16x8;
typedef __attribute__((ext_vector_type(8))) unsigned short us8;
typedef __attribute__((ext_vector_type(4))) float f32x4;

__device__ __forceinline__ float bf2f(u16 s) {
  union { u32 u; float f; } c; c.u = ((u32)s) << 16; return c.f;
}
__device__ __forceinline__ u16 f2bf(float f) {
  union { float f; u32 u; } c; c.f = f;
  u32 u = c.u;
  return (u16)((u + 0x7fffu + ((u >> 16) & 1u)) >> 16);  // RNE
}
__device__ __forceinline__ float gelu_f(float v) {
  return 0.5f * v * (1.0f + erff(v * 0.7071067811865475f));
}
__device__ __forceinline__ void gl2lds16(const u16* g, u16* l) {
  __builtin_amdgcn_global_load_lds((const __attribute__((address_space(1))) void*)g,
                                   (__attribute__((address_space(3))) void*)l, 16, 0, 0);
}
__device__ __forceinline__ f32x4 mfma16(bf16x8 a, bf16x8 b, f32x4 c) {
  return __builtin_amdgcn_mfma_f32_16x16x32_bf16(a, b, c, 0, 0, 0);
}
// chunk swizzle for 64-u16 (128B) rows: permute 16B chunks within the row
__device__ __forceinline__ int swz(int row) { return (row & 7) ^ (row >> 3); }

// ---------------- A[M,K](lda) x Bt[N,K](ldb) GEMM, 128x128 tile, bf16 operands ----------------
// EPI: 0 f32=v ; 1 bf16=v ; 2 f32+=v ; 3 bf16=gelu(v)
template <int EPI>
__global__ __launch_bounds__(256)
void gemm_bt(const u16* __restrict__ A, const u16* __restrict__ Bt,
             const float* __restrict__ bias, float* __restrict__ Cf,
             u16* __restrict__ Cb, int K, int lda, int ldb, int ldc)
{
  __shared__ __align__(16) u16 As[128 * 32];
  __shared__ __align__(16) u16 Bs[128 * 32];
  const int tid = threadIdx.x;
  const int lane = tid & 63, wid = tid >> 6;
  const int wm = wid >> 1, wn = wid & 1;
  const long m0 = (long)blockIdx.y * 128, n0 = (long)blockIdx.x * 128;

  const int c0 = tid, c1 = tid + 256;
  const u16* aS0 = A + (m0 + (c0 >> 2)) * (long)lda + (c0 & 3) * 8;
  const u16* aS1 = A + (m0 + (c1 >> 2)) * (long)lda + (c1 & 3) * 8;
  const u16* bS0 = Bt + (n0 + (c0 >> 2)) * (long)ldb + (c0 & 3) * 8;
  const u16* bS1 = Bt + (n0 + (c1 >> 2)) * (long)ldb + (c1 & 3) * 8;

  f32x4 acc[4][4] = {};
  const int aro = (wm * 64 + (lane & 15)) * 32 + (lane >> 4) * 8;
  const int bro = (wn * 64 + (lane & 15)) * 32 + (lane >> 4) * 8;

  for (int k0 = 0; k0 < K; k0 += 32) {
    gl2lds16(aS0 + k0, As + c0 * 8);
    gl2lds16(aS1 + k0, As + c1 * 8);
    gl2lds16(bS0 + k0, Bs + c0 * 8);
    gl2lds16(bS1 + k0, Bs + c1 * 8);
    __syncthreads();
    bf16x8 af[4], bfr[4];
#pragma unroll
    for (int i = 0; i < 4; ++i) af[i] = *(const bf16x8*)(As + aro + i * 16 * 32);
#pragma unroll
    for (int j = 0; j < 4; ++j) bfr[j] = *(const bf16x8*)(Bs + bro + j * 16 * 32);
#pragma unroll
    for (int i = 0; i < 4; ++i)
#pragma unroll
      for (int j = 0; j < 4; ++j)
        acc[i][j] = mfma16(af[i], bfr[j], acc[i][j]);
    __syncthreads();
  }
  const int rg = (lane >> 4) * 4, cl = lane & 15;
#pragma unroll
  for (int i = 0; i < 4; ++i) {
#pragma unroll
    for (int j = 0; j < 4; ++j) {
      const long row = m0 + wm * 64 + i * 16 + rg;
      const long col = n0 + wn * 64 + j * 16 + cl;
      const float bv = bias ? bias[col] : 0.0f;
#pragma unroll
      for (int r = 0; r < 4; ++r) {
        float v = acc[i][j][r] + bv;
        long idx = (row + r) * ldc + col;
        if (EPI == 0) Cf[idx] = v;
        else if (EPI == 1) Cb[idx] = f2bf(v);
        else if (EPI == 2) Cf[idx] += v;
        else Cb[idx] = f2bf(gelu_f(v));
      }
    }
  }
}

// ---------------- V^T builder: sc[b*1024+t][1536] V-slice -> vt[(b*8+h)*64+ch][1024] ----------------
__global__ __launch_bounds__(256)
void vtr_k(const u16* __restrict__ qkv, u16* __restrict__ vt)
{
  __shared__ u16 tile[64][66];
  const int kt = blockIdx.x, hh = blockIdx.y, b = blockIdx.z;
  const int t = threadIdx.x;
#pragma unroll
  for (int it = 0; it < 2; ++it) {
    int key = (t >> 3) + it * 32, ch0 = (t & 7) * 8;
    us8 v = *(const us8*)(qkv + ((long)b * 1024 + kt * 64 + key) * 1536 + hh * 192 + 128 + ch0);
#pragma unroll
    for (int j = 0; j < 8; ++j) tile[ch0 + j][key] = v[j];
  }
  __syncthreads();
#pragma unroll
  for (int it = 0; it < 2; ++it) {
    int ch = (t >> 3) + it * 32, key0 = (t & 7) * 8;
    us8 v;
#pragma unroll
    for (int j = 0; j < 8; ++j) v[j] = tile[ch][key0 + j];
    *(us8*)(vt + (((long)b * 8 + hh) * 64 + ch) * 1024 + kt * 64 + key0) = v;
  }
}

// ---------------- flash attention: qkv[NB*1024,1536], vt[(b*8+h)*64+ch][1024] ----------------
__global__ __launch_bounds__(256)
void attn_k(const u16* __restrict__ qkv, const u16* __restrict__ vt, u16* __restrict__ o)
{
  __shared__ __align__(16) u16 Qs[64 * 64];
  __shared__ __align__(16) u16 Ks[64 * 64];
  __shared__ __align__(16) u16 Vts[64 * 64];   // [ch][key], key-chunks swizzled by swz(ch)
  __shared__ __align__(16) u16 Ps[4][16 * 64]; // per wave [qrow16][key64], swizzled by swz(qrow)
  const int tid = threadIdx.x, lane = tid & 63, wid = tid >> 6;
  const int qt = blockIdx.x, hh = blockIdx.y, b = blockIdx.z;
  const long rowbase = (long)b * 1024;
  const long vbase = (((long)b * 8 + hh) * 64) * 1024;
  const int g = lane >> 4, cl = lane & 15;
  // Q stage: LDS linear, global source column pre-swizzled
#pragma unroll
  for (int it = 0; it < 2; ++it) {
    int c = tid + it * 256;
    int row = c >> 3, c8s = (c & 7) ^ swz(row);
    gl2lds16(qkv + (rowbase + qt * 64 + row) * 1536 + hh * 192 + c8s * 8, Qs + c * 8);
  }
  float mrow[4] = {-3.0e38f, -3.0e38f, -3.0e38f, -3.0e38f};
  float lrow[4] = {0.f, 0.f, 0.f, 0.f};
  f32x4 oacc[4] = {};
  const int Rq = wid * 16 + cl, sq = swz(Rq) << 3;   // Q read row / swizzle
  const int sp = swz(cl) << 3;                        // P read row = cl
  for (int kt = 0; kt < 16; ++kt) {
#pragma unroll
    for (int it = 0; it < 2; ++it) {  // K stage, pre-swizzled source
      int c = tid + it * 256;
      int row = c >> 3, c8s = (c & 7) ^ swz(row);
      gl2lds16(qkv + (rowbase + kt * 64 + row) * 1536 + hh * 192 + 64 + c8s * 8, Ks + c * 8);
    }
#pragma unroll
    for (int it = 0; it < 2; ++it) {  // V^T stage, pre-swizzled source
      int c = tid + it * 256;
      int ch = c >> 3, c8s = (c & 7) ^ swz(ch);
      gl2lds16(vt + vbase + (long)ch * 1024 + kt * 64 + c8s * 8, Vts + c * 8);
    }
    __syncthreads();
    bf16x8 aq[2];
#pragma unroll
    for (int kb = 0; kb < 2; ++kb)
      aq[kb] = *(const bf16x8*)(Qs + Rq * 64 + ((kb * 32 + g * 8) ^ sq));
    f32x4 s[4] = {};
#pragma unroll
    for (int j = 0; j < 4; ++j) {
      const int Rk = j * 16 + cl, sk = swz(Rk) << 3;
#pragma unroll
      for (int kb = 0; kb < 2; ++kb) {
        bf16x8 bk = *(const bf16x8*)(Ks + Rk * 64 + ((kb * 32 + g * 8) ^ sk));
        s[j] = mfma16(aq[kb], bk, s[j]);
      }
    }
    float pv_[4][4], alpha[4];
#pragma unroll
    for (int r = 0; r < 4; ++r) {
      float mx = fmaxf(fmaxf(s[0][r], s[1][r]), fmaxf(s[2][r], s[3][r])) * 0.125f;
#pragma unroll
      for (int off = 1; off < 16; off <<= 1) mx = fmaxf(mx, __shfl_xor(mx, off, 64));
      float mnew = fmaxf(mrow[r], mx);
      alpha[r] = __expf(mrow[r] - mnew);
      mrow[r] = mnew;
      float ts = 0.f;
#pragma unroll
      for (int j = 0; j < 4; ++j) {
        float p = __expf(s[j][r] * 0.125f - mnew);
        pv_[j][r] = p; ts += p;
      }
#pragma unroll
      for (int off = 1; off < 16; off <<= 1) ts += __shfl_xor(ts, off, 64);
      lrow[r] = lrow[r] * alpha[r] + ts;
    }
#pragma unroll
    for (int cb = 0; cb < 4; ++cb) {
      f32x4 t = oacc[cb];
      t[0] *= alpha[0]; t[1] *= alpha[1]; t[2] *= alpha[2]; t[3] *= alpha[3];
      oacc[cb] = t;
    }
#pragma unroll
    for (int r = 0; r < 4; ++r) {
      const int pr = g * 4 + r, fp = swz(pr) << 3;
#pragma unroll
      for (int j = 0; j < 4; ++j)
        Ps[wid][pr * 64 + ((j * 16 + cl) ^ fp)] = f2bf(pv_[j][r]);
    }
    __syncthreads();  // order P stores vs fragment loads
    bf16x8 pa[2];
#pragma unroll
    for (int kb = 0; kb < 2; ++kb)
      pa[kb] = *(const bf16x8*)(&Ps[wid][cl * 64 + ((kb * 32 + g * 8) ^ sp)]);
#pragma unroll
    for (int kb = 0; kb < 2; ++kb)
#pragma unroll
      for (int cb = 0; cb < 4; ++cb) {
        const int ch = cb * 16 + cl;
        bf16x8 vb = *(const bf16x8*)(Vts + ch * 64 + ((kb * 32 + g * 8) ^ (swz(ch) << 3)));
        oacc[cb] = mfma16(pa[kb], vb, oacc[cb]);
      }
    __syncthreads();
  }
#pragma unroll
  for (int cb = 0; cb < 4; ++cb)
#pragma unroll
    for (int r = 0; r < 4; ++r) {
      long row = rowbase + qt * 64 + wid * 16 + g * 4 + r;
      o[row * 512 + hh * 64 + cb * 16 + cl] = f2bf(oacc[cb][r] / lrow[r]);
    }
}

// ---------------- LayerNorm, one wave per 512-row. MODE 0: f32->f32, 1: f32->bf16
template <int MODE>
__global__ __launch_bounds__(256)
void ln_k(const float* __restrict__ in_, const float* __restrict__ gg,
          const float* __restrict__ bb, void* __restrict__ out_)
{
  const long row = (long)blockIdx.x * 4 + (threadIdx.x >> 6);
  const int lane = threadIdx.x & 63;
  float x[8];
  const float* p = in_ + row * 512 + lane * 8;
  *(float4*)(x) = *(const float4*)(p);
  *(float4*)(x + 4) = *(const float4*)(p + 4);
  float s = 0.f;
#pragma unroll
  for (int j = 0; j < 8; ++j) s += x[j];
#pragma unroll
  for (int off = 1; off < 64; off <<= 1) s += __shfl_xor(s, off, 64);
  const float mean = s * (1.0f / 512.0f);
  float vs = 0.f;
#pragma unroll
  for (int j = 0; j < 8; ++j) { float d = x[j] - mean; vs += d * d; }
#pragma unroll
  for (int off = 1; off < 64; off <<= 1) vs += __shfl_xor(vs, off, 64);
  const float rstd = rsqrtf(vs * (1.0f / 512.0f) + 1e-5f);
  if (MODE == 0) {
    float y[8];
#pragma unroll
    for (int j = 0; j < 8; ++j)
      y[j] = (x[j] - mean) * rstd * gg[lane * 8 + j] + bb[lane * 8 + j];
    float* q = (float*)out_ + row * 512 + lane * 8;
    *(float4*)(q) = *(const float4*)(y);
    *(float4*)(q + 4) = *(const float4*)(y + 4);
  } else {
    us8 ov;
#pragma unroll
    for (int j = 0; j < 8; ++j)
      ov[j] = f2bf((x[j] - mean) * rstd * gg[lane * 8 + j] + bb[lane * 8 + j]);
    *(us8*)((u16*)out_ + row * 512 + lane * 8) = ov;
  }
}

// ---------------- input embed: h = E[t] + sum_9 scalars*w_in rows + b_in (fp32) ----------------
__global__ __launch_bounds__(256)
void embed_k(const float* __restrict__ x, const float* __restrict__ par,
             const float* __restrict__ E, const float* __restrict__ w_in,
             const float* __restrict__ b_in, float* __restrict__ h)
{
  const long bt = blockIdx.x;
  const int b = (int)(bt >> 10), t = (int)(bt & 1023);
  float xs[9];
#pragma unroll
  for (int c = 0; c < 3; ++c) xs[c] = x[((long)b * 3 + c) * 1024 + t];
#pragma unroll
  for (int c = 0; c < 6; ++c) xs[3 + c] = par[((long)b * 6 + c) * 1024 + t];
  for (int w = threadIdx.x; w < 512; w += 256) {
    float a = E[(long)t * 512 + w] + b_in[w];
#pragma unroll
    for (int c = 0; c < 9; ++c) a += xs[c] * w_in[c * 512 + w];
    h[bt * 512 + w] = a;
  }
}

// ---------------- fp32 -> bf16 transpose [R,C] -> [C,R] ----------------
__global__ __launch_bounds__(256)
void tr_k(const float* __restrict__ in, u16* __restrict__ out, int R, int C)
{
  __shared__ u16 tile[32][33];
  const int r0 = blockIdx.y * 32, c0 = blockIdx.x * 32;
  const int tx = threadIdx.x & 31, ty = threadIdx.x >> 5;
  for (int rr = ty; rr < 32; rr += 8) tile[rr][tx] = f2bf(in[(long)(r0 + rr) * C + c0 + tx]);
  __syncthreads();
  for (int rr = ty; rr < 32; rr += 8) out[(long)(c0 + rr) * R + r0 + tx] = tile[tx][rr];
}

// ---------------- fp32 -> bf16 cast ----------------
__global__ __launch_bounds__(256)
void cast_k(const float* __restrict__ in, u16* __restrict__ out, long n)
{
  long i = ((long)blockIdx.x * 256 + threadIdx.x) * 4;
  if (i + 3 < n) {
    float4 v = *(const float4*)(in + i);
    out[i] = f2bf(v.x); out[i + 1] = f2bf(v.y); out[i + 2] = f2bf(v.z); out[i + 3] = f2bf(v.w);
  }
}

// ---------------- masked max-pool, stage 1: coalesced per-(b, t-chunk) partial max ----------------
__global__ __launch_bounds__(256)
void pool1_k(const float* __restrict__ hm, const float* __restrict__ mask, float* __restrict__ part)
{
  const int c = blockIdx.x, b = blockIdx.y;
  const int t0 = c * 128;
  const int w0 = threadIdx.x, w1 = threadIdx.x + 256;
  float m0 = -3.0e38f, m1 = -3.0e38f;
  for (int t = 0; t < 128; ++t) {
    const float mv = mask[b * 1024 + t0 + t];
    const float neg = (1.0f - mv) * (-100000.0f);
    const float* row = hm + ((long)b * 1024 + t0 + t) * 512;
    m0 = fmaxf(m0, row[w0] * mv + neg);
    m1 = fmaxf(m1, row[w1] * mv + neg);
  }
  part[((long)b * 8 + c) * 512 + w0] = m0;
  part[((long)b * 8 + c) * 512 + w1] = m1;
}
// ---------------- stage 2: combine 8 chunks ----------------
__global__ __launch_bounds__(256)
void pool2_k(const float* __restrict__ part, float* __restrict__ pooled)
{
  const int b = blockIdx.y;
  const int w = blockIdx.x * 256 + threadIdx.x;
  float m = -3.0e38f;
#pragma unroll
  for (int c = 0; c < 8; ++c) m = fmaxf(m, part[((long)b * 8 + c) * 512 + w]);
  pooled[b * 512 + w] = m;
}

// ---------------- masked transpose to output h [B,512,T] fp32 ----------------
__global__ __launch_bounds__(256)
void tout_k(const float* __restrict__ hm, const float* __restrict__ mask, float* __restrict__ outh)
{
  __shared__ float tile[64][65];
  const int t0 = blockIdx.x * 64, w0 = blockIdx.y * 64, b = blockIdx.z;
  const int tx = threadIdx.x & 63, ty = threadIdx.x >> 6;
  for (int i = ty; i < 64; i += 4)
    tile[i][tx] = hm[((long)b * 1024 + t0 + i) * 512 + w0 + tx];
  __syncthreads();
  const float mv = mask[b * 1024 + t0 + tx];
  for (int i = ty; i < 64; i += 4)
    outh[((long)b * 512 + w0 + i) * 1024 + t0 + tx] = tile[tx][i] * mv;
}

// ---------------- tiny aggregator matmuls (fp32 weights) ----------------
__global__ __launch_bounds__(256)
void agg1_k(const float* __restrict__ pooled, const float* __restrict__ wf,
            const float* __restrict__ bf_, float* __restrict__ z1)
{
  const int b = blockIdx.y;
  const int n = blockIdx.x * 256 + threadIdx.x;
  float acc = 0.f;
  for (int k = 0; k < 512; ++k) acc += pooled[b * 512 + k] * wf[(long)k * 2048 + n];
  z1[(long)b * 2048 + n] = gelu_f(acc + bf_[n]);
}
__global__ __launch_bounds__(256)
void agg2_k(const float* __restrict__ z1, const float* __restrict__ wp,
            const float* __restrict__ bp, float* __restrict__ zo)
{
  const int b = blockIdx.y;
  const int n = blockIdx.x * 256 + threadIdx.x;
  float acc = 0.f;
  for (int k = 0; k < 2048; ++k) acc += z1[(long)b * 2048 + k] * wp[(long)k * 512 + n];
  zo[b * 512 + n] = acc + bp[n];
}

extern "C" void kernel_launch(void* const* d_in, const int* in_sizes, int n_in,
                              void* d_out, int out_size, void* d_ws, size_t ws_size,
                              hipStream_t stream)
{
  (void)in_sizes; (void)n_in; (void)out_size; (void)ws_size;
  const float* x        = (const float*)d_in[0];
  const float* params   = (const float*)d_in[1];
  const float* mask     = (const float*)d_in[2];
  const float* class_emb= (const float*)d_in[3];
  const float* w_in     = (const float*)d_in[4];
  const float* b_in     = (const float*)d_in[5];
  const float* ln_pre_g = (const float*)d_in[6];
  const float* ln_pre_b = (const float*)d_in[7];
  const float* qkv_w    = (const float*)d_in[8];
  const float* qkv_b    = (const float*)d_in[9];
  const float* attn_pw  = (const float*)d_in[10];
  const float* attn_pb  = (const float*)d_in[11];
  const float* ln1_g    = (const float*)d_in[12];
  const float* ln1_b    = (const float*)d_in[13];
  const float* fc_w     = (const float*)d_in[14];
  const float* fc_b     = (const float*)d_in[15];
  const float* fcp_w    = (const float*)d_in[16];
  const float* fcp_b    = (const float*)d_in[17];
  const float* ln2_g    = (const float*)d_in[18];
  const float* ln2_b    = (const float*)d_in[19];
  const float* ln_post_g= (const float*)d_in[20];
  const float* ln_post_b= (const float*)d_in[21];
  const float* w_out    = (const float*)d_in[22];
  const float* b_out    = (const float*)d_in[23];
  const float* agg_fc_w = (const float*)d_in[24];
  const float* agg_fc_b = (const float*)d_in[25];
  const float* agg_pw   = (const float*)d_in[26];
  const float* agg_pb   = (const float*)d_in[27];

  float* out_f = (float*)d_out;          // z: [0, 16384)
  float* out_h = out_f + 16384;          // h: 64 MiB fp32 region
  u16* sc = (u16*)out_h;                 // bf16 scratch: up to 16384x2048 (64 MiB)

  // ---- workspace layout (~125 MiB) ----
  char* ws = (char*)d_ws;
  float* hf = (float*)ws;       ws += (size_t)32768 * 512 * 4;   // residual fp32 (64 MiB)
  u16* hn = (u16*)ws;           ws += (size_t)32768 * 512 * 2;   // LN / attn-out bf16 (32 MiB)
  float* E = (float*)ws;        ws += (size_t)1024 * 512 * 4;    // class-emb proj (2 MiB)
  u16* ce_b = (u16*)ws;         ws += (size_t)1024 * 1024 * 2;   // class_emb bf16 (2 MiB)
  u16* wt_qkv = (u16*)ws;       ws += (size_t)1536 * 512 * 2;    // per-layer transposes (6.3 MiB)
  u16* wt_pw  = (u16*)ws;       ws += (size_t)512 * 512 * 2;
  u16* wt_fc  = (u16*)ws;       ws += (size_t)2048 * 512 * 2;
  u16* wt_fcp = (u16*)ws;       ws += (size_t)512 * 2048 * 2;
  u16* w_in_t = (u16*)ws;       ws += (size_t)512 * 1024 * 2;
  u16* w_out_t= (u16*)ws;       ws += (size_t)512 * 512 * 2;
  float* pooled = (float*)ws;   ws += (size_t)32 * 512 * 4;
  float* z1     = (float*)ws;   ws += (size_t)32 * 2048 * 4;
  float* part   = (float*)ws;   ws += (size_t)32 * 8 * 512 * 4;  // pool partials (0.5 MiB)
  u16* vt       = (u16*)ws;     ws += (size_t)16 * 8 * 64 * 1024 * 2;  // V^T per half (16 MiB)

  // one-time converts + class-emb projection + embed + ln_pre
  cast_k<<<1024, 256, 0, stream>>>(class_emb, ce_b, 1024 * 1024);
  tr_k<<<dim3(16, 32), 256, 0, stream>>>(w_in + 9 * 512, w_in_t, 1024, 512);
  tr_k<<<dim3(16, 16), 256, 0, stream>>>(w_out, w_out_t, 512, 512);
  gemm_bt<0><<<dim3(4, 8), 256, 0, stream>>>(ce_b, w_in_t, nullptr, E, nullptr,
                                             1024, 1024, 1024, 512);
  embed_k<<<32768, 256, 0, stream>>>(x, params, E, w_in, b_in, hf);
  ln_k<0><<<8192, 256, 0, stream>>>(hf, ln_pre_g, ln_pre_b, hf);

  for (int l = 0; l < 12; ++l) {
    tr_k<<<dim3(48, 16), 256, 0, stream>>>(qkv_w + (size_t)l * 512 * 1536, wt_qkv, 512, 1536);
    tr_k<<<dim3(16, 16), 256, 0, stream>>>(attn_pw + (size_t)l * 512 * 512, wt_pw, 512, 512);
    tr_k<<<dim3(64, 16), 256, 0, stream>>>(fc_w + (size_t)l * 512 * 2048, wt_fc, 512, 2048);
    tr_k<<<dim3(16, 64), 256, 0, stream>>>(fcp_w + (size_t)l * 2048 * 512, wt_fcp, 2048, 512);

    // LN1 full batch -> hn (bf16)
    ln_k<1><<<8192, 256, 0, stream>>>(hf, ln1_g + l * 512, ln1_b + l * 512, hn);
    // QKV + V^T + attention per batch-half (16 batches); attn-out overwrites hn half
    for (int half = 0; half < 2; ++half) {
      const size_t ro = (size_t)half * 16384;
      gemm_bt<1><<<dim3(12, 128), 256, 0, stream>>>(hn + ro * 512, wt_qkv, qkv_b + l * 1536,
                                                    nullptr, sc, 512, 512, 512, 1536);
      vtr_k<<<dim3(16, 8, 16), 256, 0, stream>>>(sc, vt);
      attn_k<<<dim3(16, 8, 16), 256, 0, stream>>>(sc, vt, hn + ro * 512);
    }
    // attn projection full batch: h += hn @ pw^T + b
    gemm_bt<2><<<dim3(4, 256), 256, 0, stream>>>(hn, wt_pw, attn_pb + l * 512,
                                                 hf, nullptr, 512, 512, 512, 512);
    // LN2 full batch -> hn
    ln_k<1><<<8192, 256, 0, stream>>>(hf, ln2_g + l * 512, ln2_b + l * 512, hn);
    // FF per batch-half: mid [16384x2048] bf16 in sc (64 MiB)
    for (int half = 0; half < 2; ++half) {
      const size_t ro = (size_t)half * 16384;
      gemm_bt<3><<<dim3(16, 128), 256, 0, stream>>>(hn + ro * 512, wt_fc, fc_b + l * 2048,
                                                    nullptr, sc, 512, 512, 512, 2048);
      gemm_bt<2><<<dim3(4, 128), 256, 0, stream>>>(sc, wt_fcp, fcp_b + l * 512,
                                                   hf + ro * 512, nullptr, 2048, 2048, 2048, 512);
    }
  }

  // final LN + out-proj (residual becomes final h), then pool/agg, then h output
  ln_k<1><<<8192, 256, 0, stream>>>(hf, ln_post_g, ln_post_b, hn);
  gemm_bt<0><<<dim3(4, 256), 256, 0, stream>>>(hn, w_out_t, b_out, hf, nullptr,
                                               512, 512, 512, 512);
  pool1_k<<<dim3(8, 32), 256, 0, stream>>>(hf, mask, part);
  pool2_k<<<dim3(2, 32), 256, 0, stream>>>(part, pooled);
  agg1_k<<<dim3(8, 32), 256, 0, stream>>>(pooled, agg_fc_w, agg_fc_b, z1);
  agg2_k<<<dim3(2, 32), 256, 0, stream>>>(z1, agg_pw, agg_pb, out_f);
  tout_k<<<dim3(16, 8, 32), 256, 0, stream>>>(hf, mask, out_h);
}

// Round 9
// 8456.626 us; speedup vs baseline: 1.6300x; 1.0873x over previous
//
#include <hip/hip_runtime.h>

// PartCodeTransformer forward on MI355X (gfx950).
// I/O fp32; internal bf16 MFMA + fp32 accum/residual.
// GEMM: m97-structure 128x128 tile, BK=32, global_load_lds(16B), mfma_f32_16x16x32_bf16.
// Round 9 attention: swapped QK^T (lane-local softmax rows), double-buffered K/V with
// counted s_waitcnt vmcnt(4) + raw s_barrier (2 barriers/kt, loads in flight), setprio
// around MFMA. XOR-swizzled LDS (T2) retained.

typedef unsigned short u16;
typedef unsigned int u32;
typedef __attribute__((ext_vector_type(8))) short bf16x8;
typedef __attribute__((ext_vector_type(8))) unsigned short us8;
typedef __attribute__((ext_vector_type(4))) float f32x4;

__device__ __forceinline__ float bf2f(u16 s) {
  union { u32 u; float f; } c; c.u = ((u32)s) << 16; return c.f;
}
__device__ __forceinline__ u16 f2bf(float f) {
  union { float f; u32 u; } c; c.f = f;
  u32 u = c.u;
  return (u16)((u + 0x7fffu + ((u >> 16) & 1u)) >> 16);  // RNE
}
__device__ __forceinline__ float gelu_f(float v) {
  return 0.5f * v * (1.0f + erff(v * 0.7071067811865475f));
}
__device__ __forceinline__ void gl2lds16(const u16* g, u16* l) {
  __builtin_amdgcn_global_load_lds((const __attribute__((address_space(1))) void*)g,
                                   (__attribute__((address_space(3))) void*)l, 16, 0, 0);
}
__device__ __forceinline__ f32x4 mfma16(bf16x8 a, bf16x8 b, f32x4 c) {
  return __builtin_amdgcn_mfma_f32_16x16x32_bf16(a, b, c, 0, 0, 0);
}
// chunk swizzle for 64-u16 (128B) rows: permute 16B chunks within the row
__device__ __forceinline__ int swz(int row) { return (row & 7) ^ (row >> 3); }

// ---------------- A[M,K](lda) x Bt[N,K](ldb) GEMM, 128x128 tile, bf16 operands ----------------
// EPI: 0 f32=v ; 1 bf16=v ; 2 f32+=v ; 3 bf16=gelu(v)
template <int EPI>
__global__ __launch_bounds__(256)
void gemm_bt(const u16* __restrict__ A, const u16* __restrict__ Bt,
             const float* __restrict__ bias, float* __restrict__ Cf,
             u16* __restrict__ Cb, int K, int lda, int ldb, int ldc)
{
  __shared__ __align__(16) u16 As[128 * 32];
  __shared__ __align__(16) u16 Bs[128 * 32];
  const int tid = threadIdx.x;
  const int lane = tid & 63, wid = tid >> 6;
  const int wm = wid >> 1, wn = wid & 1;
  const long m0 = (long)blockIdx.y * 128, n0 = (long)blockIdx.x * 128;

  const int c0 = tid, c1 = tid + 256;
  const u16* aS0 = A + (m0 + (c0 >> 2)) * (long)lda + (c0 & 3) * 8;
  const u16* aS1 = A + (m0 + (c1 >> 2)) * (long)lda + (c1 & 3) * 8;
  const u16* bS0 = Bt + (n0 + (c0 >> 2)) * (long)ldb + (c0 & 3) * 8;
  const u16* bS1 = Bt + (n0 + (c1 >> 2)) * (long)ldb + (c1 & 3) * 8;

  f32x4 acc[4][4] = {};
  const int aro = (wm * 64 + (lane & 15)) * 32 + (lane >> 4) * 8;
  const int bro = (wn * 64 + (lane & 15)) * 32 + (lane >> 4) * 8;

  for (int k0 = 0; k0 < K; k0 += 32) {
    gl2lds16(aS0 + k0, As + c0 * 8);
    gl2lds16(aS1 + k0, As + c1 * 8);
    gl2lds16(bS0 + k0, Bs + c0 * 8);
    gl2lds16(bS1 + k0, Bs + c1 * 8);
    __syncthreads();
    bf16x8 af[4], bfr[4];
#pragma unroll
    for (int i = 0; i < 4; ++i) af[i] = *(const bf16x8*)(As + aro + i * 16 * 32);
#pragma unroll
    for (int j = 0; j < 4; ++j) bfr[j] = *(const bf16x8*)(Bs + bro + j * 16 * 32);
#pragma unroll
    for (int i = 0; i < 4; ++i)
#pragma unroll
      for (int j = 0; j < 4; ++j)
        acc[i][j] = mfma16(af[i], bfr[j], acc[i][j]);
    __syncthreads();
  }
  const int rg = (lane >> 4) * 4, cl = lane & 15;
#pragma unroll
  for (int i = 0; i < 4; ++i) {
#pragma unroll
    for (int j = 0; j < 4; ++j) {
      const long row = m0 + wm * 64 + i * 16 + rg;
      const long col = n0 + wn * 64 + j * 16 + cl;
      const float bv = bias ? bias[col] : 0.0f;
#pragma unroll
      for (int r = 0; r < 4; ++r) {
        float v = acc[i][j][r] + bv;
        long idx = (row + r) * ldc + col;
        if (EPI == 0) Cf[idx] = v;
        else if (EPI == 1) Cb[idx] = f2bf(v);
        else if (EPI == 2) Cf[idx] += v;
        else Cb[idx] = f2bf(gelu_f(v));
      }
    }
  }
}

// ---------------- V^T builder: sc[b*1024+t][1536] V-slice -> vt[(b*8+h)*64+ch][1024] ----------------
__global__ __launch_bounds__(256)
void vtr_k(const u16* __restrict__ qkv, u16* __restrict__ vt)
{
  __shared__ u16 tile[64][66];
  const int kt = blockIdx.x, hh = blockIdx.y, b = blockIdx.z;
  const int t = threadIdx.x;
#pragma unroll
  for (int it = 0; it < 2; ++it) {
    int key = (t >> 3) + it * 32, ch0 = (t & 7) * 8;
    us8 v = *(const us8*)(qkv + ((long)b * 1024 + kt * 64 + key) * 1536 + hh * 192 + 128 + ch0);
#pragma unroll
    for (int j = 0; j < 8; ++j) tile[ch0 + j][key] = v[j];
  }
  __syncthreads();
#pragma unroll
  for (int it = 0; it < 2; ++it) {
    int ch = (t >> 3) + it * 32, key0 = (t & 7) * 8;
    us8 v;
#pragma unroll
    for (int j = 0; j < 8; ++j) v[j] = tile[ch][key0 + j];
    *(us8*)(vt + (((long)b * 8 + hh) * 64 + ch) * 1024 + kt * 64 + key0) = v;
  }
}

// ---------------- flash attention: swapped QK^T, dbuf K/V, counted vmcnt ----------------
__global__ __launch_bounds__(256)
void attn_k(const u16* __restrict__ qkv, const u16* __restrict__ vt, u16* __restrict__ o)
{
  __shared__ __align__(16) u16 Qs[64 * 64];
  __shared__ __align__(16) u16 Ks[2][64 * 64];
  __shared__ __align__(16) u16 Vts[2][64 * 64];  // [ch][key], key-chunks swizzled by swz(ch)
  __shared__ __align__(16) u16 Ps[4][16 * 64];   // per wave [q16][key64], k-chunks swizzled by swz(q)
  const int tid = threadIdx.x, lane = tid & 63, wid = tid >> 6;
  const int qt = blockIdx.x, hh = blockIdx.y, b = blockIdx.z;
  const long rowbase = (long)b * 1024;
  const long vbase = (((long)b * 8 + hh) * 64) * 1024;
  const int g = lane >> 4, cl = lane & 15;

  // Q stage: LDS linear, global source column pre-swizzled (2 loads)
#pragma unroll
  for (int it = 0; it < 2; ++it) {
    int c = tid + it * 256;
    int row = c >> 3, c8s = (c & 7) ^ swz(row);
    gl2lds16(qkv + (rowbase + qt * 64 + row) * 1536 + hh * 192 + c8s * 8, Qs + c * 8);
  }
  // K/V stage for tile kt into buf (4 loads)
#define STAGE_KV(buf, kt_)                                                              \
  {                                                                                     \
    _Pragma("unroll") for (int it = 0; it < 2; ++it) {                                  \
      int c = tid + it * 256;                                                           \
      int row = c >> 3, c8s = (c & 7) ^ swz(row);                                       \
      gl2lds16(qkv + (rowbase + (kt_) * 64 + row) * 1536 + hh * 192 + 64 + c8s * 8,     \
               Ks[buf] + c * 8);                                                        \
    }                                                                                   \
    _Pragma("unroll") for (int it = 0; it < 2; ++it) {                                  \
      int c = tid + it * 256;                                                           \
      int ch = c >> 3, c8s = (c & 7) ^ swz(ch);                                         \
      gl2lds16(vt + vbase + (long)ch * 1024 + (kt_) * 64 + c8s * 8, Vts[buf] + c * 8);  \
    }                                                                                   \
  }
  STAGE_KV(0, 0);

  float m = -3.0e38f, l = 0.f;
  f32x4 oacc[4] = {};
  const int Rq = wid * 16 + cl, sq = swz(Rq) << 3;  // Q fragment row / swizzle
  const int spw = swz(cl) << 3;                      // P row (= q = cl) swizzle
  bf16x8 aq[2];

  for (int kt = 0; kt < 16; ++kt) {
    const int cur = kt & 1;
    if (kt < 15) {
      STAGE_KV(cur ^ 1, kt + 1);
      asm volatile("s_waitcnt vmcnt(4)" ::: "memory");  // own Q+stage(kt) landed; stage(kt+1) in flight
    } else {
      asm volatile("s_waitcnt vmcnt(0)" ::: "memory");
    }
    __builtin_amdgcn_s_barrier();                       // all waves' stage(kt) landed
    if (kt == 0) {
#pragma unroll
      for (int kb = 0; kb < 2; ++kb)
        aq[kb] = *(const bf16x8*)(Qs + Rq * 64 + ((kb * 32 + g * 8) ^ sq));
    }
    // QK^T swapped: s[j] = S^T[k = j*16 + g*4 + r][q = cl]
    f32x4 s[4] = {};
    __builtin_amdgcn_s_setprio(1);
#pragma unroll
    for (int j = 0; j < 4; ++j) {
      const int Rk = j * 16 + cl, sk = swz(Rk) << 3;
#pragma unroll
      for (int kb = 0; kb < 2; ++kb) {
        bf16x8 bk = *(const bf16x8*)(Ks[cur] + Rk * 64 + ((kb * 32 + g * 8) ^ sk));
        s[j] = mfma16(bk, aq[kb], s[j]);
      }
    }
    __builtin_amdgcn_s_setprio(0);
    // lane-local softmax for q = cl over 16 k-values (+2-step cross-g reduce)
    float mx = s[0][0];
#pragma unroll
    for (int j = 0; j < 4; ++j)
#pragma unroll
      for (int r = 0; r < 4; ++r) mx = fmaxf(mx, s[j][r]);
    mx *= 0.125f;
    mx = fmaxf(mx, __shfl_xor(mx, 16, 64));
    mx = fmaxf(mx, __shfl_xor(mx, 32, 64));
    const float mnew = fmaxf(m, mx);
    const float al = __expf(m - mnew);
    m = mnew;
    float p[4][4], ts = 0.f;
#pragma unroll
    for (int j = 0; j < 4; ++j)
#pragma unroll
      for (int r = 0; r < 4; ++r) {
        p[j][r] = __expf(s[j][r] * 0.125f - mnew);
        ts += p[j][r];
      }
    ts += __shfl_xor(ts, 16, 64);
    ts += __shfl_xor(ts, 32, 64);
    l = l * al + ts;
    // fetch alpha for oacc rows q = g*4+r (source lane: same g, cl = g*4+r)
    float alr[4];
#pragma unroll
    for (int r = 0; r < 4; ++r) alr[r] = __shfl(al, (lane & 48) | (g * 4 + r), 64);
#pragma unroll
    for (int cb = 0; cb < 4; ++cb) {
      f32x4 t = oacc[cb];
      t[0] *= alr[0]; t[1] *= alr[1]; t[2] *= alr[2]; t[3] *= alr[3];
      oacc[cb] = t;
    }
    // P store: Ps[wid][q=cl][k], k-chunks swizzled by swz(cl)
#pragma unroll
    for (int j = 0; j < 4; ++j)
#pragma unroll
      for (int r = 0; r < 4; ++r)
        Ps[wid][cl * 64 + ((j * 16 + g * 4 + r) ^ spw)] = f2bf(p[j][r]);
    asm volatile("s_waitcnt lgkmcnt(0)" ::: "memory");  // within-wave P write->read ordering
    bf16x8 pa[2];
#pragma unroll
    for (int kb = 0; kb < 2; ++kb)
      pa[kb] = *(const bf16x8*)(&Ps[wid][cl * 64 + ((kb * 32 + g * 8) ^ spw)]);
    __builtin_amdgcn_s_setprio(1);
#pragma unroll
    for (int kb = 0; kb < 2; ++kb)
#pragma unroll
      for (int cb = 0; cb < 4; ++cb) {
        const int ch = cb * 16 + cl;
        bf16x8 vb = *(const bf16x8*)(Vts[cur] + ch * 64 + ((kb * 32 + g * 8) ^ (swz(ch) << 3)));
        oacc[cb] = mfma16(pa[kb], vb, oacc[cb]);
      }
    __builtin_amdgcn_s_setprio(0);
    __builtin_amdgcn_s_barrier();                       // compute(kt) done; next STAGE may overwrite
  }
#undef STAGE_KV
  // final l for oacc rows q = g*4+r
  float lr[4];
#pragma unroll
  for (int r = 0; r < 4; ++r) lr[r] = __shfl(l, (lane & 48) | (g * 4 + r), 64);
#pragma unroll
  for (int cb = 0; cb < 4; ++cb)
#pragma unroll
    for (int r = 0; r < 4; ++r) {
      long row = rowbase + qt * 64 + wid * 16 + g * 4 + r;
      o[row * 512 + hh * 64 + cb * 16 + cl] = f2bf(oacc[cb][r] / lr[r]);
    }
}

// ---------------- LayerNorm, one wave per 512-row. MODE 0: f32->f32, 1: f32->bf16
template <int MODE>
__global__ __launch_bounds__(256)
void ln_k(const float* __restrict__ in_, const float* __restrict__ gg,
          const float* __restrict__ bb, void* __restrict__ out_)
{
  const long row = (long)blockIdx.x * 4 + (threadIdx.x >> 6);
  const int lane = threadIdx.x & 63;
  float x[8];
  const float* p = in_ + row * 512 + lane * 8;
  *(float4*)(x) = *(const float4*)(p);
  *(float4*)(x + 4) = *(const float4*)(p + 4);
  float s = 0.f;
#pragma unroll
  for (int j = 0; j < 8; ++j) s += x[j];
#pragma unroll
  for (int off = 1; off < 64; off <<= 1) s += __shfl_xor(s, off, 64);
  const float mean = s * (1.0f / 512.0f);
  float vs = 0.f;
#pragma unroll
  for (int j = 0; j < 8; ++j) { float d = x[j] - mean; vs += d * d; }
#pragma unroll
  for (int off = 1; off < 64; off <<= 1) vs += __shfl_xor(vs, off, 64);
  const float rstd = rsqrtf(vs * (1.0f / 512.0f) + 1e-5f);
  if (MODE == 0) {
    float y[8];
#pragma unroll
    for (int j = 0; j < 8; ++j)
      y[j] = (x[j] - mean) * rstd * gg[lane * 8 + j] + bb[lane * 8 + j];
    float* q = (float*)out_ + row * 512 + lane * 8;
    *(float4*)(q) = *(const float4*)(y);
    *(float4*)(q + 4) = *(const float4*)(y + 4);
  } else {
    us8 ov;
#pragma unroll
    for (int j = 0; j < 8; ++j)
      ov[j] = f2bf((x[j] - mean) * rstd * gg[lane * 8 + j] + bb[lane * 8 + j]);
    *(us8*)((u16*)out_ + row * 512 + lane * 8) = ov;
  }
}

// ---------------- input embed: h = E[t] + sum_9 scalars*w_in rows + b_in (fp32) ----------------
__global__ __launch_bounds__(256)
void embed_k(const float* __restrict__ x, const float* __restrict__ par,
             const float* __restrict__ E, const float* __restrict__ w_in,
             const float* __restrict__ b_in, float* __restrict__ h)
{
  const long bt = blockIdx.x;
  const int b = (int)(bt >> 10), t = (int)(bt & 1023);
  float xs[9];
#pragma unroll
  for (int c = 0; c < 3; ++c) xs[c] = x[((long)b * 3 + c) * 1024 + t];
#pragma unroll
  for (int c = 0; c < 6; ++c) xs[3 + c] = par[((long)b * 6 + c) * 1024 + t];
  for (int w = threadIdx.x; w < 512; w += 256) {
    float a = E[(long)t * 512 + w] + b_in[w];
#pragma unroll
    for (int c = 0; c < 9; ++c) a += xs[c] * w_in[c * 512 + w];
    h[bt * 512 + w] = a;
  }
}

// ---------------- fp32 -> bf16 transpose [R,C] -> [C,R] ----------------
__global__ __launch_bounds__(256)
void tr_k(const float* __restrict__ in, u16* __restrict__ out, int R, int C)
{
  __shared__ u16 tile[32][33];
  const int r0 = blockIdx.y * 32, c0 = blockIdx.x * 32;
  const int tx = threadIdx.x & 31, ty = threadIdx.x >> 5;
  for (int rr = ty; rr < 32; rr += 8) tile[rr][tx] = f2bf(in[(long)(r0 + rr) * C + c0 + tx]);
  __syncthreads();
  for (int rr = ty; rr < 32; rr += 8) out[(long)(c0 + rr) * R + r0 + tx] = tile[tx][rr];
}

// ---------------- fp32 -> bf16 cast ----------------
__global__ __launch_bounds__(256)
void cast_k(const float* __restrict__ in, u16* __restrict__ out, long n)
{
  long i = ((long)blockIdx.x * 256 + threadIdx.x) * 4;
  if (i + 3 < n) {
    float4 v = *(const float4*)(in + i);
    out[i] = f2bf(v.x); out[i + 1] = f2bf(v.y); out[i + 2] = f2bf(v.z); out[i + 3] = f2bf(v.w);
  }
}

// ---------------- masked max-pool, stage 1: coalesced per-(b, t-chunk) partial max ----------------
__global__ __launch_bounds__(256)
void pool1_k(const float* __restrict__ hm, const float* __restrict__ mask, float* __restrict__ part)
{
  const int c = blockIdx.x, b = blockIdx.y;
  const int t0 = c * 128;
  const int w0 = threadIdx.x, w1 = threadIdx.x + 256;
  float m0 = -3.0e38f, m1 = -3.0e38f;
  for (int t = 0; t < 128; ++t) {
    const float mv = mask[b * 1024 + t0 + t];
    const float neg = (1.0f - mv) * (-100000.0f);
    const float* row = hm + ((long)b * 1024 + t0 + t) * 512;
    m0 = fmaxf(m0, row[w0] * mv + neg);
    m1 = fmaxf(m1, row[w1] * mv + neg);
  }
  part[((long)b * 8 + c) * 512 + w0] = m0;
  part[((long)b * 8 + c) * 512 + w1] = m1;
}
// ---------------- stage 2: combine 8 chunks ----------------
__global__ __launch_bounds__(256)
void pool2_k(const float* __restrict__ part, float* __restrict__ pooled)
{
  const int b = blockIdx.y;
  const int w = blockIdx.x * 256 + threadIdx.x;
  float m = -3.0e38f;
#pragma unroll
  for (int c = 0; c < 8; ++c) m = fmaxf(m, part[((long)b * 8 + c) * 512 + w]);
  pooled[b * 512 + w] = m;
}

// ---------------- masked transpose to output h [B,512,T] fp32 ----------------
__global__ __launch_bounds__(256)
void tout_k(const float* __restrict__ hm, const float* __restrict__ mask, float* __restrict__ outh)
{
  __shared__ float tile[64][65];
  const int t0 = blockIdx.x * 64, w0 = blockIdx.y * 64, b = blockIdx.z;
  const int tx = threadIdx.x & 63, ty = threadIdx.x >> 6;
  for (int i = ty; i < 64; i += 4)
    tile[i][tx] = hm[((long)b * 1024 + t0 + i) * 512 + w0 + tx];
  __syncthreads();
  const float mv = mask[b * 1024 + t0 + tx];
  for (int i = ty; i < 64; i += 4)
    outh[((long)b * 512 + w0 + i) * 1024 + t0 + tx] = tile[tx][i] * mv;
}

// ---------------- tiny aggregator matmuls (fp32 weights) ----------------
__global__ __launch_bounds__(256)
void agg1_k(const float* __restrict__ pooled, const float* __restrict__ wf,
            const float* __restrict__ bf_, float* __restrict__ z1)
{
  const int b = blockIdx.y;
  const int n = blockIdx.x * 256 + threadIdx.x;
  float acc = 0.f;
  for (int k = 0; k < 512; ++k) acc += pooled[b * 512 + k] * wf[(long)k * 2048 + n];
  z1[(long)b * 2048 + n] = gelu_f(acc + bf_[n]);
}
__global__ __launch_bounds__(256)
void agg2_k(const float* __restrict__ z1, const float* __restrict__ wp,
            const float* __restrict__ bp, float* __restrict__ zo)
{
  const int b = blockIdx.y;
  const int n = blockIdx.x * 256 + threadIdx.x;
  float acc = 0.f;
  for (int k = 0; k < 2048; ++k) acc += z1[(long)b * 2048 + k] * wp[(long)k * 512 + n];
  zo[b * 512 + n] = acc + bp[n];
}

extern "C" void kernel_launch(void* const* d_in, const int* in_sizes, int n_in,
                              void* d_out, int out_size, void* d_ws, size_t ws_size,
                              hipStream_t stream)
{
  (void)in_sizes; (void)n_in; (void)out_size; (void)ws_size;
  const float* x        = (const float*)d_in[0];
  const float* params   = (const float*)d_in[1];
  const float* mask     = (const float*)d_in[2];
  const float* class_emb= (const float*)d_in[3];
  const float* w_in     = (const float*)d_in[4];
  const float* b_in     = (const float*)d_in[5];
  const float* ln_pre_g = (const float*)d_in[6];
  const float* ln_pre_b = (const float*)d_in[7];
  const float* qkv_w    = (const float*)d_in[8];
  const float* qkv_b    = (const float*)d_in[9];
  const float* attn_pw  = (const float*)d_in[10];
  const float* attn_pb  = (const float*)d_in[11];
  const float* ln1_g    = (const float*)d_in[12];
  const float* ln1_b    = (const float*)d_in[13];
  const float* fc_w     = (const float*)d_in[14];
  const float* fc_b     = (const float*)d_in[15];
  const float* fcp_w    = (const float*)d_in[16];
  const float* fcp_b    = (const float*)d_in[17];
  const float* ln2_g    = (const float*)d_in[18];
  const float* ln2_b    = (const float*)d_in[19];
  const float* ln_post_g= (const float*)d_in[20];
  const float* ln_post_b= (const float*)d_in[21];
  const float* w_out    = (const float*)d_in[22];
  const float* b_out    = (const float*)d_in[23];
  const float* agg_fc_w = (const float*)d_in[24];
  const float* agg_fc_b = (const float*)d_in[25];
  const float* agg_pw   = (const float*)d_in[26];
  const float* agg_pb   = (const float*)d_in[27];

  float* out_f = (float*)d_out;          // z: [0, 16384)
  float* out_h = out_f + 16384;          // h: 64 MiB fp32 region
  u16* sc = (u16*)out_h;                 // bf16 scratch: up to 16384x2048 (64 MiB)

  // ---- workspace layout (~125 MiB) ----
  char* ws = (char*)d_ws;
  float* hf = (float*)ws;       ws += (size_t)32768 * 512 * 4;   // residual fp32 (64 MiB)
  u16* hn = (u16*)ws;           ws += (size_t)32768 * 512 * 2;   // LN / attn-out bf16 (32 MiB)
  float* E = (float*)ws;        ws += (size_t)1024 * 512 * 4;    // class-emb proj (2 MiB)
  u16* ce_b = (u16*)ws;         ws += (size_t)1024 * 1024 * 2;   // class_emb bf16 (2 MiB)
  u16* wt_qkv = (u16*)ws;       ws += (size_t)1536 * 512 * 2;    // per-layer transposes (6.3 MiB)
  u16* wt_pw  = (u16*)ws;       ws += (size_t)512 * 512 * 2;
  u16* wt_fc  = (u16*)ws;       ws += (size_t)2048 * 512 * 2;
  u16* wt_fcp = (u16*)ws;       ws += (size_t)512 * 2048 * 2;
  u16* w_in_t = (u16*)ws;       ws += (size_t)512 * 1024 * 2;
  u16* w_out_t= (u16*)ws;       ws += (size_t)512 * 512 * 2;
  float* pooled = (float*)ws;   ws += (size_t)32 * 512 * 4;
  float* z1     = (float*)ws;   ws += (size_t)32 * 2048 * 4;
  float* part   = (float*)ws;   ws += (size_t)32 * 8 * 512 * 4;  // pool partials (0.5 MiB)
  u16* vt       = (u16*)ws;     ws += (size_t)16 * 8 * 64 * 1024 * 2;  // V^T per half (16 MiB)

  // one-time converts + class-emb projection + embed + ln_pre
  cast_k<<<1024, 256, 0, stream>>>(class_emb, ce_b, 1024 * 1024);
  tr_k<<<dim3(16, 32), 256, 0, stream>>>(w_in + 9 * 512, w_in_t, 1024, 512);
  tr_k<<<dim3(16, 16), 256, 0, stream>>>(w_out, w_out_t, 512, 512);
  gemm_bt<0><<<dim3(4, 8), 256, 0, stream>>>(ce_b, w_in_t, nullptr, E, nullptr,
                                             1024, 1024, 1024, 512);
  embed_k<<<32768, 256, 0, stream>>>(x, params, E, w_in, b_in, hf);
  ln_k<0><<<8192, 256, 0, stream>>>(hf, ln_pre_g, ln_pre_b, hf);

  for (int l = 0; l < 12; ++l) {
    tr_k<<<dim3(48, 16), 256, 0, stream>>>(qkv_w + (size_t)l * 512 * 1536, wt_qkv, 512, 1536);
    tr_k<<<dim3(16, 16), 256, 0, stream>>>(attn_pw + (size_t)l * 512 * 512, wt_pw, 512, 512);
    tr_k<<<dim3(64, 16), 256, 0, stream>>>(fc_w + (size_t)l * 512 * 2048, wt_fc, 512, 2048);
    tr_k<<<dim3(16, 64), 256, 0, stream>>>(fcp_w + (size_t)l * 2048 * 512, wt_fcp, 2048, 512);

    // LN1 full batch -> hn (bf16)
    ln_k<1><<<8192, 256, 0, stream>>>(hf, ln1_g + l * 512, ln1_b + l * 512, hn);
    // QKV + V^T + attention per batch-half (16 batches); attn-out overwrites hn half
    for (int half = 0; half < 2; ++half) {
      const size_t ro = (size_t)half * 16384;
      gemm_bt<1><<<dim3(12, 128), 256, 0, stream>>>(hn + ro * 512, wt_qkv, qkv_b + l * 1536,
                                                    nullptr, sc, 512, 512, 512, 1536);
      vtr_k<<<dim3(16, 8, 16), 256, 0, stream>>>(sc, vt);
      attn_k<<<dim3(16, 8, 16), 256, 0, stream>>>(sc, vt, hn + ro * 512);
    }
    // attn projection full batch: h += hn @ pw^T + b
    gemm_bt<2><<<dim3(4, 256), 256, 0, stream>>>(hn, wt_pw, attn_pb + l * 512,
                                                 hf, nullptr, 512, 512, 512, 512);
    // LN2 full batch -> hn
    ln_k<1><<<8192, 256, 0, stream>>>(hf, ln2_g + l * 512, ln2_b + l * 512, hn);
    // FF per batch-half: mid [16384x2048] bf16 in sc (64 MiB)
    for (int half = 0; half < 2; ++half) {
      const size_t ro = (size_t)half * 16384;
      gemm_bt<3><<<dim3(16, 128), 256, 0, stream>>>(hn + ro * 512, wt_fc, fc_b + l * 2048,
                                                    nullptr, sc, 512, 512, 512, 2048);
      gemm_bt<2><<<dim3(4, 128), 256, 0, stream>>>(sc, wt_fcp, fcp_b + l * 512,
                                                   hf + ro * 512, nullptr, 2048, 2048, 2048, 512);
    }
  }

  // final LN + out-proj (residual becomes final h), then pool/agg, then h output
  ln_k<1><<<8192, 256, 0, stream>>>(hf, ln_post_g, ln_post_b, hn);
  gemm_bt<0><<<dim3(4, 256), 256, 0, stream>>>(hn, w_out_t, b_out, hf, nullptr,
                                               512, 512, 512, 512);
  pool1_k<<<dim3(8, 32), 256, 0, stream>>>(hf, mask, part);
  pool2_k<<<dim3(2, 32), 256, 0, stream>>>(part, pooled);
  agg1_k<<<dim3(8, 32), 256, 0, stream>>>(pooled, agg_fc_w, agg_fc_b, z1);
  agg2_k<<<dim3(2, 32), 256, 0, stream>>>(z1, agg_pw, agg_pb, out_f);
  tout_k<<<dim3(16, 8, 32), 256, 0, stream>>>(hf, mask, out_h);
}

// Round 10
// 8430.943 us; speedup vs baseline: 1.6350x; 1.0030x over previous
//
#include <hip/hip_runtime.h>
#include <hip/hip_bf16.h>

// PartCodeTransformer forward on MI355X (gfx950).
// I/O fp32; internal bf16 MFMA + fp32 accum/residual.
// GEMM: m97-structure 128x128 tile, BK=32, global_load_lds(16B), mfma_f32_16x16x32_bf16.
// Round 10: hardware bf16 cvt (__float2bfloat16) replaces manual RNE everywhere hot;
// defer-max (T13, THR=8) skips O-rescale when tile max doesn't grow. Attn keeps swapped
// QK^T + dbuf K/V + counted vmcnt + setprio + T2 swizzle.

typedef unsigned short u16;
typedef unsigned int u32;
typedef __attribute__((ext_vector_type(8))) short bf16x8;
typedef __attribute__((ext_vector_type(8))) unsigned short us8;
typedef __attribute__((ext_vector_type(4))) float f32x4;

__device__ __forceinline__ float bf2f(u16 s) {
  union { u32 u; float f; } c; c.u = ((u32)s) << 16; return c.f;
}
__device__ __forceinline__ u16 f2bf(float f) {
  __hip_bfloat16 h = __float2bfloat16(f);   // hardware RNE cvt
  union { __hip_bfloat16 h; u16 u; } c; c.h = h; return c.u;
}
__device__ __forceinline__ float gelu_f(float v) {
  return 0.5f * v * (1.0f + erff(v * 0.7071067811865475f));
}
__device__ __forceinline__ void gl2lds16(const u16* g, u16* l) {
  __builtin_amdgcn_global_load_lds((const __attribute__((address_space(1))) void*)g,
                                   (__attribute__((address_space(3))) void*)l, 16, 0, 0);
}
__device__ __forceinline__ f32x4 mfma16(bf16x8 a, bf16x8 b, f32x4 c) {
  return __builtin_amdgcn_mfma_f32_16x16x32_bf16(a, b, c, 0, 0, 0);
}
// chunk swizzle for 64-u16 (128B) rows: permute 16B chunks within the row
__device__ __forceinline__ int swz(int row) { return (row & 7) ^ (row >> 3); }

// ---------------- A[M,K](lda) x Bt[N,K](ldb) GEMM, 128x128 tile, bf16 operands ----------------
// EPI: 0 f32=v ; 1 bf16=v ; 2 f32+=v ; 3 bf16=gelu(v)
template <int EPI>
__global__ __launch_bounds__(256)
void gemm_bt(const u16* __restrict__ A, const u16* __restrict__ Bt,
             const float* __restrict__ bias, float* __restrict__ Cf,
             u16* __restrict__ Cb, int K, int lda, int ldb, int ldc)
{
  __shared__ __align__(16) u16 As[128 * 32];
  __shared__ __align__(16) u16 Bs[128 * 32];
  const int tid = threadIdx.x;
  const int lane = tid & 63, wid = tid >> 6;
  const int wm = wid >> 1, wn = wid & 1;
  const long m0 = (long)blockIdx.y * 128, n0 = (long)blockIdx.x * 128;

  const int c0 = tid, c1 = tid + 256;
  const u16* aS0 = A + (m0 + (c0 >> 2)) * (long)lda + (c0 & 3) * 8;
  const u16* aS1 = A + (m0 + (c1 >> 2)) * (long)lda + (c1 & 3) * 8;
  const u16* bS0 = Bt + (n0 + (c0 >> 2)) * (long)ldb + (c0 & 3) * 8;
  const u16* bS1 = Bt + (n0 + (c1 >> 2)) * (long)ldb + (c1 & 3) * 8;

  f32x4 acc[4][4] = {};
  const int aro = (wm * 64 + (lane & 15)) * 32 + (lane >> 4) * 8;
  const int bro = (wn * 64 + (lane & 15)) * 32 + (lane >> 4) * 8;

  for (int k0 = 0; k0 < K; k0 += 32) {
    gl2lds16(aS0 + k0, As + c0 * 8);
    gl2lds16(aS1 + k0, As + c1 * 8);
    gl2lds16(bS0 + k0, Bs + c0 * 8);
    gl2lds16(bS1 + k0, Bs + c1 * 8);
    __syncthreads();
    bf16x8 af[4], bfr[4];
#pragma unroll
    for (int i = 0; i < 4; ++i) af[i] = *(const bf16x8*)(As + aro + i * 16 * 32);
#pragma unroll
    for (int j = 0; j < 4; ++j) bfr[j] = *(const bf16x8*)(Bs + bro + j * 16 * 32);
#pragma unroll
    for (int i = 0; i < 4; ++i)
#pragma unroll
      for (int j = 0; j < 4; ++j)
        acc[i][j] = mfma16(af[i], bfr[j], acc[i][j]);
    __syncthreads();
  }
  const int rg = (lane >> 4) * 4, cl = lane & 15;
#pragma unroll
  for (int i = 0; i < 4; ++i) {
#pragma unroll
    for (int j = 0; j < 4; ++j) {
      const long row = m0 + wm * 64 + i * 16 + rg;
      const long col = n0 + wn * 64 + j * 16 + cl;
      const float bv = bias ? bias[col] : 0.0f;
#pragma unroll
      for (int r = 0; r < 4; ++r) {
        float v = acc[i][j][r] + bv;
        long idx = (row + r) * ldc + col;
        if (EPI == 0) Cf[idx] = v;
        else if (EPI == 1) Cb[idx] = f2bf(v);
        else if (EPI == 2) Cf[idx] += v;
        else Cb[idx] = f2bf(gelu_f(v));
      }
    }
  }
}

// ---------------- V^T builder: sc[b*1024+t][1536] V-slice -> vt[(b*8+h)*64+ch][1024] ----------------
__global__ __launch_bounds__(256)
void vtr_k(const u16* __restrict__ qkv, u16* __restrict__ vt)
{
  __shared__ u16 tile[64][66];
  const int kt = blockIdx.x, hh = blockIdx.y, b = blockIdx.z;
  const int t = threadIdx.x;
#pragma unroll
  for (int it = 0; it < 2; ++it) {
    int key = (t >> 3) + it * 32, ch0 = (t & 7) * 8;
    us8 v = *(const us8*)(qkv + ((long)b * 1024 + kt * 64 + key) * 1536 + hh * 192 + 128 + ch0);
#pragma unroll
    for (int j = 0; j < 8; ++j) tile[ch0 + j][key] = v[j];
  }
  __syncthreads();
#pragma unroll
  for (int it = 0; it < 2; ++it) {
    int ch = (t >> 3) + it * 32, key0 = (t & 7) * 8;
    us8 v;
#pragma unroll
    for (int j = 0; j < 8; ++j) v[j] = tile[ch][key0 + j];
    *(us8*)(vt + (((long)b * 8 + hh) * 64 + ch) * 1024 + kt * 64 + key0) = v;
  }
}

// ---------------- flash attention: swapped QK^T, dbuf K/V, counted vmcnt, defer-max ----------------
__global__ __launch_bounds__(256)
void attn_k(const u16* __restrict__ qkv, const u16* __restrict__ vt, u16* __restrict__ o)
{
  __shared__ __align__(16) u16 Qs[64 * 64];
  __shared__ __align__(16) u16 Ks[2][64 * 64];
  __shared__ __align__(16) u16 Vts[2][64 * 64];  // [ch][key], key-chunks swizzled by swz(ch)
  __shared__ __align__(16) u16 Ps[4][16 * 64];   // per wave [q16][key64], k-chunks swizzled by swz(q)
  const int tid = threadIdx.x, lane = tid & 63, wid = tid >> 6;
  const int qt = blockIdx.x, hh = blockIdx.y, b = blockIdx.z;
  const long rowbase = (long)b * 1024;
  const long vbase = (((long)b * 8 + hh) * 64) * 1024;
  const int g = lane >> 4, cl = lane & 15;

  // Q stage: LDS linear, global source column pre-swizzled (2 loads)
#pragma unroll
  for (int it = 0; it < 2; ++it) {
    int c = tid + it * 256;
    int row = c >> 3, c8s = (c & 7) ^ swz(row);
    gl2lds16(qkv + (rowbase + qt * 64 + row) * 1536 + hh * 192 + c8s * 8, Qs + c * 8);
  }
  // K/V stage for tile kt into buf (4 loads)
#define STAGE_KV(buf, kt_)                                                              \
  {                                                                                     \
    _Pragma("unroll") for (int it = 0; it < 2; ++it) {                                  \
      int c = tid + it * 256;                                                           \
      int row = c >> 3, c8s = (c & 7) ^ swz(row);                                       \
      gl2lds16(qkv + (rowbase + (kt_) * 64 + row) * 1536 + hh * 192 + 64 + c8s * 8,     \
               Ks[buf] + c * 8);                                                        \
    }                                                                                   \
    _Pragma("unroll") for (int it = 0; it < 2; ++it) {                                  \
      int c = tid + it * 256;                                                           \
      int ch = c >> 3, c8s = (c & 7) ^ swz(ch);                                         \
      gl2lds16(vt + vbase + (long)ch * 1024 + (kt_) * 64 + c8s * 8, Vts[buf] + c * 8);  \
    }                                                                                   \
  }
  STAGE_KV(0, 0);

  float m = -3.0e38f, l = 0.f;
  f32x4 oacc[4] = {};
  const int Rq = wid * 16 + cl, sq = swz(Rq) << 3;  // Q fragment row / swizzle
  const int spw = swz(cl) << 3;                      // P row (= q = cl) swizzle
  bf16x8 aq[2];

  for (int kt = 0; kt < 16; ++kt) {
    const int cur = kt & 1;
    if (kt < 15) {
      STAGE_KV(cur ^ 1, kt + 1);
      asm volatile("s_waitcnt vmcnt(4)" ::: "memory");  // own Q+stage(kt) landed; stage(kt+1) in flight
    } else {
      asm volatile("s_waitcnt vmcnt(0)" ::: "memory");
    }
    __builtin_amdgcn_s_barrier();                       // all waves' stage(kt) landed
    if (kt == 0) {
#pragma unroll
      for (int kb = 0; kb < 2; ++kb)
        aq[kb] = *(const bf16x8*)(Qs + Rq * 64 + ((kb * 32 + g * 8) ^ sq));
    }
    // QK^T swapped: s[j] = S^T[k = j*16 + g*4 + r][q = cl]
    f32x4 s[4] = {};
    __builtin_amdgcn_s_setprio(1);
#pragma unroll
    for (int j = 0; j < 4; ++j) {
      const int Rk = j * 16 + cl, sk = swz(Rk) << 3;
#pragma unroll
      for (int kb = 0; kb < 2; ++kb) {
        bf16x8 bk = *(const bf16x8*)(Ks[cur] + Rk * 64 + ((kb * 32 + g * 8) ^ sk));
        s[j] = mfma16(bk, aq[kb], s[j]);
      }
    }
    __builtin_amdgcn_s_setprio(0);
    // lane-local softmax for q = cl over 16 k-values (+2-step cross-g reduce)
    float mx = s[0][0];
#pragma unroll
    for (int j = 0; j < 4; ++j)
#pragma unroll
      for (int r = 0; r < 4; ++r) mx = fmaxf(mx, s[j][r]);
    mx *= 0.125f;
    mx = fmaxf(mx, __shfl_xor(mx, 16, 64));
    mx = fmaxf(mx, __shfl_xor(mx, 32, 64));
    // defer-max (T13): rescale only when some row's max grew past THR=8
    if (!__all(mx <= m + 8.f)) {
      const float mnew = fmaxf(m, mx);
      const float al = __expf(m - mnew);
      m = mnew;
      l *= al;
      float alr[4];
#pragma unroll
      for (int r = 0; r < 4; ++r) alr[r] = __shfl(al, (lane & 48) | (g * 4 + r), 64);
#pragma unroll
      for (int cb = 0; cb < 4; ++cb) {
        f32x4 t = oacc[cb];
        t[0] *= alr[0]; t[1] *= alr[1]; t[2] *= alr[2]; t[3] *= alr[3];
        oacc[cb] = t;
      }
    }
    float p[4][4], ts = 0.f;
#pragma unroll
    for (int j = 0; j < 4; ++j)
#pragma unroll
      for (int r = 0; r < 4; ++r) {
        p[j][r] = __expf(s[j][r] * 0.125f - m);
        ts += p[j][r];
      }
    ts += __shfl_xor(ts, 16, 64);
    ts += __shfl_xor(ts, 32, 64);
    l += ts;
    // P store: Ps[wid][q=cl][k], k-chunks swizzled by swz(cl)
#pragma unroll
    for (int j = 0; j < 4; ++j)
#pragma unroll
      for (int r = 0; r < 4; ++r)
        Ps[wid][cl * 64 + ((j * 16 + g * 4 + r) ^ spw)] = f2bf(p[j][r]);
    asm volatile("s_waitcnt lgkmcnt(0)" ::: "memory");  // within-wave P write->read ordering
    bf16x8 pa[2];
#pragma unroll
    for (int kb = 0; kb < 2; ++kb)
      pa[kb] = *(const bf16x8*)(&Ps[wid][cl * 64 + ((kb * 32 + g * 8) ^ spw)]);
    __builtin_amdgcn_s_setprio(1);
#pragma unroll
    for (int kb = 0; kb < 2; ++kb)
#pragma unroll
      for (int cb = 0; cb < 4; ++cb) {
        const int ch = cb * 16 + cl;
        bf16x8 vb = *(const bf16x8*)(Vts[cur] + ch * 64 + ((kb * 32 + g * 8) ^ (swz(ch) << 3)));
        oacc[cb] = mfma16(pa[kb], vb, oacc[cb]);
      }
    __builtin_amdgcn_s_setprio(0);
    __builtin_amdgcn_s_barrier();                       // compute(kt) done; next STAGE may overwrite
  }
#undef STAGE_KV
  // final l for oacc rows q = g*4+r
  float lr[4];
#pragma unroll
  for (int r = 0; r < 4; ++r) lr[r] = __shfl(l, (lane & 48) | (g * 4 + r), 64);
#pragma unroll
  for (int cb = 0; cb < 4; ++cb)
#pragma unroll
    for (int r = 0; r < 4; ++r) {
      long row = rowbase + qt * 64 + wid * 16 + g * 4 + r;
      o[row * 512 + hh * 64 + cb * 16 + cl] = f2bf(oacc[cb][r] / lr[r]);
    }
}

// ---------------- LayerNorm, one wave per 512-row. MODE 0: f32->f32, 1: f32->bf16
template <int MODE>
__global__ __launch_bounds__(256)
void ln_k(const float* __restrict__ in_, const float* __restrict__ gg,
          const float* __restrict__ bb, void* __restrict__ out_)
{
  const long row = (long)blockIdx.x * 4 + (threadIdx.x >> 6);
  const int lane = threadIdx.x & 63;
  float x[8];
  const float* p = in_ + row * 512 + lane * 8;
  *(float4*)(x) = *(const float4*)(p);
  *(float4*)(x + 4) = *(const float4*)(p + 4);
  float s = 0.f;
#pragma unroll
  for (int j = 0; j < 8; ++j) s += x[j];
#pragma unroll
  for (int off = 1; off < 64; off <<= 1) s += __shfl_xor(s, off, 64);
  const float mean = s * (1.0f / 512.0f);
  float vs = 0.f;
#pragma unroll
  for (int j = 0; j < 8; ++j) { float d = x[j] - mean; vs += d * d; }
#pragma unroll
  for (int off = 1; off < 64; off <<= 1) vs += __shfl_xor(vs, off, 64);
  const float rstd = rsqrtf(vs * (1.0f / 512.0f) + 1e-5f);
  if (MODE == 0) {
    float y[8];
#pragma unroll
    for (int j = 0; j < 8; ++j)
      y[j] = (x[j] - mean) * rstd * gg[lane * 8 + j] + bb[lane * 8 + j];
    float* q = (float*)out_ + row * 512 + lane * 8;
    *(float4*)(q) = *(const float4*)(y);
    *(float4*)(q + 4) = *(const float4*)(y + 4);
  } else {
    us8 ov;
#pragma unroll
    for (int j = 0; j < 8; ++j)
      ov[j] = f2bf((x[j] - mean) * rstd * gg[lane * 8 + j] + bb[lane * 8 + j]);
    *(us8*)((u16*)out_ + row * 512 + lane * 8) = ov;
  }
}

// ---------------- input embed: h = E[t] + sum_9 scalars*w_in rows + b_in (fp32) ----------------
__global__ __launch_bounds__(256)
void embed_k(const float* __restrict__ x, const float* __restrict__ par,
             const float* __restrict__ E, const float* __restrict__ w_in,
             const float* __restrict__ b_in, float* __restrict__ h)
{
  const long bt = blockIdx.x;
  const int b = (int)(bt >> 10), t = (int)(bt & 1023);
  float xs[9];
#pragma unroll
  for (int c = 0; c < 3; ++c) xs[c] = x[((long)b * 3 + c) * 1024 + t];
#pragma unroll
  for (int c = 0; c < 6; ++c) xs[3 + c] = par[((long)b * 6 + c) * 1024 + t];
  for (int w = threadIdx.x; w < 512; w += 256) {
    float a = E[(long)t * 512 + w] + b_in[w];
#pragma unroll
    for (int c = 0; c < 9; ++c) a += xs[c] * w_in[c * 512 + w];
    h[bt * 512 + w] = a;
  }
}

// ---------------- fp32 -> bf16 transpose [R,C] -> [C,R] ----------------
__global__ __launch_bounds__(256)
void tr_k(const float* __restrict__ in, u16* __restrict__ out, int R, int C)
{
  __shared__ u16 tile[32][33];
  const int r0 = blockIdx.y * 32, c0 = blockIdx.x * 32;
  const int tx = threadIdx.x & 31, ty = threadIdx.x >> 5;
  for (int rr = ty; rr < 32; rr += 8) tile[rr][tx] = f2bf(in[(long)(r0 + rr) * C + c0 + tx]);
  __syncthreads();
  for (int rr = ty; rr < 32; rr += 8) out[(long)(c0 + rr) * R + r0 + tx] = tile[tx][rr];
}

// ---------------- fp32 -> bf16 cast ----------------
__global__ __launch_bounds__(256)
void cast_k(const float* __restrict__ in, u16* __restrict__ out, long n)
{
  long i = ((long)blockIdx.x * 256 + threadIdx.x) * 4;
  if (i + 3 < n) {
    float4 v = *(const float4*)(in + i);
    out[i] = f2bf(v.x); out[i + 1] = f2bf(v.y); out[i + 2] = f2bf(v.z); out[i + 3] = f2bf(v.w);
  }
}

// ---------------- masked max-pool, stage 1: coalesced per-(b, t-chunk) partial max ----------------
__global__ __launch_bounds__(256)
void pool1_k(const float* __restrict__ hm, const float* __restrict__ mask, float* __restrict__ part)
{
  const int c = blockIdx.x, b = blockIdx.y;
  const int t0 = c * 128;
  const int w0 = threadIdx.x, w1 = threadIdx.x + 256;
  float m0 = -3.0e38f, m1 = -3.0e38f;
  for (int t = 0; t < 128; ++t) {
    const float mv = mask[b * 1024 + t0 + t];
    const float neg = (1.0f - mv) * (-100000.0f);
    const float* row = hm + ((long)b * 1024 + t0 + t) * 512;
    m0 = fmaxf(m0, row[w0] * mv + neg);
    m1 = fmaxf(m1, row[w1] * mv + neg);
  }
  part[((long)b * 8 + c) * 512 + w0] = m0;
  part[((long)b * 8 + c) * 512 + w1] = m1;
}
// ---------------- stage 2: combine 8 chunks ----------------
__global__ __launch_bounds__(256)
void pool2_k(const float* __restrict__ part, float* __restrict__ pooled)
{
  const int b = blockIdx.y;
  const int w = blockIdx.x * 256 + threadIdx.x;
  float m = -3.0e38f;
#pragma unroll
  for (int c = 0; c < 8; ++c) m = fmaxf(m, part[((long)b * 8 + c) * 512 + w]);
  pooled[b * 512 + w] = m;
}

// ---------------- masked transpose to output h [B,512,T] fp32 ----------------
__global__ __launch_bounds__(256)
void tout_k(const float* __restrict__ hm, const float* __restrict__ mask, float* __restrict__ outh)
{
  __shared__ float tile[64][65];
  const int t0 = blockIdx.x * 64, w0 = blockIdx.y * 64, b = blockIdx.z;
  const int tx = threadIdx.x & 63, ty = threadIdx.x >> 6;
  for (int i = ty; i < 64; i += 4)
    tile[i][tx] = hm[((long)b * 1024 + t0 + i) * 512 + w0 + tx];
  __syncthreads();
  const float mv = mask[b * 1024 + t0 + tx];
  for (int i = ty; i < 64; i += 4)
    outh[((long)b * 512 + w0 + i) * 1024 + t0 + tx] = tile[tx][i] * mv;
}

// ---------------- tiny aggregator matmuls (fp32 weights) ----------------
__global__ __launch_bounds__(256)
void agg1_k(const float* __restrict__ pooled, const float* __restrict__ wf,
            const float* __restrict__ bf_, float* __restrict__ z1)
{
  const int b = blockIdx.y;
  const int n = blockIdx.x * 256 + threadIdx.x;
  float acc = 0.f;
  for (int k = 0; k < 512; ++k) acc += pooled[b * 512 + k] * wf[(long)k * 2048 + n];
  z1[(long)b * 2048 + n] = gelu_f(acc + bf_[n]);
}
__global__ __launch_bounds__(256)
void agg2_k(const float* __restrict__ z1, const float* __restrict__ wp,
            const float* __restrict__ bp, float* __restrict__ zo)
{
  const int b = blockIdx.y;
  const int n = blockIdx.x * 256 + threadIdx.x;
  float acc = 0.f;
  for (int k = 0; k < 2048; ++k) acc += z1[(long)b * 2048 + k] * wp[(long)k * 512 + n];
  zo[b * 512 + n] = acc + bp[n];
}

extern "C" void kernel_launch(void* const* d_in, const int* in_sizes, int n_in,
                              void* d_out, int out_size, void* d_ws, size_t ws_size,
                              hipStream_t stream)
{
  (void)in_sizes; (void)n_in; (void)out_size; (void)ws_size;
  const float* x        = (const float*)d_in[0];
  const float* params   = (const float*)d_in[1];
  const float* mask     = (const float*)d_in[2];
  const float* class_emb= (const float*)d_in[3];
  const float* w_in     = (const float*)d_in[4];
  const float* b_in     = (const float*)d_in[5];
  const float* ln_pre_g = (const float*)d_in[6];
  const float* ln_pre_b = (const float*)d_in[7];
  const float* qkv_w    = (const float*)d_in[8];
  const float* qkv_b    = (const float*)d_in[9];
  const float* attn_pw  = (const float*)d_in[10];
  const float* attn_pb  = (const float*)d_in[11];
  const float* ln1_g    = (const float*)d_in[12];
  const float* ln1_b    = (const float*)d_in[13];
  const float* fc_w     = (const float*)d_in[14];
  const float* fc_b     = (const float*)d_in[15];
  const float* fcp_w    = (const float*)d_in[16];
  const float* fcp_b    = (const float*)d_in[17];
  const float* ln2_g    = (const float*)d_in[18];
  const float* ln2_b    = (const float*)d_in[19];
  const float* ln_post_g= (const float*)d_in[20];
  const float* ln_post_b= (const float*)d_in[21];
  const float* w_out    = (const float*)d_in[22];
  const float* b_out    = (const float*)d_in[23];
  const float* agg_fc_w = (const float*)d_in[24];
  const float* agg_fc_b = (const float*)d_in[25];
  const float* agg_pw   = (const float*)d_in[26];
  const float* agg_pb   = (const float*)d_in[27];

  float* out_f = (float*)d_out;          // z: [0, 16384)
  float* out_h = out_f + 16384;          // h: 64 MiB fp32 region
  u16* sc = (u16*)out_h;                 // bf16 scratch: up to 16384x2048 (64 MiB)

  // ---- workspace layout (~125 MiB) ----
  char* ws = (char*)d_ws;
  float* hf = (float*)ws;       ws += (size_t)32768 * 512 * 4;   // residual fp32 (64 MiB)
  u16* hn = (u16*)ws;           ws += (size_t)32768 * 512 * 2;   // LN / attn-out bf16 (32 MiB)
  float* E = (float*)ws;        ws += (size_t)1024 * 512 * 4;    // class-emb proj (2 MiB)
  u16* ce_b = (u16*)ws;         ws += (size_t)1024 * 1024 * 2;   // class_emb bf16 (2 MiB)
  u16* wt_qkv = (u16*)ws;       ws += (size_t)1536 * 512 * 2;    // per-layer transposes (6.3 MiB)
  u16* wt_pw  = (u16*)ws;       ws += (size_t)512 * 512 * 2;
  u16* wt_fc  = (u16*)ws;       ws += (size_t)2048 * 512 * 2;
  u16* wt_fcp = (u16*)ws;       ws += (size_t)512 * 2048 * 2;
  u16* w_in_t = (u16*)ws;       ws += (size_t)512 * 1024 * 2;
  u16* w_out_t= (u16*)ws;       ws += (size_t)512 * 512 * 2;
  float* pooled = (float*)ws;   ws += (size_t)32 * 512 * 4;
  float* z1     = (float*)ws;   ws += (size_t)32 * 2048 * 4;
  float* part   = (float*)ws;   ws += (size_t)32 * 8 * 512 * 4;  // pool partials (0.5 MiB)
  u16* vt       = (u16*)ws;     ws += (size_t)16 * 8 * 64 * 1024 * 2;  // V^T per half (16 MiB)

  // one-time converts + class-emb projection + embed + ln_pre
  cast_k<<<1024, 256, 0, stream>>>(class_emb, ce_b, 1024 * 1024);
  tr_k<<<dim3(16, 32), 256, 0, stream>>>(w_in + 9 * 512, w_in_t, 1024, 512);
  tr_k<<<dim3(16, 16), 256, 0, stream>>>(w_out, w_out_t, 512, 512);
  gemm_bt<0><<<dim3(4, 8), 256, 0, stream>>>(ce_b, w_in_t, nullptr, E, nullptr,
                                             1024, 1024, 1024, 512);
  embed_k<<<32768, 256, 0, stream>>>(x, params, E, w_in, b_in, hf);
  ln_k<0><<<8192, 256, 0, stream>>>(hf, ln_pre_g, ln_pre_b, hf);

  for (int l = 0; l < 12; ++l) {
    tr_k<<<dim3(48, 16), 256, 0, stream>>>(qkv_w + (size_t)l * 512 * 1536, wt_qkv, 512, 1536);
    tr_k<<<dim3(16, 16), 256, 0, stream>>>(attn_pw + (size_t)l * 512 * 512, wt_pw, 512, 512);
    tr_k<<<dim3(64, 16), 256, 0, stream>>>(fc_w + (size_t)l * 512 * 2048, wt_fc, 512, 2048);
    tr_k<<<dim3(16, 64), 256, 0, stream>>>(fcp_w + (size_t)l * 2048 * 512, wt_fcp, 2048, 512);

    // LN1 full batch -> hn (bf16)
    ln_k<1><<<8192, 256, 0, stream>>>(hf, ln1_g + l * 512, ln1_b + l * 512, hn);
    // QKV + V^T + attention per batch-half (16 batches); attn-out overwrites hn half
    for (int half = 0; half < 2; ++half) {
      const size_t ro = (size_t)half * 16384;
      gemm_bt<1><<<dim3(12, 128), 256, 0, stream>>>(hn + ro * 512, wt_qkv, qkv_b + l * 1536,
                                                    nullptr, sc, 512, 512, 512, 1536);
      vtr_k<<<dim3(16, 8, 16), 256, 0, stream>>>(sc, vt);
      attn_k<<<dim3(16, 8, 16), 256, 0, stream>>>(sc, vt, hn + ro * 512);
    }
    // attn projection full batch: h += hn @ pw^T + b
    gemm_bt<2><<<dim3(4, 256), 256, 0, stream>>>(hn, wt_pw, attn_pb + l * 512,
                                                 hf, nullptr, 512, 512, 512, 512);
    // LN2 full batch -> hn
    ln_k<1><<<8192, 256, 0, stream>>>(hf, ln2_g + l * 512, ln2_b + l * 512, hn);
    // FF per batch-half: mid [16384x2048] bf16 in sc (64 MiB)
    for (int half = 0; half < 2; ++half) {
      const size_t ro = (size_t)half * 16384;
      gemm_bt<3><<<dim3(16, 128), 256, 0, stream>>>(hn + ro * 512, wt_fc, fc_b + l * 2048,
                                                    nullptr, sc, 512, 512, 512, 2048);
      gemm_bt<2><<<dim3(4, 128), 256, 0, stream>>>(sc, wt_fcp, fcp_b + l * 512,
                                                   hf + ro * 512, nullptr, 2048, 2048, 2048, 512);
    }
  }

  // final LN + out-proj (residual becomes final h), then pool/agg, then h output
  ln_k<1><<<8192, 256, 0, stream>>>(hf, ln_post_g, ln_post_b, hn);
  gemm_bt<0><<<dim3(4, 256), 256, 0, stream>>>(hn, w_out_t, b_out, hf, nullptr,
                                               512, 512, 512, 512);
  pool1_k<<<dim3(8, 32), 256, 0, stream>>>(hf, mask, part);
  pool2_k<<<dim3(2, 32), 256, 0, stream>>>(part, pooled);
  agg1_k<<<dim3(8, 32), 256, 0, stream>>>(pooled, agg_fc_w, agg_fc_b, z1);
  agg2_k<<<dim3(2, 32), 256, 0, stream>>>(z1, agg_pw, agg_pb, out_f);
  tout_k<<<dim3(16, 8, 32), 256, 0, stream>>>(hf, mask, out_h);
}

// Round 11
// 7970.099 us; speedup vs baseline: 1.7295x; 1.0578x over previous
//
#include <hip/hip_runtime.h>
#include <hip/hip_bf16.h>

// PartCodeTransformer forward on MI355X (gfx950).
// I/O fp32; internal bf16 MFMA + fp32 accum/residual.
// Round 11: gemm_bt 2-phase dbuf pipeline (STAGE next -> vmcnt(4) -> barrier -> MFMA ->
// barrier; loads in flight across compute). attn: P-scratch overlaid on Qs (40KB LDS ->
// 4 blocks/CU) and P-store as 4x ds_write_b64. All prior techniques retained.

typedef unsigned short u16;
typedef unsigned int u32;
typedef __attribute__((ext_vector_type(8))) short bf16x8;
typedef __attribute__((ext_vector_type(8))) unsigned short us8;
typedef __attribute__((ext_vector_type(4))) unsigned short us4;
typedef __attribute__((ext_vector_type(4))) float f32x4;

__device__ __forceinline__ float bf2f(u16 s) {
  union { u32 u; float f; } c; c.u = ((u32)s) << 16; return c.f;
}
__device__ __forceinline__ u16 f2bf(float f) {
  __hip_bfloat16 h = __float2bfloat16(f);   // hardware RNE cvt
  union { __hip_bfloat16 h; u16 u; } c; c.h = h; return c.u;
}
__device__ __forceinline__ float gelu_f(float v) {
  return 0.5f * v * (1.0f + erff(v * 0.7071067811865475f));
}
__device__ __forceinline__ void gl2lds16(const u16* g, u16* l) {
  __builtin_amdgcn_global_load_lds((const __attribute__((address_space(1))) void*)g,
                                   (__attribute__((address_space(3))) void*)l, 16, 0, 0);
}
__device__ __forceinline__ f32x4 mfma16(bf16x8 a, bf16x8 b, f32x4 c) {
  return __builtin_amdgcn_mfma_f32_16x16x32_bf16(a, b, c, 0, 0, 0);
}
// chunk swizzle for 64-u16 (128B) rows: permute 16B chunks within the row
__device__ __forceinline__ int swz(int row) { return (row & 7) ^ (row >> 3); }

// ---------------- A[M,K](lda) x Bt[N,K](ldb) GEMM, 128x128 tile, 2-phase dbuf ----------------
// EPI: 0 f32=v ; 1 bf16=v ; 2 f32+=v ; 3 bf16=gelu(v)
template <int EPI>
__global__ __launch_bounds__(256)
void gemm_bt(const u16* __restrict__ A, const u16* __restrict__ Bt,
             const float* __restrict__ bias, float* __restrict__ Cf,
             u16* __restrict__ Cb, int K, int lda, int ldb, int ldc)
{
  __shared__ __align__(16) u16 As[2][128 * 32];
  __shared__ __align__(16) u16 Bs[2][128 * 32];
  const int tid = threadIdx.x;
  const int lane = tid & 63, wid = tid >> 6;
  const int wm = wid >> 1, wn = wid & 1;
  const long m0 = (long)blockIdx.y * 128, n0 = (long)blockIdx.x * 128;

  const int c0 = tid, c1 = tid + 256;
  const u16* aS0 = A + (m0 + (c0 >> 2)) * (long)lda + (c0 & 3) * 8;
  const u16* aS1 = A + (m0 + (c1 >> 2)) * (long)lda + (c1 & 3) * 8;
  const u16* bS0 = Bt + (n0 + (c0 >> 2)) * (long)ldb + (c0 & 3) * 8;
  const u16* bS1 = Bt + (n0 + (c1 >> 2)) * (long)ldb + (c1 & 3) * 8;

  f32x4 acc[4][4] = {};
  const int aro = (wm * 64 + (lane & 15)) * 32 + (lane >> 4) * 8;
  const int bro = (wn * 64 + (lane & 15)) * 32 + (lane >> 4) * 8;
  const int nt = K >> 5;

#define STAGE_AB(buf, k0_)                          \
  gl2lds16(aS0 + (k0_), As[buf] + c0 * 8);          \
  gl2lds16(aS1 + (k0_), As[buf] + c1 * 8);          \
  gl2lds16(bS0 + (k0_), Bs[buf] + c0 * 8);          \
  gl2lds16(bS1 + (k0_), Bs[buf] + c1 * 8);

  STAGE_AB(0, 0);
  for (int t = 0; t < nt; ++t) {
    const int cur = t & 1;
    if (t < nt - 1) {
      STAGE_AB(cur ^ 1, (t + 1) * 32);
      asm volatile("s_waitcnt vmcnt(4)" ::: "memory");  // own stage(t) landed; stage(t+1) in flight
    } else {
      asm volatile("s_waitcnt vmcnt(0)" ::: "memory");
    }
    __builtin_amdgcn_s_barrier();                       // all waves' stage(t) landed
    bf16x8 af[4], bfr[4];
#pragma unroll
    for (int i = 0; i < 4; ++i) af[i] = *(const bf16x8*)(As[cur] + aro + i * 16 * 32);
#pragma unroll
    for (int j = 0; j < 4; ++j) bfr[j] = *(const bf16x8*)(Bs[cur] + bro + j * 16 * 32);
    __builtin_amdgcn_s_setprio(1);
#pragma unroll
    for (int i = 0; i < 4; ++i)
#pragma unroll
      for (int j = 0; j < 4; ++j)
        acc[i][j] = mfma16(af[i], bfr[j], acc[i][j]);
    __builtin_amdgcn_s_setprio(0);
    __builtin_amdgcn_s_barrier();                       // compute(t) done; next STAGE may overwrite
  }
#undef STAGE_AB
  const int rg = (lane >> 4) * 4, cl = lane & 15;
#pragma unroll
  for (int i = 0; i < 4; ++i) {
#pragma unroll
    for (int j = 0; j < 4; ++j) {
      const long row = m0 + wm * 64 + i * 16 + rg;
      const long col = n0 + wn * 64 + j * 16 + cl;
      const float bv = bias ? bias[col] : 0.0f;
#pragma unroll
      for (int r = 0; r < 4; ++r) {
        float v = acc[i][j][r] + bv;
        long idx = (row + r) * ldc + col;
        if (EPI == 0) Cf[idx] = v;
        else if (EPI == 1) Cb[idx] = f2bf(v);
        else if (EPI == 2) Cf[idx] += v;
        else Cb[idx] = f2bf(gelu_f(v));
      }
    }
  }
}

// ---------------- V^T builder: sc[b*1024+t][1536] V-slice -> vt[(b*8+h)*64+ch][1024] ----------------
__global__ __launch_bounds__(256)
void vtr_k(const u16* __restrict__ qkv, u16* __restrict__ vt)
{
  __shared__ u16 tile[64][66];
  const int kt = blockIdx.x, hh = blockIdx.y, b = blockIdx.z;
  const int t = threadIdx.x;
#pragma unroll
  for (int it = 0; it < 2; ++it) {
    int key = (t >> 3) + it * 32, ch0 = (t & 7) * 8;
    us8 v = *(const us8*)(qkv + ((long)b * 1024 + kt * 64 + key) * 1536 + hh * 192 + 128 + ch0);
#pragma unroll
    for (int j = 0; j < 8; ++j) tile[ch0 + j][key] = v[j];
  }
  __syncthreads();
#pragma unroll
  for (int it = 0; it < 2; ++it) {
    int ch = (t >> 3) + it * 32, key0 = (t & 7) * 8;
    us8 v;
#pragma unroll
    for (int j = 0; j < 8; ++j) v[j] = tile[ch][key0 + j];
    *(us8*)(vt + (((long)b * 8 + hh) * 64 + ch) * 1024 + kt * 64 + key0) = v;
  }
}

// ---------------- flash attention: swapped QK^T, dbuf K/V, counted vmcnt, defer-max ----------------
// LDS 40KB (P overlaid on Qs) -> 4 blocks/CU.
__global__ __launch_bounds__(256)
void attn_k(const u16* __restrict__ qkv, const u16* __restrict__ vt, u16* __restrict__ o)
{
  __shared__ __align__(16) u16 Qs[64 * 64];      // rows [wid*16, wid*16+16) reused as P after kt=0 read
  __shared__ __align__(16) u16 Ks[2][64 * 64];
  __shared__ __align__(16) u16 Vts[2][64 * 64];  // [ch][key], key-chunks swizzled by swz(ch)
  const int tid = threadIdx.x, lane = tid & 63, wid = tid >> 6;
  const int qt = blockIdx.x, hh = blockIdx.y, b = blockIdx.z;
  const long rowbase = (long)b * 1024;
  const long vbase = (((long)b * 8 + hh) * 64) * 1024;
  const int g = lane >> 4, cl = lane & 15;
  u16* Psw = Qs + wid * 1024;                    // per-wave 16x64 P scratch (aliases own Q rows)

  // Q stage: LDS linear, global source column pre-swizzled (2 loads)
#pragma unroll
  for (int it = 0; it < 2; ++it) {
    int c = tid + it * 256;
    int row = c >> 3, c8s = (c & 7) ^ swz(row);
    gl2lds16(qkv + (rowbase + qt * 64 + row) * 1536 + hh * 192 + c8s * 8, Qs + c * 8);
  }
  // K/V stage for tile kt into buf (4 loads)
#define STAGE_KV(buf, kt_)                                                              \
  {                                                                                     \
    _Pragma("unroll") for (int it = 0; it < 2; ++it) {                                  \
      int c = tid + it * 256;                                                           \
      int row = c >> 3, c8s = (c & 7) ^ swz(row);                                       \
      gl2lds16(qkv + (rowbase + (kt_) * 64 + row) * 1536 + hh * 192 + 64 + c8s * 8,     \
               Ks[buf] + c * 8);                                                        \
    }                                                                                   \
    _Pragma("unroll") for (int it = 0; it < 2; ++it) {                                  \
      int c = tid + it * 256;                                                           \
      int ch = c >> 3, c8s = (c & 7) ^ swz(ch);                                         \
      gl2lds16(vt + vbase + (long)ch * 1024 + (kt_) * 64 + c8s * 8, Vts[buf] + c * 8);  \
    }                                                                                   \
  }
  STAGE_KV(0, 0);

  float m = -3.0e38f, l = 0.f;
  f32x4 oacc[4] = {};
  const int Rq = wid * 16 + cl, sq = swz(Rq) << 3;  // Q fragment row / swizzle
  const int spw = swz(cl) << 3;                      // P row (= q = cl) swizzle
  bf16x8 aq[2];

  for (int kt = 0; kt < 16; ++kt) {
    const int cur = kt & 1;
    if (kt < 15) {
      STAGE_KV(cur ^ 1, kt + 1);
      asm volatile("s_waitcnt vmcnt(4)" ::: "memory");  // own Q+stage(kt) landed; stage(kt+1) in flight
    } else {
      asm volatile("s_waitcnt vmcnt(0)" ::: "memory");
    }
    __builtin_amdgcn_s_barrier();                       // all waves' stage(kt) landed
    if (kt == 0) {
#pragma unroll
      for (int kb = 0; kb < 2; ++kb)
        aq[kb] = *(const bf16x8*)(Qs + Rq * 64 + ((kb * 32 + g * 8) ^ sq));
    }
    // QK^T swapped: s[j] = S^T[k = j*16 + g*4 + r][q = cl]
    f32x4 s[4] = {};
    __builtin_amdgcn_s_setprio(1);
#pragma unroll
    for (int j = 0; j < 4; ++j) {
      const int Rk = j * 16 + cl, sk = swz(Rk) << 3;
#pragma unroll
      for (int kb = 0; kb < 2; ++kb) {
        bf16x8 bk = *(const bf16x8*)(Ks[cur] + Rk * 64 + ((kb * 32 + g * 8) ^ sk));
        s[j] = mfma16(bk, aq[kb], s[j]);
      }
    }
    __builtin_amdgcn_s_setprio(0);
    // lane-local softmax for q = cl over 16 k-values (+2-step cross-g reduce)
    float mx = s[0][0];
#pragma unroll
    for (int j = 0; j < 4; ++j)
#pragma unroll
      for (int r = 0; r < 4; ++r) mx = fmaxf(mx, s[j][r]);
    mx *= 0.125f;
    mx = fmaxf(mx, __shfl_xor(mx, 16, 64));
    mx = fmaxf(mx, __shfl_xor(mx, 32, 64));
    // defer-max (T13): rescale only when some row's max grew past THR=8
    if (!__all(mx <= m + 8.f)) {
      const float mnew = fmaxf(m, mx);
      const float al = __expf(m - mnew);
      m = mnew;
      l *= al;
      float alr[4];
#pragma unroll
      for (int r = 0; r < 4; ++r) alr[r] = __shfl(al, (lane & 48) | (g * 4 + r), 64);
#pragma unroll
      for (int cb = 0; cb < 4; ++cb) {
        f32x4 t = oacc[cb];
        t[0] *= alr[0]; t[1] *= alr[1]; t[2] *= alr[2]; t[3] *= alr[3];
        oacc[cb] = t;
      }
    }
    float p[4][4], ts = 0.f;
#pragma unroll
    for (int j = 0; j < 4; ++j)
#pragma unroll
      for (int r = 0; r < 4; ++r) {
        p[j][r] = __expf(s[j][r] * 0.125f - m);
        ts += p[j][r];
      }
    ts += __shfl_xor(ts, 16, 64);
    ts += __shfl_xor(ts, 32, 64);
    l += ts;
    // P store: 4x ds_write_b64; physical(k) = k ^ spw (spw mult of 8, base mult of 4, r<4)
#pragma unroll
    for (int j = 0; j < 4; ++j) {
      us4 pk;
      pk[0] = f2bf(p[j][0]); pk[1] = f2bf(p[j][1]);
      pk[2] = f2bf(p[j][2]); pk[3] = f2bf(p[j][3]);
      *(us4*)(&Psw[cl * 64 + ((j * 16 + g * 4) ^ spw)]) = pk;
    }
    asm volatile("s_waitcnt lgkmcnt(0)" ::: "memory");  // within-wave P write->read ordering
    bf16x8 pa[2];
#pragma unroll
    for (int kb = 0; kb < 2; ++kb)
      pa[kb] = *(const bf16x8*)(&Psw[cl * 64 + ((kb * 32 + g * 8) ^ spw)]);
    __builtin_amdgcn_s_setprio(1);
#pragma unroll
    for (int kb = 0; kb < 2; ++kb)
#pragma unroll
      for (int cb = 0; cb < 4; ++cb) {
        const int ch = cb * 16 + cl;
        bf16x8 vb = *(const bf16x8*)(Vts[cur] + ch * 64 + ((kb * 32 + g * 8) ^ (swz(ch) << 3)));
        oacc[cb] = mfma16(pa[kb], vb, oacc[cb]);
      }
    __builtin_amdgcn_s_setprio(0);
    __builtin_amdgcn_s_barrier();                       // compute(kt) done; next STAGE may overwrite
  }
#undef STAGE_KV
  // final l for oacc rows q = g*4+r
  float lr[4];
#pragma unroll
  for (int r = 0; r < 4; ++r) lr[r] = __shfl(l, (lane & 48) | (g * 4 + r), 64);
#pragma unroll
  for (int cb = 0; cb < 4; ++cb)
#pragma unroll
    for (int r = 0; r < 4; ++r) {
      long row = rowbase + qt * 64 + wid * 16 + g * 4 + r;
      o[row * 512 + hh * 64 + cb * 16 + cl] = f2bf(oacc[cb][r] / lr[r]);
    }
}

// ---------------- LayerNorm, one wave per 512-row. MODE 0: f32->f32, 1: f32->bf16
template <int MODE>
__global__ __launch_bounds__(256)
void ln_k(const float* __restrict__ in_, const float* __restrict__ gg,
          const float* __restrict__ bb, void* __restrict__ out_)
{
  const long row = (long)blockIdx.x * 4 + (threadIdx.x >> 6);
  const int lane = threadIdx.x & 63;
  float x[8];
  const float* p = in_ + row * 512 + lane * 8;
  *(float4*)(x) = *(const float4*)(p);
  *(float4*)(x + 4) = *(const float4*)(p + 4);
  float s = 0.f;
#pragma unroll
  for (int j = 0; j < 8; ++j) s += x[j];
#pragma unroll
  for (int off = 1; off < 64; off <<= 1) s += __shfl_xor(s, off, 64);
  const float mean = s * (1.0f / 512.0f);
  float vs = 0.f;
#pragma unroll
  for (int j = 0; j < 8; ++j) { float d = x[j] - mean; vs += d * d; }
#pragma unroll
  for (int off = 1; off < 64; off <<= 1) vs += __shfl_xor(vs, off, 64);
  const float rstd = rsqrtf(vs * (1.0f / 512.0f) + 1e-5f);
  if (MODE == 0) {
    float y[8];
#pragma unroll
    for (int j = 0; j < 8; ++j)
      y[j] = (x[j] - mean) * rstd * gg[lane * 8 + j] + bb[lane * 8 + j];
    float* q = (float*)out_ + row * 512 + lane * 8;
    *(float4*)(q) = *(const float4*)(y);
    *(float4*)(q + 4) = *(const float4*)(y + 4);
  } else {
    us8 ov;
#pragma unroll
    for (int j = 0; j < 8; ++j)
      ov[j] = f2bf((x[j] - mean) * rstd * gg[lane * 8 + j] + bb[lane * 8 + j]);
    *(us8*)((u16*)out_ + row * 512 + lane * 8) = ov;
  }
}

// ---------------- input embed: h = E[t] + sum_9 scalars*w_in rows + b_in (fp32) ----------------
__global__ __launch_bounds__(256)
void embed_k(const float* __restrict__ x, const float* __restrict__ par,
             const float* __restrict__ E, const float* __restrict__ w_in,
             const float* __restrict__ b_in, float* __restrict__ h)
{
  const long bt = blockIdx.x;
  const int b = (int)(bt >> 10), t = (int)(bt & 1023);
  float xs[9];
#pragma unroll
  for (int c = 0; c < 3; ++c) xs[c] = x[((long)b * 3 + c) * 1024 + t];
#pragma unroll
  for (int c = 0; c < 6; ++c) xs[3 + c] = par[((long)b * 6 + c) * 1024 + t];
  for (int w = threadIdx.x; w < 512; w += 256) {
    float a = E[(long)t * 512 + w] + b_in[w];
#pragma unroll
    for (int c = 0; c < 9; ++c) a += xs[c] * w_in[c * 512 + w];
    h[bt * 512 + w] = a;
  }
}

// ---------------- fp32 -> bf16 transpose [R,C] -> [C,R] ----------------
__global__ __launch_bounds__(256)
void tr_k(const float* __restrict__ in, u16* __restrict__ out, int R, int C)
{
  __shared__ u16 tile[32][33];
  const int r0 = blockIdx.y * 32, c0 = blockIdx.x * 32;
  const int tx = threadIdx.x & 31, ty = threadIdx.x >> 5;
  for (int rr = ty; rr < 32; rr += 8) tile[rr][tx] = f2bf(in[(long)(r0 + rr) * C + c0 + tx]);
  __syncthreads();
  for (int rr = ty; rr < 32; rr += 8) out[(long)(c0 + rr) * R + r0 + tx] = tile[tx][rr];
}

// ---------------- fp32 -> bf16 cast ----------------
__global__ __launch_bounds__(256)
void cast_k(const float* __restrict__ in, u16* __restrict__ out, long n)
{
  long i = ((long)blockIdx.x * 256 + threadIdx.x) * 4;
  if (i + 3 < n) {
    float4 v = *(const float4*)(in + i);
    out[i] = f2bf(v.x); out[i + 1] = f2bf(v.y); out[i + 2] = f2bf(v.z); out[i + 3] = f2bf(v.w);
  }
}

// ---------------- masked max-pool, stage 1: coalesced per-(b, t-chunk) partial max ----------------
__global__ __launch_bounds__(256)
void pool1_k(const float* __restrict__ hm, const float* __restrict__ mask, float* __restrict__ part)
{
  const int c = blockIdx.x, b = blockIdx.y;
  const int t0 = c * 128;
  const int w0 = threadIdx.x, w1 = threadIdx.x + 256;
  float m0 = -3.0e38f, m1 = -3.0e38f;
  for (int t = 0; t < 128; ++t) {
    const float mv = mask[b * 1024 + t0 + t];
    const float neg = (1.0f - mv) * (-100000.0f);
    const float* row = hm + ((long)b * 1024 + t0 + t) * 512;
    m0 = fmaxf(m0, row[w0] * mv + neg);
    m1 = fmaxf(m1, row[w1] * mv + neg);
  }
  part[((long)b * 8 + c) * 512 + w0] = m0;
  part[((long)b * 8 + c) * 512 + w1] = m1;
}
// ---------------- stage 2: combine 8 chunks ----------------
__global__ __launch_bounds__(256)
void pool2_k(const float* __restrict__ part, float* __restrict__ pooled)
{
  const int b = blockIdx.y;
  const int w = blockIdx.x * 256 + threadIdx.x;
  float m = -3.0e38f;
#pragma unroll
  for (int c = 0; c < 8; ++c) m = fmaxf(m, part[((long)b * 8 + c) * 512 + w]);
  pooled[b * 512 + w] = m;
}

// ---------------- masked transpose to output h [B,512,T] fp32 ----------------
__global__ __launch_bounds__(256)
void tout_k(const float* __restrict__ hm, const float* __restrict__ mask, float* __restrict__ outh)
{
  __shared__ float tile[64][65];
  const int t0 = blockIdx.x * 64, w0 = blockIdx.y * 64, b = blockIdx.z;
  const int tx = threadIdx.x & 63, ty = threadIdx.x >> 6;
  for (int i = ty; i < 64; i += 4)
    tile[i][tx] = hm[((long)b * 1024 + t0 + i) * 512 + w0 + tx];
  __syncthreads();
  const float mv = mask[b * 1024 + t0 + tx];
  for (int i = ty; i < 64; i += 4)
    outh[((long)b * 512 + w0 + i) * 1024 + t0 + tx] = tile[tx][i] * mv;
}

// ---------------- tiny aggregator matmuls (fp32 weights) ----------------
__global__ __launch_bounds__(256)
void agg1_k(const float* __restrict__ pooled, const float* __restrict__ wf,
            const float* __restrict__ bf_, float* __restrict__ z1)
{
  const int b = blockIdx.y;
  const int n = blockIdx.x * 256 + threadIdx.x;
  float acc = 0.f;
  for (int k = 0; k < 512; ++k) acc += pooled[b * 512 + k] * wf[(long)k * 2048 + n];
  z1[(long)b * 2048 + n] = gelu_f(acc + bf_[n]);
}
__global__ __launch_bounds__(256)
void agg2_k(const float* __restrict__ z1, const float* __restrict__ wp,
            const float* __restrict__ bp, float* __restrict__ zo)
{
  const int b = blockIdx.y;
  const int n = blockIdx.x * 256 + threadIdx.x;
  float acc = 0.f;
  for (int k = 0; k < 2048; ++k) acc += z1[(long)b * 2048 + k] * wp[(long)k * 512 + n];
  zo[b * 512 + n] = acc + bp[n];
}

extern "C" void kernel_launch(void* const* d_in, const int* in_sizes, int n_in,
                              void* d_out, int out_size, void* d_ws, size_t ws_size,
                              hipStream_t stream)
{
  (void)in_sizes; (void)n_in; (void)out_size; (void)ws_size;
  const float* x        = (const float*)d_in[0];
  const float* params   = (const float*)d_in[1];
  const float* mask     = (const float*)d_in[2];
  const float* class_emb= (const float*)d_in[3];
  const float* w_in     = (const float*)d_in[4];
  const float* b_in     = (const float*)d_in[5];
  const float* ln_pre_g = (const float*)d_in[6];
  const float* ln_pre_b = (const float*)d_in[7];
  const float* qkv_w    = (const float*)d_in[8];
  const float* qkv_b    = (const float*)d_in[9];
  const float* attn_pw  = (const float*)d_in[10];
  const float* attn_pb  = (const float*)d_in[11];
  const float* ln1_g    = (const float*)d_in[12];
  const float* ln1_b    = (const float*)d_in[13];
  const float* fc_w     = (const float*)d_in[14];
  const float* fc_b     = (const float*)d_in[15];
  const float* fcp_w    = (const float*)d_in[16];
  const float* fcp_b    = (const float*)d_in[17];
  const float* ln2_g    = (const float*)d_in[18];
  const float* ln2_b    = (const float*)d_in[19];
  const float* ln_post_g= (const float*)d_in[20];
  const float* ln_post_b= (const float*)d_in[21];
  const float* w_out    = (const float*)d_in[22];
  const float* b_out    = (const float*)d_in[23];
  const float* agg_fc_w = (const float*)d_in[24];
  const float* agg_fc_b = (const float*)d_in[25];
  const float* agg_pw   = (const float*)d_in[26];
  const float* agg_pb   = (const float*)d_in[27];

  float* out_f = (float*)d_out;          // z: [0, 16384)
  float* out_h = out_f + 16384;          // h: 64 MiB fp32 region
  u16* sc = (u16*)out_h;                 // bf16 scratch: up to 16384x2048 (64 MiB)

  // ---- workspace layout (~125 MiB) ----
  char* ws = (char*)d_ws;
  float* hf = (float*)ws;       ws += (size_t)32768 * 512 * 4;   // residual fp32 (64 MiB)
  u16* hn = (u16*)ws;           ws += (size_t)32768 * 512 * 2;   // LN / attn-out bf16 (32 MiB)
  float* E = (float*)ws;        ws += (size_t)1024 * 512 * 4;    // class-emb proj (2 MiB)
  u16* ce_b = (u16*)ws;         ws += (size_t)1024 * 1024 * 2;   // class_emb bf16 (2 MiB)
  u16* wt_qkv = (u16*)ws;       ws += (size_t)1536 * 512 * 2;    // per-layer transposes (6.3 MiB)
  u16* wt_pw  = (u16*)ws;       ws += (size_t)512 * 512 * 2;
  u16* wt_fc  = (u16*)ws;       ws += (size_t)2048 * 512 * 2;
  u16* wt_fcp = (u16*)ws;       ws += (size_t)512 * 2048 * 2;
  u16* w_in_t = (u16*)ws;       ws += (size_t)512 * 1024 * 2;
  u16* w_out_t= (u16*)ws;       ws += (size_t)512 * 512 * 2;
  float* pooled = (float*)ws;   ws += (size_t)32 * 512 * 4;
  float* z1     = (float*)ws;   ws += (size_t)32 * 2048 * 4;
  float* part   = (float*)ws;   ws += (size_t)32 * 8 * 512 * 4;  // pool partials (0.5 MiB)
  u16* vt       = (u16*)ws;     ws += (size_t)16 * 8 * 64 * 1024 * 2;  // V^T per half (16 MiB)

  // one-time converts + class-emb projection + embed + ln_pre
  cast_k<<<1024, 256, 0, stream>>>(class_emb, ce_b, 1024 * 1024);
  tr_k<<<dim3(16, 32), 256, 0, stream>>>(w_in + 9 * 512, w_in_t, 1024, 512);
  tr_k<<<dim3(16, 16), 256, 0, stream>>>(w_out, w_out_t, 512, 512);
  gemm_bt<0><<<dim3(4, 8), 256, 0, stream>>>(ce_b, w_in_t, nullptr, E, nullptr,
                                             1024, 1024, 1024, 512);
  embed_k<<<32768, 256, 0, stream>>>(x, params, E, w_in, b_in, hf);
  ln_k<0><<<8192, 256, 0, stream>>>(hf, ln_pre_g, ln_pre_b, hf);

  for (int l = 0; l < 12; ++l) {
    tr_k<<<dim3(48, 16), 256, 0, stream>>>(qkv_w + (size_t)l * 512 * 1536, wt_qkv, 512, 1536);
    tr_k<<<dim3(16, 16), 256, 0, stream>>>(attn_pw + (size_t)l * 512 * 512, wt_pw, 512, 512);
    tr_k<<<dim3(64, 16), 256, 0, stream>>>(fc_w + (size_t)l * 512 * 2048, wt_fc, 512, 2048);
    tr_k<<<dim3(16, 64), 256, 0, stream>>>(fcp_w + (size_t)l * 2048 * 512, wt_fcp, 2048, 512);

    // LN1 full batch -> hn (bf16)
    ln_k<1><<<8192, 256, 0, stream>>>(hf, ln1_g + l * 512, ln1_b + l * 512, hn);
    // QKV + V^T + attention per batch-half (16 batches); attn-out overwrites hn half
    for (int half = 0; half < 2; ++half) {
      const size_t ro = (size_t)half * 16384;
      gemm_bt<1><<<dim3(12, 128), 256, 0, stream>>>(hn + ro * 512, wt_qkv, qkv_b + l * 1536,
                                                    nullptr, sc, 512, 512, 512, 1536);
      vtr_k<<<dim3(16, 8, 16), 256, 0, stream>>>(sc, vt);
      attn_k<<<dim3(16, 8, 16), 256, 0, stream>>>(sc, vt, hn + ro * 512);
    }
    // attn projection full batch: h += hn @ pw^T + b
    gemm_bt<2><<<dim3(4, 256), 256, 0, stream>>>(hn, wt_pw, attn_pb + l * 512,
                                                 hf, nullptr, 512, 512, 512, 512);
    // LN2 full batch -> hn
    ln_k<1><<<8192, 256, 0, stream>>>(hf, ln2_g + l * 512, ln2_b + l * 512, hn);
    // FF per batch-half: mid [16384x2048] bf16 in sc (64 MiB)
    for (int half = 0; half < 2; ++half) {
      const size_t ro = (size_t)half * 16384;
      gemm_bt<3><<<dim3(16, 128), 256, 0, stream>>>(hn + ro * 512, wt_fc, fc_b + l * 2048,
                                                    nullptr, sc, 512, 512, 512, 2048);
      gemm_bt<2><<<dim3(4, 128), 256, 0, stream>>>(sc, wt_fcp, fcp_b + l * 512,
                                                   hf + ro * 512, nullptr, 2048, 2048, 2048, 512);
    }
  }

  // final LN + out-proj (residual becomes final h), then pool/agg, then h output
  ln_k<1><<<8192, 256, 0, stream>>>(hf, ln_post_g, ln_post_b, hn);
  gemm_bt<0><<<dim3(4, 256), 256, 0, stream>>>(hn, w_out_t, b_out, hf, nullptr,
                                               512, 512, 512, 512);
  pool1_k<<<dim3(8, 32), 256, 0, stream>>>(hf, mask, part);
  pool2_k<<<dim3(2, 32), 256, 0, stream>>>(part, pooled);
  agg1_k<<<dim3(8, 32), 256, 0, stream>>>(pooled, agg_fc_w, agg_fc_b, z1);
  agg2_k<<<dim3(2, 32), 256, 0, stream>>>(z1, agg_pw, agg_pb, out_f);
  tout_k<<<dim3(16, 8, 32), 256, 0, stream>>>(hf, mask, out_h);
}

// Round 12
// 7558.546 us; speedup vs baseline: 1.8237x; 1.0544x over previous
//
#include <hip/hip_runtime.h>
#include <hip/hip_bf16.h>

// PartCodeTransformer forward on MI355X (gfx950).
// I/O fp32; internal bf16 MFMA + fp32 accum/residual.
// Round 12: attn 8-wave blocks (QBLK=128, 48KB LDS, 3 blk/CU = 24 waves/CU), K/V staging
// amortized over 2x q-rows; V-transpose fused into QKV GEMM epilogue (EPI=4) - vtr pass
// removed. GEMM keeps 2-phase dbuf pipeline; all prior techniques retained.

typedef unsigned short u16;
typedef unsigned int u32;
typedef __attribute__((ext_vector_type(8))) short bf16x8;
typedef __attribute__((ext_vector_type(8))) unsigned short us8;
typedef __attribute__((ext_vector_type(4))) unsigned short us4;
typedef __attribute__((ext_vector_type(4))) float f32x4;

__device__ __forceinline__ float bf2f(u16 s) {
  union { u32 u; float f; } c; c.u = ((u32)s) << 16; return c.f;
}
__device__ __forceinline__ u16 f2bf(float f) {
  __hip_bfloat16 h = __float2bfloat16(f);   // hardware RNE cvt
  union { __hip_bfloat16 h; u16 u; } c; c.h = h; return c.u;
}
__device__ __forceinline__ float gelu_f(float v) {
  return 0.5f * v * (1.0f + erff(v * 0.7071067811865475f));
}
__device__ __forceinline__ void gl2lds16(const u16* g, u16* l) {
  __builtin_amdgcn_global_load_lds((const __attribute__((address_space(1))) void*)g,
                                   (__attribute__((address_space(3))) void*)l, 16, 0, 0);
}
__device__ __forceinline__ f32x4 mfma16(bf16x8 a, bf16x8 b, f32x4 c) {
  return __builtin_amdgcn_mfma_f32_16x16x32_bf16(a, b, c, 0, 0, 0);
}
// chunk swizzle: permute 16B chunks within a 128B row; valid for any row index
__device__ __forceinline__ int swz(int row) { return (row ^ (row >> 3)) & 7; }

// ---------------- A[M,K](lda) x Bt[N,K](ldb) GEMM, 128x128 tile, 2-phase dbuf ----------------
// EPI: 0 f32=v ; 1 bf16=v ; 2 f32+=v ; 3 bf16=gelu(v) ; 4 qkv: Q/K->Cb, V->Vt transposed
template <int EPI>
__global__ __launch_bounds__(256)
void gemm_bt(const u16* __restrict__ A, const u16* __restrict__ Bt,
             const float* __restrict__ bias, float* __restrict__ Cf,
             u16* __restrict__ Cb, u16* __restrict__ Vt, int K, int lda, int ldb, int ldc)
{
  __shared__ __align__(16) u16 As[2][128 * 32];
  __shared__ __align__(16) u16 Bs[2][128 * 32];
  const int tid = threadIdx.x;
  const int lane = tid & 63, wid = tid >> 6;
  const int wm = wid >> 1, wn = wid & 1;
  const long m0 = (long)blockIdx.y * 128, n0 = (long)blockIdx.x * 128;

  const int c0 = tid, c1 = tid + 256;
  const u16* aS0 = A + (m0 + (c0 >> 2)) * (long)lda + (c0 & 3) * 8;
  const u16* aS1 = A + (m0 + (c1 >> 2)) * (long)lda + (c1 & 3) * 8;
  const u16* bS0 = Bt + (n0 + (c0 >> 2)) * (long)ldb + (c0 & 3) * 8;
  const u16* bS1 = Bt + (n0 + (c1 >> 2)) * (long)ldb + (c1 & 3) * 8;

  f32x4 acc[4][4] = {};
  const int aro = (wm * 64 + (lane & 15)) * 32 + (lane >> 4) * 8;
  const int bro = (wn * 64 + (lane & 15)) * 32 + (lane >> 4) * 8;
  const int nt = K >> 5;

#define STAGE_AB(buf, k0_)                          \
  gl2lds16(aS0 + (k0_), As[buf] + c0 * 8);          \
  gl2lds16(aS1 + (k0_), As[buf] + c1 * 8);          \
  gl2lds16(bS0 + (k0_), Bs[buf] + c0 * 8);          \
  gl2lds16(bS1 + (k0_), Bs[buf] + c1 * 8);

  STAGE_AB(0, 0);
  for (int t = 0; t < nt; ++t) {
    const int cur = t & 1;
    if (t < nt - 1) {
      STAGE_AB(cur ^ 1, (t + 1) * 32);
      asm volatile("s_waitcnt vmcnt(4)" ::: "memory");
    } else {
      asm volatile("s_waitcnt vmcnt(0)" ::: "memory");
    }
    __builtin_amdgcn_s_barrier();
    bf16x8 af[4], bfr[4];
#pragma unroll
    for (int i = 0; i < 4; ++i) af[i] = *(const bf16x8*)(As[cur] + aro + i * 16 * 32);
#pragma unroll
    for (int j = 0; j < 4; ++j) bfr[j] = *(const bf16x8*)(Bs[cur] + bro + j * 16 * 32);
    __builtin_amdgcn_s_setprio(1);
#pragma unroll
    for (int i = 0; i < 4; ++i)
#pragma unroll
      for (int j = 0; j < 4; ++j)
        acc[i][j] = mfma16(af[i], bfr[j], acc[i][j]);
    __builtin_amdgcn_s_setprio(0);
    __builtin_amdgcn_s_barrier();
  }
#undef STAGE_AB
  const int rg = (lane >> 4) * 4, cl = lane & 15;
#pragma unroll
  for (int i = 0; i < 4; ++i) {
#pragma unroll
    for (int j = 0; j < 4; ++j) {
      const long row = m0 + wm * 64 + i * 16 + rg;
      const long col = n0 + wn * 64 + j * 16 + cl;
      const float bv = bias ? bias[col] : 0.0f;
      if (EPI == 4) {
        const int hh = (int)col / 192, off = (int)col - hh * 192;
        if (off < 128) {
#pragma unroll
          for (int r = 0; r < 4; ++r)
            Cb[(row + r) * ldc + col] = f2bf(acc[i][j][r] + bv);
        } else {
          us4 pk;
#pragma unroll
          for (int r = 0; r < 4; ++r) pk[r] = f2bf(acc[i][j][r] + bv);
          const long bl = row >> 10, t0 = row & 1023;
          *(us4*)(Vt + (((bl * 8 + hh) * 64 + (off - 128)) << 10) + t0) = pk;
        }
      } else {
#pragma unroll
        for (int r = 0; r < 4; ++r) {
          float v = acc[i][j][r] + bv;
          long idx = (row + r) * ldc + col;
          if (EPI == 0) Cf[idx] = v;
          else if (EPI == 1) Cb[idx] = f2bf(v);
          else if (EPI == 2) Cf[idx] += v;
          else Cb[idx] = f2bf(gelu_f(v));
        }
      }
    }
  }
}

// ---------------- flash attention: 8 waves, QBLK=128, swapped QK^T, dbuf K/V ----------------
// LDS 48KB (P overlaid on each wave's own Q rows) -> 3 blocks/CU, 24 waves/CU.
__global__ __launch_bounds__(512)
void attn_k(const u16* __restrict__ qkv, const u16* __restrict__ vt, u16* __restrict__ o)
{
  __shared__ __align__(16) u16 Qs[128 * 64];     // wave w's rows [w*16,w*16+16) reused as P
  __shared__ __align__(16) u16 Ks[2][64 * 64];
  __shared__ __align__(16) u16 Vts[2][64 * 64];  // [ch][key], key-chunks swizzled by swz(ch)
  const int tid = threadIdx.x, lane = tid & 63, wid = tid >> 6;
  const int qt = blockIdx.x, hh = blockIdx.y, b = blockIdx.z;
  const long rowbase = (long)b * 1024;
  const long vbase = (((long)b * 8 + hh) * 64) * 1024;
  const int g = lane >> 4, cl = lane & 15;
  u16* Psw = Qs + wid * 1024;                    // per-wave 16x64 P scratch

  // Q stage: 128 rows, LDS linear, global source column pre-swizzled (2 loads/thread)
#pragma unroll
  for (int it = 0; it < 2; ++it) {
    int c = tid + it * 512;
    int row = c >> 3, c8s = (c & 7) ^ swz(row);
    gl2lds16(qkv + (rowbase + qt * 128 + row) * 1536 + hh * 192 + c8s * 8, Qs + c * 8);
  }
  // K/V stage for tile kt into buf (2 loads/thread)
#define STAGE_KV(buf, kt_)                                                            \
  {                                                                                   \
    int row = tid >> 3, c8s = (tid & 7) ^ swz(row);                                   \
    gl2lds16(qkv + (rowbase + (kt_) * 64 + row) * 1536 + hh * 192 + 64 + c8s * 8,     \
             Ks[buf] + tid * 8);                                                      \
    gl2lds16(vt + vbase + (long)row * 1024 + (kt_) * 64 + c8s * 8, Vts[buf] + tid * 8); \
  }
  STAGE_KV(0, 0);

  float m = -3.0e38f, l = 0.f;
  f32x4 oacc[4] = {};
  const int Rq = wid * 16 + cl, sq = swz(Rq) << 3;  // Q fragment row / swizzle
  const int spw = swz(cl) << 3;                      // P row (= q = cl) swizzle
  bf16x8 aq[2];

  for (int kt = 0; kt < 16; ++kt) {
    const int cur = kt & 1;
    if (kt < 15) {
      STAGE_KV(cur ^ 1, kt + 1);
      asm volatile("s_waitcnt vmcnt(2)" ::: "memory");  // Q+stage(kt) landed; stage(kt+1) in flight
    } else {
      asm volatile("s_waitcnt vmcnt(0)" ::: "memory");
    }
    __builtin_amdgcn_s_barrier();                       // all waves' stage(kt) landed
    if (kt == 0) {
#pragma unroll
      for (int kb = 0; kb < 2; ++kb)
        aq[kb] = *(const bf16x8*)(Qs + Rq * 64 + ((kb * 32 + g * 8) ^ sq));
    }
    // QK^T swapped: s[j] = S^T[k = j*16 + g*4 + r][q = cl]
    f32x4 s[4] = {};
    __builtin_amdgcn_s_setprio(1);
#pragma unroll
    for (int j = 0; j < 4; ++j) {
      const int Rk = j * 16 + cl, sk = swz(Rk) << 3;
#pragma unroll
      for (int kb = 0; kb < 2; ++kb) {
        bf16x8 bk = *(const bf16x8*)(Ks[cur] + Rk * 64 + ((kb * 32 + g * 8) ^ sk));
        s[j] = mfma16(bk, aq[kb], s[j]);
      }
    }
    __builtin_amdgcn_s_setprio(0);
    // lane-local softmax for q = cl over 16 k-values (+2-step cross-g reduce)
    float mx = s[0][0];
#pragma unroll
    for (int j = 0; j < 4; ++j)
#pragma unroll
      for (int r = 0; r < 4; ++r) mx = fmaxf(mx, s[j][r]);
    mx *= 0.125f;
    mx = fmaxf(mx, __shfl_xor(mx, 16, 64));
    mx = fmaxf(mx, __shfl_xor(mx, 32, 64));
    // defer-max (T13): rescale only when some row's max grew past THR=8
    if (!__all(mx <= m + 8.f)) {
      const float mnew = fmaxf(m, mx);
      const float al = __expf(m - mnew);
      m = mnew;
      l *= al;
      float alr[4];
#pragma unroll
      for (int r = 0; r < 4; ++r) alr[r] = __shfl(al, (lane & 48) | (g * 4 + r), 64);
#pragma unroll
      for (int cb = 0; cb < 4; ++cb) {
        f32x4 t = oacc[cb];
        t[0] *= alr[0]; t[1] *= alr[1]; t[2] *= alr[2]; t[3] *= alr[3];
        oacc[cb] = t;
      }
    }
    float p[4][4], ts = 0.f;
#pragma unroll
    for (int j = 0; j < 4; ++j)
#pragma unroll
      for (int r = 0; r < 4; ++r) {
        p[j][r] = __expf(s[j][r] * 0.125f - m);
        ts += p[j][r];
      }
    ts += __shfl_xor(ts, 16, 64);
    ts += __shfl_xor(ts, 32, 64);
    l += ts;
    // P store: 4x ds_write_b64; physical(k) = k ^ spw (spw mult of 8, base mult of 4)
#pragma unroll
    for (int j = 0; j < 4; ++j) {
      us4 pk;
      pk[0] = f2bf(p[j][0]); pk[1] = f2bf(p[j][1]);
      pk[2] = f2bf(p[j][2]); pk[3] = f2bf(p[j][3]);
      *(us4*)(&Psw[cl * 64 + ((j * 16 + g * 4) ^ spw)]) = pk;
    }
    asm volatile("s_waitcnt lgkmcnt(0)" ::: "memory");  // within-wave P write->read ordering
    bf16x8 pa[2];
#pragma unroll
    for (int kb = 0; kb < 2; ++kb)
      pa[kb] = *(const bf16x8*)(&Psw[cl * 64 + ((kb * 32 + g * 8) ^ spw)]);
    __builtin_amdgcn_s_setprio(1);
#pragma unroll
    for (int kb = 0; kb < 2; ++kb)
#pragma unroll
      for (int cb = 0; cb < 4; ++cb) {
        const int ch = cb * 16 + cl;
        bf16x8 vb = *(const bf16x8*)(Vts[cur] + ch * 64 + ((kb * 32 + g * 8) ^ (swz(ch) << 3)));
        oacc[cb] = mfma16(pa[kb], vb, oacc[cb]);
      }
    __builtin_amdgcn_s_setprio(0);
    __builtin_amdgcn_s_barrier();                       // compute(kt) done; next STAGE may overwrite
  }
#undef STAGE_KV
  // final l for oacc rows q = g*4+r
  float lr[4];
#pragma unroll
  for (int r = 0; r < 4; ++r) lr[r] = __shfl(l, (lane & 48) | (g * 4 + r), 64);
#pragma unroll
  for (int cb = 0; cb < 4; ++cb)
#pragma unroll
    for (int r = 0; r < 4; ++r) {
      long row = rowbase + qt * 128 + wid * 16 + g * 4 + r;
      o[row * 512 + hh * 64 + cb * 16 + cl] = f2bf(oacc[cb][r] / lr[r]);
    }
}

// ---------------- LayerNorm, one wave per 512-row. MODE 0: f32->f32, 1: f32->bf16
template <int MODE>
__global__ __launch_bounds__(256)
void ln_k(const float* __restrict__ in_, const float* __restrict__ gg,
          const float* __restrict__ bb, void* __restrict__ out_)
{
  const long row = (long)blockIdx.x * 4 + (threadIdx.x >> 6);
  const int lane = threadIdx.x & 63;
  float x[8];
  const float* p = in_ + row * 512 + lane * 8;
  *(float4*)(x) = *(const float4*)(p);
  *(float4*)(x + 4) = *(const float4*)(p + 4);
  float s = 0.f;
#pragma unroll
  for (int j = 0; j < 8; ++j) s += x[j];
#pragma unroll
  for (int off = 1; off < 64; off <<= 1) s += __shfl_xor(s, off, 64);
  const float mean = s * (1.0f / 512.0f);
  float vs = 0.f;
#pragma unroll
  for (int j = 0; j < 8; ++j) { float d = x[j] - mean; vs += d * d; }
#pragma unroll
  for (int off = 1; off < 64; off <<= 1) vs += __shfl_xor(vs, off, 64);
  const float rstd = rsqrtf(vs * (1.0f / 512.0f) + 1e-5f);
  if (MODE == 0) {
    float y[8];
#pragma unroll
    for (int j = 0; j < 8; ++j)
      y[j] = (x[j] - mean) * rstd * gg[lane * 8 + j] + bb[lane * 8 + j];
    float* q = (float*)out_ + row * 512 + lane * 8;
    *(float4*)(q) = *(const float4*)(y);
    *(float4*)(q + 4) = *(const float4*)(y + 4);
  } else {
    us8 ov;
#pragma unroll
    for (int j = 0; j < 8; ++j)
      ov[j] = f2bf((x[j] - mean) * rstd * gg[lane * 8 + j] + bb[lane * 8 + j]);
    *(us8*)((u16*)out_ + row * 512 + lane * 8) = ov;
  }
}

// ---------------- input embed: h = E[t] + sum_9 scalars*w_in rows + b_in (fp32) ----------------
__global__ __launch_bounds__(256)
void embed_k(const float* __restrict__ x, const float* __restrict__ par,
             const float* __restrict__ E, const float* __restrict__ w_in,
             const float* __restrict__ b_in, float* __restrict__ h)
{
  const long bt = blockIdx.x;
  const int b = (int)(bt >> 10), t = (int)(bt & 1023);
  float xs[9];
#pragma unroll
  for (int c = 0; c < 3; ++c) xs[c] = x[((long)b * 3 + c) * 1024 + t];
#pragma unroll
  for (int c = 0; c < 6; ++c) xs[3 + c] = par[((long)b * 6 + c) * 1024 + t];
  for (int w = threadIdx.x; w < 512; w += 256) {
    float a = E[(long)t * 512 + w] + b_in[w];
#pragma unroll
    for (int c = 0; c < 9; ++c) a += xs[c] * w_in[c * 512 + w];
    h[bt * 512 + w] = a;
  }
}

// ---------------- fp32 -> bf16 transpose [R,C] -> [C,R] ----------------
__global__ __launch_bounds__(256)
void tr_k(const float* __restrict__ in, u16* __restrict__ out, int R, int C)
{
  __shared__ u16 tile[32][33];
  const int r0 = blockIdx.y * 32, c0 = blockIdx.x * 32;
  const int tx = threadIdx.x & 31, ty = threadIdx.x >> 5;
  for (int rr = ty; rr < 32; rr += 8) tile[rr][tx] = f2bf(in[(long)(r0 + rr) * C + c0 + tx]);
  __syncthreads();
  for (int rr = ty; rr < 32; rr += 8) out[(long)(c0 + rr) * R + r0 + tx] = tile[tx][rr];
}

// ---------------- fp32 -> bf16 cast ----------------
__global__ __launch_bounds__(256)
void cast_k(const float* __restrict__ in, u16* __restrict__ out, long n)
{
  long i = ((long)blockIdx.x * 256 + threadIdx.x) * 4;
  if (i + 3 < n) {
    float4 v = *(const float4*)(in + i);
    out[i] = f2bf(v.x); out[i + 1] = f2bf(v.y); out[i + 2] = f2bf(v.z); out[i + 3] = f2bf(v.w);
  }
}

// ---------------- masked max-pool, stage 1: coalesced per-(b, t-chunk) partial max ----------------
__global__ __launch_bounds__(256)
void pool1_k(const float* __restrict__ hm, const float* __restrict__ mask, float* __restrict__ part)
{
  const int c = blockIdx.x, b = blockIdx.y;
  const int t0 = c * 128;
  const int w0 = threadIdx.x, w1 = threadIdx.x + 256;
  float m0 = -3.0e38f, m1 = -3.0e38f;
  for (int t = 0; t < 128; ++t) {
    const float mv = mask[b * 1024 + t0 + t];
    const float neg = (1.0f - mv) * (-100000.0f);
    const float* row = hm + ((long)b * 1024 + t0 + t) * 512;
    m0 = fmaxf(m0, row[w0] * mv + neg);
    m1 = fmaxf(m1, row[w1] * mv + neg);
  }
  part[((long)b * 8 + c) * 512 + w0] = m0;
  part[((long)b * 8 + c) * 512 + w1] = m1;
}
// ---------------- stage 2: combine 8 chunks ----------------
__global__ __launch_bounds__(256)
void pool2_k(const float* __restrict__ part, float* __restrict__ pooled)
{
  const int b = blockIdx.y;
  const int w = blockIdx.x * 256 + threadIdx.x;
  float m = -3.0e38f;
#pragma unroll
  for (int c = 0; c < 8; ++c) m = fmaxf(m, part[((long)b * 8 + c) * 512 + w]);
  pooled[b * 512 + w] = m;
}

// ---------------- masked transpose to output h [B,512,T] fp32 ----------------
__global__ __launch_bounds__(256)
void tout_k(const float* __restrict__ hm, const float* __restrict__ mask, float* __restrict__ outh)
{
  __shared__ float tile[64][65];
  const int t0 = blockIdx.x * 64, w0 = blockIdx.y * 64, b = blockIdx.z;
  const int tx = threadIdx.x & 63, ty = threadIdx.x >> 6;
  for (int i = ty; i < 64; i += 4)
    tile[i][tx] = hm[((long)b * 1024 + t0 + i) * 512 + w0 + tx];
  __syncthreads();
  const float mv = mask[b * 1024 + t0 + tx];
  for (int i = ty; i < 64; i += 4)
    outh[((long)b * 512 + w0 + i) * 1024 + t0 + tx] = tile[tx][i] * mv;
}

// ---------------- tiny aggregator matmuls (fp32 weights) ----------------
__global__ __launch_bounds__(256)
void agg1_k(const float* __restrict__ pooled, const float* __restrict__ wf,
            const float* __restrict__ bf_, float* __restrict__ z1)
{
  const int b = blockIdx.y;
  const int n = blockIdx.x * 256 + threadIdx.x;
  float acc = 0.f;
  for (int k = 0; k < 512; ++k) acc += pooled[b * 512 + k] * wf[(long)k * 2048 + n];
  z1[(long)b * 2048 + n] = gelu_f(acc + bf_[n]);
}
__global__ __launch_bounds__(256)
void agg2_k(const float* __restrict__ z1, const float* __restrict__ wp,
            const float* __restrict__ bp, float* __restrict__ zo)
{
  const int b = blockIdx.y;
  const int n = blockIdx.x * 256 + threadIdx.x;
  float acc = 0.f;
  for (int k = 0; k < 2048; ++k) acc += z1[(long)b * 2048 + k] * wp[(long)k * 512 + n];
  zo[b * 512 + n] = acc + bp[n];
}

extern "C" void kernel_launch(void* const* d_in, const int* in_sizes, int n_in,
                              void* d_out, int out_size, void* d_ws, size_t ws_size,
                              hipStream_t stream)
{
  (void)in_sizes; (void)n_in; (void)out_size; (void)ws_size;
  const float* x        = (const float*)d_in[0];
  const float* params   = (const float*)d_in[1];
  const float* mask     = (const float*)d_in[2];
  const float* class_emb= (const float*)d_in[3];
  const float* w_in     = (const float*)d_in[4];
  const float* b_in     = (const float*)d_in[5];
  const float* ln_pre_g = (const float*)d_in[6];
  const float* ln_pre_b = (const float*)d_in[7];
  const float* qkv_w    = (const float*)d_in[8];
  const float* qkv_b    = (const float*)d_in[9];
  const float* attn_pw  = (const float*)d_in[10];
  const float* attn_pb  = (const float*)d_in[11];
  const float* ln1_g    = (const float*)d_in[12];
  const float* ln1_b    = (const float*)d_in[13];
  const float* fc_w     = (const float*)d_in[14];
  const float* fc_b     = (const float*)d_in[15];
  const float* fcp_w    = (const float*)d_in[16];
  const float* fcp_b    = (const float*)d_in[17];
  const float* ln2_g    = (const float*)d_in[18];
  const float* ln2_b    = (const float*)d_in[19];
  const float* ln_post_g= (const float*)d_in[20];
  const float* ln_post_b= (const float*)d_in[21];
  const float* w_out    = (const float*)d_in[22];
  const float* b_out    = (const float*)d_in[23];
  const float* agg_fc_w = (const float*)d_in[24];
  const float* agg_fc_b = (const float*)d_in[25];
  const float* agg_pw   = (const float*)d_in[26];
  const float* agg_pb   = (const float*)d_in[27];

  float* out_f = (float*)d_out;          // z: [0, 16384)
  float* out_h = out_f + 16384;          // h: 64 MiB fp32 region
  u16* sc = (u16*)out_h;                 // bf16 scratch: up to 16384x2048 (64 MiB)

  // ---- workspace layout (~125 MiB) ----
  char* ws = (char*)d_ws;
  float* hf = (float*)ws;       ws += (size_t)32768 * 512 * 4;   // residual fp32 (64 MiB)
  u16* hn = (u16*)ws;           ws += (size_t)32768 * 512 * 2;   // LN / attn-out bf16 (32 MiB)
  float* E = (float*)ws;        ws += (size_t)1024 * 512 * 4;    // class-emb proj (2 MiB)
  u16* ce_b = (u16*)ws;         ws += (size_t)1024 * 1024 * 2;   // class_emb bf16 (2 MiB)
  u16* wt_qkv = (u16*)ws;       ws += (size_t)1536 * 512 * 2;    // per-layer transposes (6.3 MiB)
  u16* wt_pw  = (u16*)ws;       ws += (size_t)512 * 512 * 2;
  u16* wt_fc  = (u16*)ws;       ws += (size_t)2048 * 512 * 2;
  u16* wt_fcp = (u16*)ws;       ws += (size_t)512 * 2048 * 2;
  u16* w_in_t = (u16*)ws;       ws += (size_t)512 * 1024 * 2;
  u16* w_out_t= (u16*)ws;       ws += (size_t)512 * 512 * 2;
  float* pooled = (float*)ws;   ws += (size_t)32 * 512 * 4;
  float* z1     = (float*)ws;   ws += (size_t)32 * 2048 * 4;
  float* part   = (float*)ws;   ws += (size_t)32 * 8 * 512 * 4;  // pool partials (0.5 MiB)
  u16* vt       = (u16*)ws;     ws += (size_t)16 * 8 * 64 * 1024 * 2;  // V^T per half (16 MiB)

  // one-time converts + class-emb projection + embed + ln_pre
  cast_k<<<1024, 256, 0, stream>>>(class_emb, ce_b, 1024 * 1024);
  tr_k<<<dim3(16, 32), 256, 0, stream>>>(w_in + 9 * 512, w_in_t, 1024, 512);
  tr_k<<<dim3(16, 16), 256, 0, stream>>>(w_out, w_out_t, 512, 512);
  gemm_bt<0><<<dim3(4, 8), 256, 0, stream>>>(ce_b, w_in_t, nullptr, E, nullptr, nullptr,
                                             1024, 1024, 1024, 512);
  embed_k<<<32768, 256, 0, stream>>>(x, params, E, w_in, b_in, hf);
  ln_k<0><<<8192, 256, 0, stream>>>(hf, ln_pre_g, ln_pre_b, hf);

  for (int l = 0; l < 12; ++l) {
    tr_k<<<dim3(48, 16), 256, 0, stream>>>(qkv_w + (size_t)l * 512 * 1536, wt_qkv, 512, 1536);
    tr_k<<<dim3(16, 16), 256, 0, stream>>>(attn_pw + (size_t)l * 512 * 512, wt_pw, 512, 512);
    tr_k<<<dim3(64, 16), 256, 0, stream>>>(fc_w + (size_t)l * 512 * 2048, wt_fc, 512, 2048);
    tr_k<<<dim3(16, 64), 256, 0, stream>>>(fcp_w + (size_t)l * 2048 * 512, wt_fcp, 2048, 512);

    // LN1 full batch -> hn (bf16)
    ln_k<1><<<8192, 256, 0, stream>>>(hf, ln1_g + l * 512, ln1_b + l * 512, hn);
    // QKV (V written transposed to vt) + attention per batch-half; attn-out overwrites hn half
    for (int half = 0; half < 2; ++half) {
      const size_t ro = (size_t)half * 16384;
      gemm_bt<4><<<dim3(12, 128), 256, 0, stream>>>(hn + ro * 512, wt_qkv, qkv_b + l * 1536,
                                                    nullptr, sc, vt, 512, 512, 512, 1536);
      attn_k<<<dim3(8, 8, 16), 512, 0, stream>>>(sc, vt, hn + ro * 512);
    }
    // attn projection full batch: h += hn @ pw^T + b
    gemm_bt<2><<<dim3(4, 256), 256, 0, stream>>>(hn, wt_pw, attn_pb + l * 512,
                                                 hf, nullptr, nullptr, 512, 512, 512, 512);
    // LN2 full batch -> hn
    ln_k<1><<<8192, 256, 0, stream>>>(hf, ln2_g + l * 512, ln2_b + l * 512, hn);
    // FF per batch-half: mid [16384x2048] bf16 in sc (64 MiB)
    for (int half = 0; half < 2; ++half) {
      const size_t ro = (size_t)half * 16384;
      gemm_bt<3><<<dim3(16, 128), 256, 0, stream>>>(hn + ro * 512, wt_fc, fc_b + l * 2048,
                                                    nullptr, sc, nullptr, 512, 512, 512, 2048);
      gemm_bt<2><<<dim3(4, 128), 256, 0, stream>>>(sc, wt_fcp, fcp_b + l * 512,
                                                   hf + ro * 512, nullptr, nullptr, 2048, 2048, 2048, 512);
    }
  }

  // final LN + out-proj (residual becomes final h), then pool/agg, then h output
  ln_k<1><<<8192, 256, 0, stream>>>(hf, ln_post_g, ln_post_b, hn);
  gemm_bt<0><<<dim3(4, 256), 256, 0, stream>>>(hn, w_out_t, b_out, hf, nullptr, nullptr,
                                               512, 512, 512, 512);
  pool1_k<<<dim3(8, 32), 256, 0, stream>>>(hf, mask, part);
  pool2_k<<<dim3(2, 32), 256, 0, stream>>>(part, pooled);
  agg1_k<<<dim3(8, 32), 256, 0, stream>>>(pooled, agg_fc_w, agg_fc_b, z1);
  agg2_k<<<dim3(2, 32), 256, 0, stream>>>(z1, agg_pw, agg_pb, out_f);
  tout_k<<<dim3(16, 8, 32), 256, 0, stream>>>(hf, mask, out_h);
}

// Round 13
// 7328.548 us; speedup vs baseline: 1.8809x; 1.0314x over previous
//
#include <hip/hip_runtime.h>
#include <hip/hip_bf16.h>

// PartCodeTransformer forward on MI355X (gfx950).
// I/O fp32; internal bf16 MFMA + fp32 accum/residual.
// Round 13: GEMM 256x128 tile, 8 waves (512 thr), BK=32, 2-phase dbuf counted-vmcnt(3).
// Per-wave math identical to the 128x128 version (4Mx2N wave grid). Attn unchanged
// (8-wave QBLK=128, swapped QK^T, dbuf K/V, defer-max, T2 swizzle, EPI=4 fused V^T).

typedef unsigned short u16;
typedef unsigned int u32;
typedef __attribute__((ext_vector_type(8))) short bf16x8;
typedef __attribute__((ext_vector_type(8))) unsigned short us8;
typedef __attribute__((ext_vector_type(4))) unsigned short us4;
typedef __attribute__((ext_vector_type(4))) float f32x4;

__device__ __forceinline__ float bf2f(u16 s) {
  union { u32 u; float f; } c; c.u = ((u32)s) << 16; return c.f;
}
__device__ __forceinline__ u16 f2bf(float f) {
  __hip_bfloat16 h = __float2bfloat16(f);   // hardware RNE cvt
  union { __hip_bfloat16 h; u16 u; } c; c.h = h; return c.u;
}
__device__ __forceinline__ float gelu_f(float v) {
  return 0.5f * v * (1.0f + erff(v * 0.7071067811865475f));
}
__device__ __forceinline__ void gl2lds16(const u16* g, u16* l) {
  __builtin_amdgcn_global_load_lds((const __attribute__((address_space(1))) void*)g,
                                   (__attribute__((address_space(3))) void*)l, 16, 0, 0);
}
__device__ __forceinline__ f32x4 mfma16(bf16x8 a, bf16x8 b, f32x4 c) {
  return __builtin_amdgcn_mfma_f32_16x16x32_bf16(a, b, c, 0, 0, 0);
}
// chunk swizzle: permute 16B chunks within a 128B row; valid for any row index
__device__ __forceinline__ int swz(int row) { return (row ^ (row >> 3)) & 7; }

// ------------- A[M,K](lda) x Bt[N,K](ldb) GEMM, 256x128 tile, 8 waves, 2-phase dbuf -------------
// EPI: 0 f32=v ; 1 bf16=v ; 2 f32+=v ; 3 bf16=gelu(v) ; 4 qkv: Q/K->Cb, V->Vt transposed
template <int EPI>
__global__ __launch_bounds__(512)
void gemm_bt(const u16* __restrict__ A, const u16* __restrict__ Bt,
             const float* __restrict__ bias, float* __restrict__ Cf,
             u16* __restrict__ Cb, u16* __restrict__ Vt, int K, int lda, int ldb, int ldc)
{
  __shared__ __align__(16) u16 As[2][256 * 32];   // 32 KB
  __shared__ __align__(16) u16 Bs[2][128 * 32];   // 16 KB
  const int tid = threadIdx.x;
  const int lane = tid & 63, wid = tid >> 6;
  const int wm = wid & 3, wn = wid >> 2;          // 4 M-waves x 2 N-waves, 64x64 each
  const long m0 = (long)blockIdx.y * 256, n0 = (long)blockIdx.x * 128;

  const int c0 = tid, c1 = tid + 512;
  const u16* aS0 = A + (m0 + (c0 >> 2)) * (long)lda + (c0 & 3) * 8;
  const u16* aS1 = A + (m0 + (c1 >> 2)) * (long)lda + (c1 & 3) * 8;
  const u16* bS0 = Bt + (n0 + (tid >> 2)) * (long)ldb + (tid & 3) * 8;

  f32x4 acc[4][4] = {};
  const int aro = (wm * 64 + (lane & 15)) * 32 + (lane >> 4) * 8;
  const int bro = (wn * 64 + (lane & 15)) * 32 + (lane >> 4) * 8;
  const int nt = K >> 5;

#define STAGE_AB(buf, k0_)                          \
  gl2lds16(aS0 + (k0_), As[buf] + c0 * 8);          \
  gl2lds16(aS1 + (k0_), As[buf] + c1 * 8);          \
  gl2lds16(bS0 + (k0_), Bs[buf] + tid * 8);

  STAGE_AB(0, 0);
  for (int t = 0; t < nt; ++t) {
    const int cur = t & 1;
    if (t < nt - 1) {
      STAGE_AB(cur ^ 1, (t + 1) * 32);
      asm volatile("s_waitcnt vmcnt(3)" ::: "memory");  // own stage(t) landed; stage(t+1) in flight
    } else {
      asm volatile("s_waitcnt vmcnt(0)" ::: "memory");
    }
    __builtin_amdgcn_s_barrier();
    bf16x8 af[4], bfr[4];
#pragma unroll
    for (int i = 0; i < 4; ++i) af[i] = *(const bf16x8*)(As[cur] + aro + i * 16 * 32);
#pragma unroll
    for (int j = 0; j < 4; ++j) bfr[j] = *(const bf16x8*)(Bs[cur] + bro + j * 16 * 32);
    __builtin_amdgcn_s_setprio(1);
#pragma unroll
    for (int i = 0; i < 4; ++i)
#pragma unroll
      for (int j = 0; j < 4; ++j)
        acc[i][j] = mfma16(af[i], bfr[j], acc[i][j]);
    __builtin_amdgcn_s_setprio(0);
    __builtin_amdgcn_s_barrier();
  }
#undef STAGE_AB
  const int rg = (lane >> 4) * 4, cl = lane & 15;
#pragma unroll
  for (int i = 0; i < 4; ++i) {
#pragma unroll
    for (int j = 0; j < 4; ++j) {
      const long row = m0 + wm * 64 + i * 16 + rg;
      const long col = n0 + wn * 64 + j * 16 + cl;
      const float bv = bias ? bias[col] : 0.0f;
      if (EPI == 4) {
        const int hh = (int)col / 192, off = (int)col - hh * 192;
        if (off < 128) {
#pragma unroll
          for (int r = 0; r < 4; ++r)
            Cb[(row + r) * ldc + col] = f2bf(acc[i][j][r] + bv);
        } else {
          us4 pk;
#pragma unroll
          for (int r = 0; r < 4; ++r) pk[r] = f2bf(acc[i][j][r] + bv);
          const long bl = row >> 10, t0 = row & 1023;
          *(us4*)(Vt + (((bl * 8 + hh) * 64 + (off - 128)) << 10) + t0) = pk;
        }
      } else {
#pragma unroll
        for (int r = 0; r < 4; ++r) {
          float v = acc[i][j][r] + bv;
          long idx = (row + r) * ldc + col;
          if (EPI == 0) Cf[idx] = v;
          else if (EPI == 1) Cb[idx] = f2bf(v);
          else if (EPI == 2) Cf[idx] += v;
          else Cb[idx] = f2bf(gelu_f(v));
        }
      }
    }
  }
}

// ---------------- flash attention: 8 waves, QBLK=128, swapped QK^T, dbuf K/V ----------------
// LDS 48KB (P overlaid on each wave's own Q rows) -> 3 blocks/CU, 24 waves/CU.
__global__ __launch_bounds__(512)
void attn_k(const u16* __restrict__ qkv, const u16* __restrict__ vt, u16* __restrict__ o)
{
  __shared__ __align__(16) u16 Qs[128 * 64];     // wave w's rows [w*16,w*16+16) reused as P
  __shared__ __align__(16) u16 Ks[2][64 * 64];
  __shared__ __align__(16) u16 Vts[2][64 * 64];  // [ch][key], key-chunks swizzled by swz(ch)
  const int tid = threadIdx.x, lane = tid & 63, wid = tid >> 6;
  const int qt = blockIdx.x, hh = blockIdx.y, b = blockIdx.z;
  const long rowbase = (long)b * 1024;
  const long vbase = (((long)b * 8 + hh) * 64) * 1024;
  const int g = lane >> 4, cl = lane & 15;
  u16* Psw = Qs + wid * 1024;                    // per-wave 16x64 P scratch

  // Q stage: 128 rows, LDS linear, global source column pre-swizzled (2 loads/thread)
#pragma unroll
  for (int it = 0; it < 2; ++it) {
    int c = tid + it * 512;
    int row = c >> 3, c8s = (c & 7) ^ swz(row);
    gl2lds16(qkv + (rowbase + qt * 128 + row) * 1536 + hh * 192 + c8s * 8, Qs + c * 8);
  }
  // K/V stage for tile kt into buf (2 loads/thread)
#define STAGE_KV(buf, kt_)                                                            \
  {                                                                                   \
    int row = tid >> 3, c8s = (tid & 7) ^ swz(row);                                   \
    gl2lds16(qkv + (rowbase + (kt_) * 64 + row) * 1536 + hh * 192 + 64 + c8s * 8,     \
             Ks[buf] + tid * 8);                                                      \
    gl2lds16(vt + vbase + (long)row * 1024 + (kt_) * 64 + c8s * 8, Vts[buf] + tid * 8); \
  }
  STAGE_KV(0, 0);

  float m = -3.0e38f, l = 0.f;
  f32x4 oacc[4] = {};
  const int Rq = wid * 16 + cl, sq = swz(Rq) << 3;  // Q fragment row / swizzle
  const int spw = swz(cl) << 3;                      // P row (= q = cl) swizzle
  bf16x8 aq[2];

  for (int kt = 0; kt < 16; ++kt) {
    const int cur = kt & 1;
    if (kt < 15) {
      STAGE_KV(cur ^ 1, kt + 1);
      asm volatile("s_waitcnt vmcnt(2)" ::: "memory");  // Q+stage(kt) landed; stage(kt+1) in flight
    } else {
      asm volatile("s_waitcnt vmcnt(0)" ::: "memory");
    }
    __builtin_amdgcn_s_barrier();                       // all waves' stage(kt) landed
    if (kt == 0) {
#pragma unroll
      for (int kb = 0; kb < 2; ++kb)
        aq[kb] = *(const bf16x8*)(Qs + Rq * 64 + ((kb * 32 + g * 8) ^ sq));
    }
    // QK^T swapped: s[j] = S^T[k = j*16 + g*4 + r][q = cl]
    f32x4 s[4] = {};
    __builtin_amdgcn_s_setprio(1);
#pragma unroll
    for (int j = 0; j < 4; ++j) {
      const int Rk = j * 16 + cl, sk = swz(Rk) << 3;
#pragma unroll
      for (int kb = 0; kb < 2; ++kb) {
        bf16x8 bk = *(const bf16x8*)(Ks[cur] + Rk * 64 + ((kb * 32 + g * 8) ^ sk));
        s[j] = mfma16(bk, aq[kb], s[j]);
      }
    }
    __builtin_amdgcn_s_setprio(0);
    // lane-local softmax for q = cl over 16 k-values (+2-step cross-g reduce)
    float mx = s[0][0];
#pragma unroll
    for (int j = 0; j < 4; ++j)
#pragma unroll
      for (int r = 0; r < 4; ++r) mx = fmaxf(mx, s[j][r]);
    mx *= 0.125f;
    mx = fmaxf(mx, __shfl_xor(mx, 16, 64));
    mx = fmaxf(mx, __shfl_xor(mx, 32, 64));
    // defer-max (T13): rescale only when some row's max grew past THR=8
    if (!__all(mx <= m + 8.f)) {
      const float mnew = fmaxf(m, mx);
      const float al = __expf(m - mnew);
      m = mnew;
      l *= al;
      float alr[4];
#pragma unroll
      for (int r = 0; r < 4; ++r) alr[r] = __shfl(al, (lane & 48) | (g * 4 + r), 64);
#pragma unroll
      for (int cb = 0; cb < 4; ++cb) {
        f32x4 t = oacc[cb];
        t[0] *= alr[0]; t[1] *= alr[1]; t[2] *= alr[2]; t[3] *= alr[3];
        oacc[cb] = t;
      }
    }
    float p[4][4], ts = 0.f;
#pragma unroll
    for (int j = 0; j < 4; ++j)
#pragma unroll
      for (int r = 0; r < 4; ++r) {
        p[j][r] = __expf(s[j][r] * 0.125f - m);
        ts += p[j][r];
      }
    ts += __shfl_xor(ts, 16, 64);
    ts += __shfl_xor(ts, 32, 64);
    l += ts;
    // P store: 4x ds_write_b64; physical(k) = k ^ spw (spw mult of 8, base mult of 4)
#pragma unroll
    for (int j = 0; j < 4; ++j) {
      us4 pk;
      pk[0] = f2bf(p[j][0]); pk[1] = f2bf(p[j][1]);
      pk[2] = f2bf(p[j][2]); pk[3] = f2bf(p[j][3]);
      *(us4*)(&Psw[cl * 64 + ((j * 16 + g * 4) ^ spw)]) = pk;
    }
    asm volatile("s_waitcnt lgkmcnt(0)" ::: "memory");  // within-wave P write->read ordering
    bf16x8 pa[2];
#pragma unroll
    for (int kb = 0; kb < 2; ++kb)
      pa[kb] = *(const bf16x8*)(&Psw[cl * 64 + ((kb * 32 + g * 8) ^ spw)]);
    __builtin_amdgcn_s_setprio(1);
#pragma unroll
    for (int kb = 0; kb < 2; ++kb)
#pragma unroll
      for (int cb = 0; cb < 4; ++cb) {
        const int ch = cb * 16 + cl;
        bf16x8 vb = *(const bf16x8*)(Vts[cur] + ch * 64 + ((kb * 32 + g * 8) ^ (swz(ch) << 3)));
        oacc[cb] = mfma16(pa[kb], vb, oacc[cb]);
      }
    __builtin_amdgcn_s_setprio(0);
    __builtin_amdgcn_s_barrier();                       // compute(kt) done; next STAGE may overwrite
  }
#undef STAGE_KV
  // final l for oacc rows q = g*4+r
  float lr[4];
#pragma unroll
  for (int r = 0; r < 4; ++r) lr[r] = __shfl(l, (lane & 48) | (g * 4 + r), 64);
#pragma unroll
  for (int cb = 0; cb < 4; ++cb)
#pragma unroll
    for (int r = 0; r < 4; ++r) {
      long row = rowbase + qt * 128 + wid * 16 + g * 4 + r;
      o[row * 512 + hh * 64 + cb * 16 + cl] = f2bf(oacc[cb][r] / lr[r]);
    }
}

// ---------------- LayerNorm, one wave per 512-row. MODE 0: f32->f32, 1: f32->bf16
template <int MODE>
__global__ __launch_bounds__(256)
void ln_k(const float* __restrict__ in_, const float* __restrict__ gg,
          const float* __restrict__ bb, void* __restrict__ out_)
{
  const long row = (long)blockIdx.x * 4 + (threadIdx.x >> 6);
  const int lane = threadIdx.x & 63;
  float x[8];
  const float* p = in_ + row * 512 + lane * 8;
  *(float4*)(x) = *(const float4*)(p);
  *(float4*)(x + 4) = *(const float4*)(p + 4);
  float s = 0.f;
#pragma unroll
  for (int j = 0; j < 8; ++j) s += x[j];
#pragma unroll
  for (int off = 1; off < 64; off <<= 1) s += __shfl_xor(s, off, 64);
  const float mean = s * (1.0f / 512.0f);
  float vs = 0.f;
#pragma unroll
  for (int j = 0; j < 8; ++j) { float d = x[j] - mean; vs += d * d; }
#pragma unroll
  for (int off = 1; off < 64; off <<= 1) vs += __shfl_xor(vs, off, 64);
  const float rstd = rsqrtf(vs * (1.0f / 512.0f) + 1e-5f);
  if (MODE == 0) {
    float y[8];
#pragma unroll
    for (int j = 0; j < 8; ++j)
      y[j] = (x[j] - mean) * rstd * gg[lane * 8 + j] + bb[lane * 8 + j];
    float* q = (float*)out_ + row * 512 + lane * 8;
    *(float4*)(q) = *(const float4*)(y);
    *(float4*)(q + 4) = *(const float4*)(y + 4);
  } else {
    us8 ov;
#pragma unroll
    for (int j = 0; j < 8; ++j)
      ov[j] = f2bf((x[j] - mean) * rstd * gg[lane * 8 + j] + bb[lane * 8 + j]);
    *(us8*)((u16*)out_ + row * 512 + lane * 8) = ov;
  }
}

// ---------------- input embed: h = E[t] + sum_9 scalars*w_in rows + b_in (fp32) ----------------
__global__ __launch_bounds__(256)
void embed_k(const float* __restrict__ x, const float* __restrict__ par,
             const float* __restrict__ E, const float* __restrict__ w_in,
             const float* __restrict__ b_in, float* __restrict__ h)
{
  const long bt = blockIdx.x;
  const int b = (int)(bt >> 10), t = (int)(bt & 1023);
  float xs[9];
#pragma unroll
  for (int c = 0; c < 3; ++c) xs[c] = x[((long)b * 3 + c) * 1024 + t];
#pragma unroll
  for (int c = 0; c < 6; ++c) xs[3 + c] = par[((long)b * 6 + c) * 1024 + t];
  for (int w = threadIdx.x; w < 512; w += 256) {
    float a = E[(long)t * 512 + w] + b_in[w];
#pragma unroll
    for (int c = 0; c < 9; ++c) a += xs[c] * w_in[c * 512 + w];
    h[bt * 512 + w] = a;
  }
}

// ---------------- fp32 -> bf16 transpose [R,C] -> [C,R] ----------------
__global__ __launch_bounds__(256)
void tr_k(const float* __restrict__ in, u16* __restrict__ out, int R, int C)
{
  __shared__ u16 tile[32][33];
  const int r0 = blockIdx.y * 32, c0 = blockIdx.x * 32;
  const int tx = threadIdx.x & 31, ty = threadIdx.x >> 5;
  for (int rr = ty; rr < 32; rr += 8) tile[rr][tx] = f2bf(in[(long)(r0 + rr) * C + c0 + tx]);
  __syncthreads();
  for (int rr = ty; rr < 32; rr += 8) out[(long)(c0 + rr) * R + r0 + tx] = tile[tx][rr];
}

// ---------------- fp32 -> bf16 cast ----------------
__global__ __launch_bounds__(256)
void cast_k(const float* __restrict__ in, u16* __restrict__ out, long n)
{
  long i = ((long)blockIdx.x * 256 + threadIdx.x) * 4;
  if (i + 3 < n) {
    float4 v = *(const float4*)(in + i);
    out[i] = f2bf(v.x); out[i + 1] = f2bf(v.y); out[i + 2] = f2bf(v.z); out[i + 3] = f2bf(v.w);
  }
}

// ---------------- masked max-pool, stage 1: coalesced per-(b, t-chunk) partial max ----------------
__global__ __launch_bounds__(256)
void pool1_k(const float* __restrict__ hm, const float* __restrict__ mask, float* __restrict__ part)
{
  const int c = blockIdx.x, b = blockIdx.y;
  const int t0 = c * 128;
  const int w0 = threadIdx.x, w1 = threadIdx.x + 256;
  float m0 = -3.0e38f, m1 = -3.0e38f;
  for (int t = 0; t < 128; ++t) {
    const float mv = mask[b * 1024 + t0 + t];
    const float neg = (1.0f - mv) * (-100000.0f);
    const float* row = hm + ((long)b * 1024 + t0 + t) * 512;
    m0 = fmaxf(m0, row[w0] * mv + neg);
    m1 = fmaxf(m1, row[w1] * mv + neg);
  }
  part[((long)b * 8 + c) * 512 + w0] = m0;
  part[((long)b * 8 + c) * 512 + w1] = m1;
}
// ---------------- stage 2: combine 8 chunks ----------------
__global__ __launch_bounds__(256)
void pool2_k(const float* __restrict__ part, float* __restrict__ pooled)
{
  const int b = blockIdx.y;
  const int w = blockIdx.x * 256 + threadIdx.x;
  float m = -3.0e38f;
#pragma unroll
  for (int c = 0; c < 8; ++c) m = fmaxf(m, part[((long)b * 8 + c) * 512 + w]);
  pooled[b * 512 + w] = m;
}

// ---------------- masked transpose to output h [B,512,T] fp32 ----------------
__global__ __launch_bounds__(256)
void tout_k(const float* __restrict__ hm, const float* __restrict__ mask, float* __restrict__ outh)
{
  __shared__ float tile[64][65];
  const int t0 = blockIdx.x * 64, w0 = blockIdx.y * 64, b = blockIdx.z;
  const int tx = threadIdx.x & 63, ty = threadIdx.x >> 6;
  for (int i = ty; i < 64; i += 4)
    tile[i][tx] = hm[((long)b * 1024 + t0 + i) * 512 + w0 + tx];
  __syncthreads();
  const float mv = mask[b * 1024 + t0 + tx];
  for (int i = ty; i < 64; i += 4)
    outh[((long)b * 512 + w0 + i) * 1024 + t0 + tx] = tile[tx][i] * mv;
}

// ---------------- tiny aggregator matmuls (fp32 weights) ----------------
__global__ __launch_bounds__(256)
void agg1_k(const float* __restrict__ pooled, const float* __restrict__ wf,
            const float* __restrict__ bf_, float* __restrict__ z1)
{
  const int b = blockIdx.y;
  const int n = blockIdx.x * 256 + threadIdx.x;
  float acc = 0.f;
  for (int k = 0; k < 512; ++k) acc += pooled[b * 512 + k] * wf[(long)k * 2048 + n];
  z1[(long)b * 2048 + n] = gelu_f(acc + bf_[n]);
}
__global__ __launch_bounds__(256)
void agg2_k(const float* __restrict__ z1, const float* __restrict__ wp,
            const float* __restrict__ bp, float* __restrict__ zo)
{
  const int b = blockIdx.y;
  const int n = blockIdx.x * 256 + threadIdx.x;
  float acc = 0.f;
  for (int k = 0; k < 2048; ++k) acc += z1[(long)b * 2048 + k] * wp[(long)k * 512 + n];
  zo[b * 512 + n] = acc + bp[n];
}

extern "C" void kernel_launch(void* const* d_in, const int* in_sizes, int n_in,
                              void* d_out, int out_size, void* d_ws, size_t ws_size,
                              hipStream_t stream)
{
  (void)in_sizes; (void)n_in; (void)out_size; (void)ws_size;
  const float* x        = (const float*)d_in[0];
  const float* params   = (const float*)d_in[1];
  const float* mask     = (const float*)d_in[2];
  const float* class_emb= (const float*)d_in[3];
  const float* w_in     = (const float*)d_in[4];
  const float* b_in     = (const float*)d_in[5];
  const float* ln_pre_g = (const float*)d_in[6];
  const float* ln_pre_b = (const float*)d_in[7];
  const float* qkv_w    = (const float*)d_in[8];
  const float* qkv_b    = (const float*)d_in[9];
  const float* attn_pw  = (const float*)d_in[10];
  const float* attn_pb  = (const float*)d_in[11];
  const float* ln1_g    = (const float*)d_in[12];
  const float* ln1_b    = (const float*)d_in[13];
  const float* fc_w     = (const float*)d_in[14];
  const float* fc_b     = (const float*)d_in[15];
  const float* fcp_w    = (const float*)d_in[16];
  const float* fcp_b    = (const float*)d_in[17];
  const float* ln2_g    = (const float*)d_in[18];
  const float* ln2_b    = (const float*)d_in[19];
  const float* ln_post_g= (const float*)d_in[20];
  const float* ln_post_b= (const float*)d_in[21];
  const float* w_out    = (const float*)d_in[22];
  const float* b_out    = (const float*)d_in[23];
  const float* agg_fc_w = (const float*)d_in[24];
  const float* agg_fc_b = (const float*)d_in[25];
  const float* agg_pw   = (const float*)d_in[26];
  const float* agg_pb   = (const float*)d_in[27];

  float* out_f = (float*)d_out;          // z: [0, 16384)
  float* out_h = out_f + 16384;          // h: 64 MiB fp32 region
  u16* sc = (u16*)out_h;                 // bf16 scratch: up to 16384x2048 (64 MiB)

  // ---- workspace layout (~125 MiB) ----
  char* ws = (char*)d_ws;
  float* hf = (float*)ws;       ws += (size_t)32768 * 512 * 4;   // residual fp32 (64 MiB)
  u16* hn = (u16*)ws;           ws += (size_t)32768 * 512 * 2;   // LN / attn-out bf16 (32 MiB)
  float* E = (float*)ws;        ws += (size_t)1024 * 512 * 4;    // class-emb proj (2 MiB)
  u16* ce_b = (u16*)ws;         ws += (size_t)1024 * 1024 * 2;   // class_emb bf16 (2 MiB)
  u16* wt_qkv = (u16*)ws;       ws += (size_t)1536 * 512 * 2;    // per-layer transposes (6.3 MiB)
  u16* wt_pw  = (u16*)ws;       ws += (size_t)512 * 512 * 2;
  u16* wt_fc  = (u16*)ws;       ws += (size_t)2048 * 512 * 2;
  u16* wt_fcp = (u16*)ws;       ws += (size_t)512 * 2048 * 2;
  u16* w_in_t = (u16*)ws;       ws += (size_t)512 * 1024 * 2;
  u16* w_out_t= (u16*)ws;       ws += (size_t)512 * 512 * 2;
  float* pooled = (float*)ws;   ws += (size_t)32 * 512 * 4;
  float* z1     = (float*)ws;   ws += (size_t)32 * 2048 * 4;
  float* part   = (float*)ws;   ws += (size_t)32 * 8 * 512 * 4;  // pool partials (0.5 MiB)
  u16* vt       = (u16*)ws;     ws += (size_t)16 * 8 * 64 * 1024 * 2;  // V^T per half (16 MiB)

  // one-time converts + class-emb projection + embed + ln_pre
  cast_k<<<1024, 256, 0, stream>>>(class_emb, ce_b, 1024 * 1024);
  tr_k<<<dim3(16, 32), 256, 0, stream>>>(w_in + 9 * 512, w_in_t, 1024, 512);
  tr_k<<<dim3(16, 16), 256, 0, stream>>>(w_out, w_out_t, 512, 512);
  gemm_bt<0><<<dim3(4, 4), 512, 0, stream>>>(ce_b, w_in_t, nullptr, E, nullptr, nullptr,
                                             1024, 1024, 1024, 512);
  embed_k<<<32768, 256, 0, stream>>>(x, params, E, w_in, b_in, hf);
  ln_k<0><<<8192, 256, 0, stream>>>(hf, ln_pre_g, ln_pre_b, hf);

  for (int l = 0; l < 12; ++l) {
    tr_k<<<dim3(48, 16), 256, 0, stream>>>(qkv_w + (size_t)l * 512 * 1536, wt_qkv, 512, 1536);
    tr_k<<<dim3(16, 16), 256, 0, stream>>>(attn_pw + (size_t)l * 512 * 512, wt_pw, 512, 512);
    tr_k<<<dim3(64, 16), 256, 0, stream>>>(fc_w + (size_t)l * 512 * 2048, wt_fc, 512, 2048);
    tr_k<<<dim3(16, 64), 256, 0, stream>>>(fcp_w + (size_t)l * 2048 * 512, wt_fcp, 2048, 512);

    // LN1 full batch -> hn (bf16)
    ln_k<1><<<8192, 256, 0, stream>>>(hf, ln1_g + l * 512, ln1_b + l * 512, hn);
    // QKV (V written transposed to vt) + attention per batch-half; attn-out overwrites hn half
    for (int half = 0; half < 2; ++half) {
      const size_t ro = (size_t)half * 16384;
      gemm_bt<4><<<dim3(12, 64), 512, 0, stream>>>(hn + ro * 512, wt_qkv, qkv_b + l * 1536,
                                                   nullptr, sc, vt, 512, 512, 512, 1536);
      attn_k<<<dim3(8, 8, 16), 512, 0, stream>>>(sc, vt, hn + ro * 512);
    }
    // attn projection full batch: h += hn @ pw^T + b
    gemm_bt<2><<<dim3(4, 128), 512, 0, stream>>>(hn, wt_pw, attn_pb + l * 512,
                                                 hf, nullptr, nullptr, 512, 512, 512, 512);
    // LN2 full batch -> hn
    ln_k<1><<<8192, 256, 0, stream>>>(hf, ln2_g + l * 512, ln2_b + l * 512, hn);
    // FF per batch-half: mid [16384x2048] bf16 in sc (64 MiB)
    for (int half = 0; half < 2; ++half) {
      const size_t ro = (size_t)half * 16384;
      gemm_bt<3><<<dim3(16, 64), 512, 0, stream>>>(hn + ro * 512, wt_fc, fc_b + l * 2048,
                                                   nullptr, sc, nullptr, 512, 512, 512, 2048);
      gemm_bt<2><<<dim3(4, 64), 512, 0, stream>>>(sc, wt_fcp, fcp_b + l * 512,
                                                  hf + ro * 512, nullptr, nullptr, 2048, 2048, 2048, 512);
    }
  }

  // final LN + out-proj (residual becomes final h), then pool/agg, then h output
  ln_k<1><<<8192, 256, 0, stream>>>(hf, ln_post_g, ln_post_b, hn);
  gemm_bt<0><<<dim3(4, 128), 512, 0, stream>>>(hn, w_out_t, b_out, hf, nullptr, nullptr,
                                               512, 512, 512, 512);
  pool1_k<<<dim3(8, 32), 256, 0, stream>>>(hf, mask, part);
  pool2_k<<<dim3(2, 32), 256, 0, stream>>>(part, pooled);
  agg1_k<<<dim3(8, 32), 256, 0, stream>>>(pooled, agg_fc_w, agg_fc_b, z1);
  agg2_k<<<dim3(2, 32), 256, 0, stream>>>(z1, agg_pw, agg_pb, out_f);
  tout_k<<<dim3(16, 8, 32), 256, 0, stream>>>(hf, mask, out_h);
}

// Round 14
// 6724.056 us; speedup vs baseline: 2.0500x; 1.0899x over previous
//
#include <hip/hip_runtime.h>
#include <hip/hip_bf16.h>

// PartCodeTransformer forward on MI355X (gfx950).
// I/O fp32; internal bf16 MFMA + fp32 accum/residual.
// Round 14: T1 XCD-aware chunked block swizzle on gemm_bt and attn_k (co-locate blocks
// sharing operand panels on one XCD's L2; cuts A/KV re-fetch). GEMM 256x128 8-wave
// 2-phase dbuf; attn 8-wave QBLK=128 swapped-QK^T dbuf; all prior techniques retained.

typedef unsigned short u16;
typedef unsigned int u32;
typedef __attribute__((ext_vector_type(8))) short bf16x8;
typedef __attribute__((ext_vector_type(8))) unsigned short us8;
typedef __attribute__((ext_vector_type(4))) unsigned short us4;
typedef __attribute__((ext_vector_type(4))) float f32x4;

__device__ __forceinline__ float bf2f(u16 s) {
  union { u32 u; float f; } c; c.u = ((u32)s) << 16; return c.f;
}
__device__ __forceinline__ u16 f2bf(float f) {
  __hip_bfloat16 h = __float2bfloat16(f);   // hardware RNE cvt
  union { __hip_bfloat16 h; u16 u; } c; c.h = h; return c.u;
}
__device__ __forceinline__ float gelu_f(float v) {
  return 0.5f * v * (1.0f + erff(v * 0.7071067811865475f));
}
__device__ __forceinline__ void gl2lds16(const u16* g, u16* l) {
  __builtin_amdgcn_global_load_lds((const __attribute__((address_space(1))) void*)g,
                                   (__attribute__((address_space(3))) void*)l, 16, 0, 0);
}
__device__ __forceinline__ f32x4 mfma16(bf16x8 a, bf16x8 b, f32x4 c) {
  return __builtin_amdgcn_mfma_f32_16x16x32_bf16(a, b, c, 0, 0, 0);
}
// chunk swizzle: permute 16B chunks within a 128B row; valid for any row index
__device__ __forceinline__ int swz(int row) { return (row ^ (row >> 3)) & 7; }

// ------------- A[M,K](lda) x Bt[N,K](ldb) GEMM, 256x128 tile, 8 waves, 2-phase dbuf -------------
// EPI: 0 f32=v ; 1 bf16=v ; 2 f32+=v ; 3 bf16=gelu(v) ; 4 qkv: Q/K->Cb, V->Vt transposed
// XCD chunked swizzle: requires gridDim.x*gridDim.y % 8 == 0 (all call sites satisfy).
template <int EPI>
__global__ __launch_bounds__(512)
void gemm_bt(const u16* __restrict__ A, const u16* __restrict__ Bt,
             const float* __restrict__ bias, float* __restrict__ Cf,
             u16* __restrict__ Cb, u16* __restrict__ Vt, int K, int lda, int ldb, int ldc)
{
  __shared__ __align__(16) u16 As[2][256 * 32];   // 32 KB
  __shared__ __align__(16) u16 Bs[2][128 * 32];   // 16 KB
  const int tid = threadIdx.x;
  const int lane = tid & 63, wid = tid >> 6;
  const int wm = wid & 3, wn = wid >> 2;          // 4 M-waves x 2 N-waves, 64x64 each
  // T1: chunked XCD swizzle — each XCD gets a contiguous logical range (N fastest)
  const int nbx = gridDim.x;
  const int nwg = nbx * gridDim.y;
  int lin = blockIdx.y * nbx + blockIdx.x;
  lin = (lin & 7) * (nwg >> 3) + (lin >> 3);
  const long m0 = (long)(lin / nbx) * 256, n0 = (long)(lin % nbx) * 128;

  const int c0 = tid, c1 = tid + 512;
  const u16* aS0 = A + (m0 + (c0 >> 2)) * (long)lda + (c0 & 3) * 8;
  const u16* aS1 = A + (m0 + (c1 >> 2)) * (long)lda + (c1 & 3) * 8;
  const u16* bS0 = Bt + (n0 + (tid >> 2)) * (long)ldb + (tid & 3) * 8;

  f32x4 acc[4][4] = {};
  const int aro = (wm * 64 + (lane & 15)) * 32 + (lane >> 4) * 8;
  const int bro = (wn * 64 + (lane & 15)) * 32 + (lane >> 4) * 8;
  const int nt = K >> 5;

#define STAGE_AB(buf, k0_)                          \
  gl2lds16(aS0 + (k0_), As[buf] + c0 * 8);          \
  gl2lds16(aS1 + (k0_), As[buf] + c1 * 8);          \
  gl2lds16(bS0 + (k0_), Bs[buf] + tid * 8);

  STAGE_AB(0, 0);
  for (int t = 0; t < nt; ++t) {
    const int cur = t & 1;
    if (t < nt - 1) {
      STAGE_AB(cur ^ 1, (t + 1) * 32);
      asm volatile("s_waitcnt vmcnt(3)" ::: "memory");  // own stage(t) landed; stage(t+1) in flight
    } else {
      asm volatile("s_waitcnt vmcnt(0)" ::: "memory");
    }
    __builtin_amdgcn_s_barrier();
    bf16x8 af[4], bfr[4];
#pragma unroll
    for (int i = 0; i < 4; ++i) af[i] = *(const bf16x8*)(As[cur] + aro + i * 16 * 32);
#pragma unroll
    for (int j = 0; j < 4; ++j) bfr[j] = *(const bf16x8*)(Bs[cur] + bro + j * 16 * 32);
    __builtin_amdgcn_s_setprio(1);
#pragma unroll
    for (int i = 0; i < 4; ++i)
#pragma unroll
      for (int j = 0; j < 4; ++j)
        acc[i][j] = mfma16(af[i], bfr[j], acc[i][j]);
    __builtin_amdgcn_s_setprio(0);
    __builtin_amdgcn_s_barrier();
  }
#undef STAGE_AB
  const int rg = (lane >> 4) * 4, cl = lane & 15;
#pragma unroll
  for (int i = 0; i < 4; ++i) {
#pragma unroll
    for (int j = 0; j < 4; ++j) {
      const long row = m0 + wm * 64 + i * 16 + rg;
      const long col = n0 + wn * 64 + j * 16 + cl;
      const float bv = bias ? bias[col] : 0.0f;
      if (EPI == 4) {
        const int hh = (int)col / 192, off = (int)col - hh * 192;
        if (off < 128) {
#pragma unroll
          for (int r = 0; r < 4; ++r)
            Cb[(row + r) * ldc + col] = f2bf(acc[i][j][r] + bv);
        } else {
          us4 pk;
#pragma unroll
          for (int r = 0; r < 4; ++r) pk[r] = f2bf(acc[i][j][r] + bv);
          const long bl = row >> 10, t0 = row & 1023;
          *(us4*)(Vt + (((bl * 8 + hh) * 64 + (off - 128)) << 10) + t0) = pk;
        }
      } else {
#pragma unroll
        for (int r = 0; r < 4; ++r) {
          float v = acc[i][j][r] + bv;
          long idx = (row + r) * ldc + col;
          if (EPI == 0) Cf[idx] = v;
          else if (EPI == 1) Cb[idx] = f2bf(v);
          else if (EPI == 2) Cf[idx] += v;
          else Cb[idx] = f2bf(gelu_f(v));
        }
      }
    }
  }
}

// ---------------- flash attention: 8 waves, QBLK=128, swapped QK^T, dbuf K/V ----------------
// 1-D grid 1024 blocks = (qt 8) x (hh 8) x (b 16), chunked XCD swizzle (qt fastest).
// LDS 48KB (P overlaid on each wave's own Q rows) -> 3 blocks/CU, 24 waves/CU.
__global__ __launch_bounds__(512)
void attn_k(const u16* __restrict__ qkv, const u16* __restrict__ vt, u16* __restrict__ o)
{
  __shared__ __align__(16) u16 Qs[128 * 64];     // wave w's rows [w*16,w*16+16) reused as P
  __shared__ __align__(16) u16 Ks[2][64 * 64];
  __shared__ __align__(16) u16 Vts[2][64 * 64];  // [ch][key], key-chunks swizzled by swz(ch)
  const int tid = threadIdx.x, lane = tid & 63, wid = tid >> 6;
  int lin = blockIdx.x;
  lin = (lin & 7) * 128 + (lin >> 3);            // T1 chunked swizzle (1024 blocks)
  const int qt = lin & 7, hh = (lin >> 3) & 7, b = lin >> 6;
  const long rowbase = (long)b * 1024;
  const long vbase = (((long)b * 8 + hh) * 64) * 1024;
  const int g = lane >> 4, cl = lane & 15;
  u16* Psw = Qs + wid * 1024;                    // per-wave 16x64 P scratch

  // Q stage: 128 rows, LDS linear, global source column pre-swizzled (2 loads/thread)
#pragma unroll
  for (int it = 0; it < 2; ++it) {
    int c = tid + it * 512;
    int row = c >> 3, c8s = (c & 7) ^ swz(row);
    gl2lds16(qkv + (rowbase + qt * 128 + row) * 1536 + hh * 192 + c8s * 8, Qs + c * 8);
  }
  // K/V stage for tile kt into buf (2 loads/thread)
#define STAGE_KV(buf, kt_)                                                            \
  {                                                                                   \
    int row = tid >> 3, c8s = (tid & 7) ^ swz(row);                                   \
    gl2lds16(qkv + (rowbase + (kt_) * 64 + row) * 1536 + hh * 192 + 64 + c8s * 8,     \
             Ks[buf] + tid * 8);                                                      \
    gl2lds16(vt + vbase + (long)row * 1024 + (kt_) * 64 + c8s * 8, Vts[buf] + tid * 8); \
  }
  STAGE_KV(0, 0);

  float m = -3.0e38f, l = 0.f;
  f32x4 oacc[4] = {};
  const int Rq = wid * 16 + cl, sq = swz(Rq) << 3;  // Q fragment row / swizzle
  const int spw = swz(cl) << 3;                      // P row (= q = cl) swizzle
  bf16x8 aq[2];

  for (int kt = 0; kt < 16; ++kt) {
    const int cur = kt & 1;
    if (kt < 15) {
      STAGE_KV(cur ^ 1, kt + 1);
      asm volatile("s_waitcnt vmcnt(2)" ::: "memory");  // Q+stage(kt) landed; stage(kt+1) in flight
    } else {
      asm volatile("s_waitcnt vmcnt(0)" ::: "memory");
    }
    __builtin_amdgcn_s_barrier();                       // all waves' stage(kt) landed
    if (kt == 0) {
#pragma unroll
      for (int kb = 0; kb < 2; ++kb)
        aq[kb] = *(const bf16x8*)(Qs + Rq * 64 + ((kb * 32 + g * 8) ^ sq));
    }
    // QK^T swapped: s[j] = S^T[k = j*16 + g*4 + r][q = cl]
    f32x4 s[4] = {};
    __builtin_amdgcn_s_setprio(1);
#pragma unroll
    for (int j = 0; j < 4; ++j) {
      const int Rk = j * 16 + cl, sk = swz(Rk) << 3;
#pragma unroll
      for (int kb = 0; kb < 2; ++kb) {
        bf16x8 bk = *(const bf16x8*)(Ks[cur] + Rk * 64 + ((kb * 32 + g * 8) ^ sk));
        s[j] = mfma16(bk, aq[kb], s[j]);
      }
    }
    __builtin_amdgcn_s_setprio(0);
    // lane-local softmax for q = cl over 16 k-values (+2-step cross-g reduce)
    float mx = s[0][0];
#pragma unroll
    for (int j = 0; j < 4; ++j)
#pragma unroll
      for (int r = 0; r < 4; ++r) mx = fmaxf(mx, s[j][r]);
    mx *= 0.125f;
    mx = fmaxf(mx, __shfl_xor(mx, 16, 64));
    mx = fmaxf(mx, __shfl_xor(mx, 32, 64));
    // defer-max (T13): rescale only when some row's max grew past THR=8
    if (!__all(mx <= m + 8.f)) {
      const float mnew = fmaxf(m, mx);
      const float al = __expf(m - mnew);
      m = mnew;
      l *= al;
      float alr[4];
#pragma unroll
      for (int r = 0; r < 4; ++r) alr[r] = __shfl(al, (lane & 48) | (g * 4 + r), 64);
#pragma unroll
      for (int cb = 0; cb < 4; ++cb) {
        f32x4 t = oacc[cb];
        t[0] *= alr[0]; t[1] *= alr[1]; t[2] *= alr[2]; t[3] *= alr[3];
        oacc[cb] = t;
      }
    }
    float p[4][4], ts = 0.f;
#pragma unroll
    for (int j = 0; j < 4; ++j)
#pragma unroll
      for (int r = 0; r < 4; ++r) {
        p[j][r] = __expf(s[j][r] * 0.125f - m);
        ts += p[j][r];
      }
    ts += __shfl_xor(ts, 16, 64);
    ts += __shfl_xor(ts, 32, 64);
    l += ts;
    // P store: 4x ds_write_b64; physical(k) = k ^ spw (spw mult of 8, base mult of 4)
#pragma unroll
    for (int j = 0; j < 4; ++j) {
      us4 pk;
      pk[0] = f2bf(p[j][0]); pk[1] = f2bf(p[j][1]);
      pk[2] = f2bf(p[j][2]); pk[3] = f2bf(p[j][3]);
      *(us4*)(&Psw[cl * 64 + ((j * 16 + g * 4) ^ spw)]) = pk;
    }
    asm volatile("s_waitcnt lgkmcnt(0)" ::: "memory");  // within-wave P write->read ordering
    bf16x8 pa[2];
#pragma unroll
    for (int kb = 0; kb < 2; ++kb)
      pa[kb] = *(const bf16x8*)(&Psw[cl * 64 + ((kb * 32 + g * 8) ^ spw)]);
    __builtin_amdgcn_s_setprio(1);
#pragma unroll
    for (int kb = 0; kb < 2; ++kb)
#pragma unroll
      for (int cb = 0; cb < 4; ++cb) {
        const int ch = cb * 16 + cl;
        bf16x8 vb = *(const bf16x8*)(Vts[cur] + ch * 64 + ((kb * 32 + g * 8) ^ (swz(ch) << 3)));
        oacc[cb] = mfma16(pa[kb], vb, oacc[cb]);
      }
    __builtin_amdgcn_s_setprio(0);
    __builtin_amdgcn_s_barrier();                       // compute(kt) done; next STAGE may overwrite
  }
#undef STAGE_KV
  // final l for oacc rows q = g*4+r
  float lr[4];
#pragma unroll
  for (int r = 0; r < 4; ++r) lr[r] = __shfl(l, (lane & 48) | (g * 4 + r), 64);
#pragma unroll
  for (int cb = 0; cb < 4; ++cb)
#pragma unroll
    for (int r = 0; r < 4; ++r) {
      long row = rowbase + qt * 128 + wid * 16 + g * 4 + r;
      o[row * 512 + hh * 64 + cb * 16 + cl] = f2bf(oacc[cb][r] / lr[r]);
    }
}

// ---------------- LayerNorm, one wave per 512-row. MODE 0: f32->f32, 1: f32->bf16
template <int MODE>
__global__ __launch_bounds__(256)
void ln_k(const float* __restrict__ in_, const float* __restrict__ gg,
          const float* __restrict__ bb, void* __restrict__ out_)
{
  const long row = (long)blockIdx.x * 4 + (threadIdx.x >> 6);
  const int lane = threadIdx.x & 63;
  float x[8];
  const float* p = in_ + row * 512 + lane * 8;
  *(float4*)(x) = *(const float4*)(p);
  *(float4*)(x + 4) = *(const float4*)(p + 4);
  float s = 0.f;
#pragma unroll
  for (int j = 0; j < 8; ++j) s += x[j];
#pragma unroll
  for (int off = 1; off < 64; off <<= 1) s += __shfl_xor(s, off, 64);
  const float mean = s * (1.0f / 512.0f);
  float vs = 0.f;
#pragma unroll
  for (int j = 0; j < 8; ++j) { float d = x[j] - mean; vs += d * d; }
#pragma unroll
  for (int off = 1; off < 64; off <<= 1) vs += __shfl_xor(vs, off, 64);
  const float rstd = rsqrtf(vs * (1.0f / 512.0f) + 1e-5f);
  if (MODE == 0) {
    float y[8];
#pragma unroll
    for (int j = 0; j < 8; ++j)
      y[j] = (x[j] - mean) * rstd * gg[lane * 8 + j] + bb[lane * 8 + j];
    float* q = (float*)out_ + row * 512 + lane * 8;
    *(float4*)(q) = *(const float4*)(y);
    *(float4*)(q + 4) = *(const float4*)(y + 4);
  } else {
    us8 ov;
#pragma unroll
    for (int j = 0; j < 8; ++j)
      ov[j] = f2bf((x[j] - mean) * rstd * gg[lane * 8 + j] + bb[lane * 8 + j]);
    *(us8*)((u16*)out_ + row * 512 + lane * 8) = ov;
  }
}

// ---------------- input embed: h = E[t] + sum_9 scalars*w_in rows + b_in (fp32) ----------------
__global__ __launch_bounds__(256)
void embed_k(const float* __restrict__ x, const float* __restrict__ par,
             const float* __restrict__ E, const float* __restrict__ w_in,
             const float* __restrict__ b_in, float* __restrict__ h)
{
  const long bt = blockIdx.x;
  const int b = (int)(bt >> 10), t = (int)(bt & 1023);
  float xs[9];
#pragma unroll
  for (int c = 0; c < 3; ++c) xs[c] = x[((long)b * 3 + c) * 1024 + t];
#pragma unroll
  for (int c = 0; c < 6; ++c) xs[3 + c] = par[((long)b * 6 + c) * 1024 + t];
  for (int w = threadIdx.x; w < 512; w += 256) {
    float a = E[(long)t * 512 + w] + b_in[w];
#pragma unroll
    for (int c = 0; c < 9; ++c) a += xs[c] * w_in[c * 512 + w];
    h[bt * 512 + w] = a;
  }
}

// ---------------- fp32 -> bf16 transpose [R,C] -> [C,R] ----------------
__global__ __launch_bounds__(256)
void tr_k(const float* __restrict__ in, u16* __restrict__ out, int R, int C)
{
  __shared__ u16 tile[32][33];
  const int r0 = blockIdx.y * 32, c0 = blockIdx.x * 32;
  const int tx = threadIdx.x & 31, ty = threadIdx.x >> 5;
  for (int rr = ty; rr < 32; rr += 8) tile[rr][tx] = f2bf(in[(long)(r0 + rr) * C + c0 + tx]);
  __syncthreads();
  for (int rr = ty; rr < 32; rr += 8) out[(long)(c0 + rr) * R + r0 + tx] = tile[tx][rr];
}

// ---------------- fp32 -> bf16 cast ----------------
__global__ __launch_bounds__(256)
void cast_k(const float* __restrict__ in, u16* __restrict__ out, long n)
{
  long i = ((long)blockIdx.x * 256 + threadIdx.x) * 4;
  if (i + 3 < n) {
    float4 v = *(const float4*)(in + i);
    out[i] = f2bf(v.x); out[i + 1] = f2bf(v.y); out[i + 2] = f2bf(v.z); out[i + 3] = f2bf(v.w);
  }
}

// ---------------- masked max-pool, stage 1: coalesced per-(b, t-chunk) partial max ----------------
__global__ __launch_bounds__(256)
void pool1_k(const float* __restrict__ hm, const float* __restrict__ mask, float* __restrict__ part)
{
  const int c = blockIdx.x, b = blockIdx.y;
  const int t0 = c * 128;
  const int w0 = threadIdx.x, w1 = threadIdx.x + 256;
  float m0 = -3.0e38f, m1 = -3.0e38f;
  for (int t = 0; t < 128; ++t) {
    const float mv = mask[b * 1024 + t0 + t];
    const float neg = (1.0f - mv) * (-100000.0f);
    const float* row = hm + ((long)b * 1024 + t0 + t) * 512;
    m0 = fmaxf(m0, row[w0] * mv + neg);
    m1 = fmaxf(m1, row[w1] * mv + neg);
  }
  part[((long)b * 8 + c) * 512 + w0] = m0;
  part[((long)b * 8 + c) * 512 + w1] = m1;
}
// ---------------- stage 2: combine 8 chunks ----------------
__global__ __launch_bounds__(256)
void pool2_k(const float* __restrict__ part, float* __restrict__ pooled)
{
  const int b = blockIdx.y;
  const int w = blockIdx.x * 256 + threadIdx.x;
  float m = -3.0e38f;
#pragma unroll
  for (int c = 0; c < 8; ++c) m = fmaxf(m, part[((long)b * 8 + c) * 512 + w]);
  pooled[b * 512 + w] = m;
}

// ---------------- masked transpose to output h [B,512,T] fp32 ----------------
__global__ __launch_bounds__(256)
void tout_k(const float* __restrict__ hm, const float* __restrict__ mask, float* __restrict__ outh)
{
  __shared__ float tile[64][65];
  const int t0 = blockIdx.x * 64, w0 = blockIdx.y * 64, b = blockIdx.z;
  const int tx = threadIdx.x & 63, ty = threadIdx.x >> 6;
  for (int i = ty; i < 64; i += 4)
    tile[i][tx] = hm[((long)b * 1024 + t0 + i) * 512 + w0 + tx];
  __syncthreads();
  const float mv = mask[b * 1024 + t0 + tx];
  for (int i = ty; i < 64; i += 4)
    outh[((long)b * 512 + w0 + i) * 1024 + t0 + tx] = tile[tx][i] * mv;
}

// ---------------- tiny aggregator matmuls (fp32 weights) ----------------
__global__ __launch_bounds__(256)
void agg1_k(const float* __restrict__ pooled, const float* __restrict__ wf,
            const float* __restrict__ bf_, float* __restrict__ z1)
{
  const int b = blockIdx.y;
  const int n = blockIdx.x * 256 + threadIdx.x;
  float acc = 0.f;
  for (int k = 0; k < 512; ++k) acc += pooled[b * 512 + k] * wf[(long)k * 2048 + n];
  z1[(long)b * 2048 + n] = gelu_f(acc + bf_[n]);
}
__global__ __launch_bounds__(256)
void agg2_k(const float* __restrict__ z1, const float* __restrict__ wp,
            const float* __restrict__ bp, float* __restrict__ zo)
{
  const int b = blockIdx.y;
  const int n = blockIdx.x * 256 + threadIdx.x;
  float acc = 0.f;
  for (int k = 0; k < 2048; ++k) acc += z1[(long)b * 2048 + k] * wp[(long)k * 512 + n];
  zo[b * 512 + n] = acc + bp[n];
}

extern "C" void kernel_launch(void* const* d_in, const int* in_sizes, int n_in,
                              void* d_out, int out_size, void* d_ws, size_t ws_size,
                              hipStream_t stream)
{
  (void)in_sizes; (void)n_in; (void)out_size; (void)ws_size;
  const float* x        = (const float*)d_in[0];
  const float* params   = (const float*)d_in[1];
  const float* mask     = (const float*)d_in[2];
  const float* class_emb= (const float*)d_in[3];
  const float* w_in     = (const float*)d_in[4];
  const float* b_in     = (const float*)d_in[5];
  const float* ln_pre_g = (const float*)d_in[6];
  const float* ln_pre_b = (const float*)d_in[7];
  const float* qkv_w    = (const float*)d_in[8];
  const float* qkv_b    = (const float*)d_in[9];
  const float* attn_pw  = (const float*)d_in[10];
  const float* attn_pb  = (const float*)d_in[11];
  const float* ln1_g    = (const float*)d_in[12];
  const float* ln1_b    = (const float*)d_in[13];
  const float* fc_w     = (const float*)d_in[14];
  const float* fc_b     = (const float*)d_in[15];
  const float* fcp_w    = (const float*)d_in[16];
  const float* fcp_b    = (const float*)d_in[17];
  const float* ln2_g    = (const float*)d_in[18];
  const float* ln2_b    = (const float*)d_in[19];
  const float* ln_post_g= (const float*)d_in[20];
  const float* ln_post_b= (const float*)d_in[21];
  const float* w_out    = (const float*)d_in[22];
  const float* b_out    = (const float*)d_in[23];
  const float* agg_fc_w = (const float*)d_in[24];
  const float* agg_fc_b = (const float*)d_in[25];
  const float* agg_pw   = (const float*)d_in[26];
  const float* agg_pb   = (const float*)d_in[27];

  float* out_f = (float*)d_out;          // z: [0, 16384)
  float* out_h = out_f + 16384;          // h: 64 MiB fp32 region
  u16* sc = (u16*)out_h;                 // bf16 scratch: up to 16384x2048 (64 MiB)

  // ---- workspace layout (~125 MiB) ----
  char* ws = (char*)d_ws;
  float* hf = (float*)ws;       ws += (size_t)32768 * 512 * 4;   // residual fp32 (64 MiB)
  u16* hn = (u16*)ws;           ws += (size_t)32768 * 512 * 2;   // LN / attn-out bf16 (32 MiB)
  float* E = (float*)ws;        ws += (size_t)1024 * 512 * 4;    // class-emb proj (2 MiB)
  u16* ce_b = (u16*)ws;         ws += (size_t)1024 * 1024 * 2;   // class_emb bf16 (2 MiB)
  u16* wt_qkv = (u16*)ws;       ws += (size_t)1536 * 512 * 2;    // per-layer transposes (6.3 MiB)
  u16* wt_pw  = (u16*)ws;       ws += (size_t)512 * 512 * 2;
  u16* wt_fc  = (u16*)ws;       ws += (size_t)2048 * 512 * 2;
  u16* wt_fcp = (u16*)ws;       ws += (size_t)512 * 2048 * 2;
  u16* w_in_t = (u16*)ws;       ws += (size_t)512 * 1024 * 2;
  u16* w_out_t= (u16*)ws;       ws += (size_t)512 * 512 * 2;
  float* pooled = (float*)ws;   ws += (size_t)32 * 512 * 4;
  float* z1     = (float*)ws;   ws += (size_t)32 * 2048 * 4;
  float* part   = (float*)ws;   ws += (size_t)32 * 8 * 512 * 4;  // pool partials (0.5 MiB)
  u16* vt       = (u16*)ws;     ws += (size_t)16 * 8 * 64 * 1024 * 2;  // V^T per half (16 MiB)

  // one-time converts + class-emb projection + embed + ln_pre
  cast_k<<<1024, 256, 0, stream>>>(class_emb, ce_b, 1024 * 1024);
  tr_k<<<dim3(16, 32), 256, 0, stream>>>(w_in + 9 * 512, w_in_t, 1024, 512);
  tr_k<<<dim3(16, 16), 256, 0, stream>>>(w_out, w_out_t, 512, 512);
  gemm_bt<0><<<dim3(4, 4), 512, 0, stream>>>(ce_b, w_in_t, nullptr, E, nullptr, nullptr,
                                             1024, 1024, 1024, 512);
  embed_k<<<32768, 256, 0, stream>>>(x, params, E, w_in, b_in, hf);
  ln_k<0><<<8192, 256, 0, stream>>>(hf, ln_pre_g, ln_pre_b, hf);

  for (int l = 0; l < 12; ++l) {
    tr_k<<<dim3(48, 16), 256, 0, stream>>>(qkv_w + (size_t)l * 512 * 1536, wt_qkv, 512, 1536);
    tr_k<<<dim3(16, 16), 256, 0, stream>>>(attn_pw + (size_t)l * 512 * 512, wt_pw, 512, 512);
    tr_k<<<dim3(64, 16), 256, 0, stream>>>(fc_w + (size_t)l * 512 * 2048, wt_fc, 512, 2048);
    tr_k<<<dim3(16, 64), 256, 0, stream>>>(fcp_w + (size_t)l * 2048 * 512, wt_fcp, 2048, 512);

    // LN1 full batch -> hn (bf16)
    ln_k<1><<<8192, 256, 0, stream>>>(hf, ln1_g + l * 512, ln1_b + l * 512, hn);
    // QKV (V written transposed to vt) + attention per batch-half; attn-out overwrites hn half
    for (int half = 0; half < 2; ++half) {
      const size_t ro = (size_t)half * 16384;
      gemm_bt<4><<<dim3(12, 64), 512, 0, stream>>>(hn + ro * 512, wt_qkv, qkv_b + l * 1536,
                                                   nullptr, sc, vt, 512, 512, 512, 1536);
      attn_k<<<1024, 512, 0, stream>>>(sc, vt, hn + ro * 512);
    }
    // attn projection full batch: h += hn @ pw^T + b
    gemm_bt<2><<<dim3(4, 128), 512, 0, stream>>>(hn, wt_pw, attn_pb + l * 512,
                                                 hf, nullptr, nullptr, 512, 512, 512, 512);
    // LN2 full batch -> hn
    ln_k<1><<<8192, 256, 0, stream>>>(hf, ln2_g + l * 512, ln2_b + l * 512, hn);
    // FF per batch-half: mid [16384x2048] bf16 in sc (64 MiB)
    for (int half = 0; half < 2; ++half) {
      const size_t ro = (size_t)half * 16384;
      gemm_bt<3><<<dim3(16, 64), 512, 0, stream>>>(hn + ro * 512, wt_fc, fc_b + l * 2048,
                                                   nullptr, sc, nullptr, 512, 512, 512, 2048);
      gemm_bt<2><<<dim3(4, 64), 512, 0, stream>>>(sc, wt_fcp, fcp_b + l * 512,
                                                  hf + ro * 512, nullptr, nullptr, 2048, 2048, 2048, 512);
    }
  }

  // final LN + out-proj (residual becomes final h), then pool/agg, then h output
  ln_k<1><<<8192, 256, 0, stream>>>(hf, ln_post_g, ln_post_b, hn);
  gemm_bt<0><<<dim3(4, 128), 512, 0, stream>>>(hn, w_out_t, b_out, hf, nullptr, nullptr,
                                               512, 512, 512, 512);
  pool1_k<<<dim3(8, 32), 256, 0, stream>>>(hf, mask, part);
  pool2_k<<<dim3(2, 32), 256, 0, stream>>>(part, pooled);
  agg1_k<<<dim3(8, 32), 256, 0, stream>>>(pooled, agg_fc_w, agg_fc_b, z1);
  agg2_k<<<dim3(2, 32), 256, 0, stream>>>(z1, agg_pw, agg_pb, out_f);
  tout_k<<<dim3(16, 8, 32), 256, 0, stream>>>(hf, mask, out_h);
}

// Round 15
// 6589.940 us; speedup vs baseline: 2.0918x; 1.0204x over previous
//
#include <hip/hip_runtime.h>
#include <hip/hip_bf16.h>

// PartCodeTransformer forward on MI355X (gfx950).
// I/O fp32; internal bf16 MFMA + fp32 accum/residual.
// Round 15: GEMM LDS XOR-swizzle (chunk ^= (row>>1)&3, pre-swizzled global source +
// swizzled fragment reads -> 2-way banks, was 8-way); agg1/agg2 split-K partials.
// T1 XCD chunked swizzle, 256x128 8-wave 2-phase GEMM, 8-wave attn all retained.

typedef unsigned short u16;
typedef unsigned int u32;
typedef __attribute__((ext_vector_type(8))) short bf16x8;
typedef __attribute__((ext_vector_type(8))) unsigned short us8;
typedef __attribute__((ext_vector_type(4))) unsigned short us4;
typedef __attribute__((ext_vector_type(4))) float f32x4;

__device__ __forceinline__ float bf2f(u16 s) {
  union { u32 u; float f; } c; c.u = ((u32)s) << 16; return c.f;
}
__device__ __forceinline__ u16 f2bf(float f) {
  __hip_bfloat16 h = __float2bfloat16(f);   // hardware RNE cvt
  union { __hip_bfloat16 h; u16 u; } c; c.h = h; return c.u;
}
__device__ __forceinline__ float gelu_f(float v) {
  return 0.5f * v * (1.0f + erff(v * 0.7071067811865475f));
}
__device__ __forceinline__ void gl2lds16(const u16* g, u16* l) {
  __builtin_amdgcn_global_load_lds((const __attribute__((address_space(1))) void*)g,
                                   (__attribute__((address_space(3))) void*)l, 16, 0, 0);
}
__device__ __forceinline__ f32x4 mfma16(bf16x8 a, bf16x8 b, f32x4 c) {
  return __builtin_amdgcn_mfma_f32_16x16x32_bf16(a, b, c, 0, 0, 0);
}
// chunk swizzle for 128B rows (attn): permute 16B chunks within the row
__device__ __forceinline__ int swz(int row) { return (row ^ (row >> 3)) & 7; }

// ------------- A[M,K](lda) x Bt[N,K](ldb) GEMM, 256x128 tile, 8 waves, 2-phase dbuf -------------
// LDS swizzle: 64B rows (BK=32 bf16) = 4 chunks of 16B; phys_chunk = log_chunk ^ ((row>>1)&3).
// EPI: 0 f32=v ; 1 bf16=v ; 2 f32+=v ; 3 bf16=gelu(v) ; 4 qkv: Q/K->Cb, V->Vt transposed
template <int EPI>
__global__ __launch_bounds__(512)
void gemm_bt(const u16* __restrict__ A, const u16* __restrict__ Bt,
             const float* __restrict__ bias, float* __restrict__ Cf,
             u16* __restrict__ Cb, u16* __restrict__ Vt, int K, int lda, int ldb, int ldc)
{
  __shared__ __align__(16) u16 As[2][256 * 32];   // 32 KB
  __shared__ __align__(16) u16 Bs[2][128 * 32];   // 16 KB
  const int tid = threadIdx.x;
  const int lane = tid & 63, wid = tid >> 6;
  const int wm = wid & 3, wn = wid >> 2;          // 4 M-waves x 2 N-waves, 64x64 each
  // T1: chunked XCD swizzle — each XCD gets a contiguous logical range (N fastest)
  const int nbx = gridDim.x;
  const int nwg = nbx * gridDim.y;
  int lin = blockIdx.y * nbx + blockIdx.x;
  lin = (lin & 7) * (nwg >> 3) + (lin >> 3);
  const long m0 = (long)(lin / nbx) * 256, n0 = (long)(lin % nbx) * 128;

  // staging: thread c covers LDS (row = c>>2, chunk = c&3); global source chunk pre-swizzled
  const int c0 = tid, c1 = tid + 512;
  const int kc0 = (c0 & 3) ^ (((c0 >> 2) >> 1) & 3);
  const int kc1 = (c1 & 3) ^ (((c1 >> 2) >> 1) & 3);
  const int kcb = (tid & 3) ^ (((tid >> 2) >> 1) & 3);
  const u16* aS0 = A + (m0 + (c0 >> 2)) * (long)lda + kc0 * 8;
  const u16* aS1 = A + (m0 + (c1 >> 2)) * (long)lda + kc1 * 8;
  const u16* bS0 = Bt + (n0 + (tid >> 2)) * (long)ldb + kcb * 8;

  f32x4 acc[4][4] = {};
  const int cl4 = lane & 15;
  const int gph = ((lane >> 4) ^ ((cl4 >> 1) & 3)) * 8;  // physical chunk offset (u16)
  const int aro = (wm * 64 + cl4) * 32 + gph;
  const int bro = (wn * 64 + cl4) * 32 + gph;
  const int nt = K >> 5;

#define STAGE_AB(buf, k0_)                          \
  gl2lds16(aS0 + (k0_), As[buf] + c0 * 8);          \
  gl2lds16(aS1 + (k0_), As[buf] + c1 * 8);          \
  gl2lds16(bS0 + (k0_), Bs[buf] + tid * 8);

  STAGE_AB(0, 0);
  for (int t = 0; t < nt; ++t) {
    const int cur = t & 1;
    if (t < nt - 1) {
      STAGE_AB(cur ^ 1, (t + 1) * 32);
      asm volatile("s_waitcnt vmcnt(3)" ::: "memory");  // own stage(t) landed; stage(t+1) in flight
    } else {
      asm volatile("s_waitcnt vmcnt(0)" ::: "memory");
    }
    __builtin_amdgcn_s_barrier();
    bf16x8 af[4], bfr[4];
#pragma unroll
    for (int i = 0; i < 4; ++i) af[i] = *(const bf16x8*)(As[cur] + aro + i * 16 * 32);
#pragma unroll
    for (int j = 0; j < 4; ++j) bfr[j] = *(const bf16x8*)(Bs[cur] + bro + j * 16 * 32);
    __builtin_amdgcn_s_setprio(1);
#pragma unroll
    for (int i = 0; i < 4; ++i)
#pragma unroll
      for (int j = 0; j < 4; ++j)
        acc[i][j] = mfma16(af[i], bfr[j], acc[i][j]);
    __builtin_amdgcn_s_setprio(0);
    __builtin_amdgcn_s_barrier();
  }
#undef STAGE_AB
  const int rg = (lane >> 4) * 4, cl = lane & 15;
#pragma unroll
  for (int i = 0; i < 4; ++i) {
#pragma unroll
    for (int j = 0; j < 4; ++j) {
      const long row = m0 + wm * 64 + i * 16 + rg;
      const long col = n0 + wn * 64 + j * 16 + cl;
      const float bv = bias ? bias[col] : 0.0f;
      if (EPI == 4) {
        const int hh = (int)col / 192, off = (int)col - hh * 192;
        if (off < 128) {
#pragma unroll
          for (int r = 0; r < 4; ++r)
            Cb[(row + r) * ldc + col] = f2bf(acc[i][j][r] + bv);
        } else {
          us4 pk;
#pragma unroll
          for (int r = 0; r < 4; ++r) pk[r] = f2bf(acc[i][j][r] + bv);
          const long bl = row >> 10, t0 = row & 1023;
          *(us4*)(Vt + (((bl * 8 + hh) * 64 + (off - 128)) << 10) + t0) = pk;
        }
      } else {
#pragma unroll
        for (int r = 0; r < 4; ++r) {
          float v = acc[i][j][r] + bv;
          long idx = (row + r) * ldc + col;
          if (EPI == 0) Cf[idx] = v;
          else if (EPI == 1) Cb[idx] = f2bf(v);
          else if (EPI == 2) Cf[idx] += v;
          else Cb[idx] = f2bf(gelu_f(v));
        }
      }
    }
  }
}

// ---------------- flash attention: 8 waves, QBLK=128, swapped QK^T, dbuf K/V ----------------
// 1-D grid 1024 blocks = (qt 8) x (hh 8) x (b 16), chunked XCD swizzle (qt fastest).
// LDS 48KB (P overlaid on each wave's own Q rows) -> 3 blocks/CU, 24 waves/CU.
__global__ __launch_bounds__(512)
void attn_k(const u16* __restrict__ qkv, const u16* __restrict__ vt, u16* __restrict__ o)
{
  __shared__ __align__(16) u16 Qs[128 * 64];     // wave w's rows [w*16,w*16+16) reused as P
  __shared__ __align__(16) u16 Ks[2][64 * 64];
  __shared__ __align__(16) u16 Vts[2][64 * 64];  // [ch][key], key-chunks swizzled by swz(ch)
  const int tid = threadIdx.x, lane = tid & 63, wid = tid >> 6;
  int lin = blockIdx.x;
  lin = (lin & 7) * 128 + (lin >> 3);            // T1 chunked swizzle (1024 blocks)
  const int qt = lin & 7, hh = (lin >> 3) & 7, b = lin >> 6;
  const long rowbase = (long)b * 1024;
  const long vbase = (((long)b * 8 + hh) * 64) * 1024;
  const int g = lane >> 4, cl = lane & 15;
  u16* Psw = Qs + wid * 1024;                    // per-wave 16x64 P scratch

  // Q stage: 128 rows, LDS linear, global source column pre-swizzled (2 loads/thread)
#pragma unroll
  for (int it = 0; it < 2; ++it) {
    int c = tid + it * 512;
    int row = c >> 3, c8s = (c & 7) ^ swz(row);
    gl2lds16(qkv + (rowbase + qt * 128 + row) * 1536 + hh * 192 + c8s * 8, Qs + c * 8);
  }
  // K/V stage for tile kt into buf (2 loads/thread)
#define STAGE_KV(buf, kt_)                                                            \
  {                                                                                   \
    int row = tid >> 3, c8s = (tid & 7) ^ swz(row);                                   \
    gl2lds16(qkv + (rowbase + (kt_) * 64 + row) * 1536 + hh * 192 + 64 + c8s * 8,     \
             Ks[buf] + tid * 8);                                                      \
    gl2lds16(vt + vbase + (long)row * 1024 + (kt_) * 64 + c8s * 8, Vts[buf] + tid * 8); \
  }
  STAGE_KV(0, 0);

  float m = -3.0e38f, l = 0.f;
  f32x4 oacc[4] = {};
  const int Rq = wid * 16 + cl, sq = swz(Rq) << 3;  // Q fragment row / swizzle
  const int spw = swz(cl) << 3;                      // P row (= q = cl) swizzle
  bf16x8 aq[2];

  for (int kt = 0; kt < 16; ++kt) {
    const int cur = kt & 1;
    if (kt < 15) {
      STAGE_KV(cur ^ 1, kt + 1);
      asm volatile("s_waitcnt vmcnt(2)" ::: "memory");  // Q+stage(kt) landed; stage(kt+1) in flight
    } else {
      asm volatile("s_waitcnt vmcnt(0)" ::: "memory");
    }
    __builtin_amdgcn_s_barrier();                       // all waves' stage(kt) landed
    if (kt == 0) {
#pragma unroll
      for (int kb = 0; kb < 2; ++kb)
        aq[kb] = *(const bf16x8*)(Qs + Rq * 64 + ((kb * 32 + g * 8) ^ sq));
    }
    // QK^T swapped: s[j] = S^T[k = j*16 + g*4 + r][q = cl]
    f32x4 s[4] = {};
    __builtin_amdgcn_s_setprio(1);
#pragma unroll
    for (int j = 0; j < 4; ++j) {
      const int Rk = j * 16 + cl, sk = swz(Rk) << 3;
#pragma unroll
      for (int kb = 0; kb < 2; ++kb) {
        bf16x8 bk = *(const bf16x8*)(Ks[cur] + Rk * 64 + ((kb * 32 + g * 8) ^ sk));
        s[j] = mfma16(bk, aq[kb], s[j]);
      }
    }
    __builtin_amdgcn_s_setprio(0);
    // lane-local softmax for q = cl over 16 k-values (+2-step cross-g reduce)
    float mx = s[0][0];
#pragma unroll
    for (int j = 0; j < 4; ++j)
#pragma unroll
      for (int r = 0; r < 4; ++r) mx = fmaxf(mx, s[j][r]);
    mx *= 0.125f;
    mx = fmaxf(mx, __shfl_xor(mx, 16, 64));
    mx = fmaxf(mx, __shfl_xor(mx, 32, 64));
    // defer-max (T13): rescale only when some row's max grew past THR=8
    if (!__all(mx <= m + 8.f)) {
      const float mnew = fmaxf(m, mx);
      const float al = __expf(m - mnew);
      m = mnew;
      l *= al;
      float alr[4];
#pragma unroll
      for (int r = 0; r < 4; ++r) alr[r] = __shfl(al, (lane & 48) | (g * 4 + r), 64);
#pragma unroll
      for (int cb = 0; cb < 4; ++cb) {
        f32x4 t = oacc[cb];
        t[0] *= alr[0]; t[1] *= alr[1]; t[2] *= alr[2]; t[3] *= alr[3];
        oacc[cb] = t;
      }
    }
    float p[4][4], ts = 0.f;
#pragma unroll
    for (int j = 0; j < 4; ++j)
#pragma unroll
      for (int r = 0; r < 4; ++r) {
        p[j][r] = __expf(s[j][r] * 0.125f - m);
        ts += p[j][r];
      }
    ts += __shfl_xor(ts, 16, 64);
    ts += __shfl_xor(ts, 32, 64);
    l += ts;
    // P store: 4x ds_write_b64; physical(k) = k ^ spw (spw mult of 8, base mult of 4)
#pragma unroll
    for (int j = 0; j < 4; ++j) {
      us4 pk;
      pk[0] = f2bf(p[j][0]); pk[1] = f2bf(p[j][1]);
      pk[2] = f2bf(p[j][2]); pk[3] = f2bf(p[j][3]);
      *(us4*)(&Psw[cl * 64 + ((j * 16 + g * 4) ^ spw)]) = pk;
    }
    asm volatile("s_waitcnt lgkmcnt(0)" ::: "memory");  // within-wave P write->read ordering
    bf16x8 pa[2];
#pragma unroll
    for (int kb = 0; kb < 2; ++kb)
      pa[kb] = *(const bf16x8*)(&Psw[cl * 64 + ((kb * 32 + g * 8) ^ spw)]);
    __builtin_amdgcn_s_setprio(1);
#pragma unroll
    for (int kb = 0; kb < 2; ++kb)
#pragma unroll
      for (int cb = 0; cb < 4; ++cb) {
        const int ch = cb * 16 + cl;
        bf16x8 vb = *(const bf16x8*)(Vts[cur] + ch * 64 + ((kb * 32 + g * 8) ^ (swz(ch) << 3)));
        oacc[cb] = mfma16(pa[kb], vb, oacc[cb]);
      }
    __builtin_amdgcn_s_setprio(0);
    __builtin_amdgcn_s_barrier();                       // compute(kt) done; next STAGE may overwrite
  }
#undef STAGE_KV
  // final l for oacc rows q = g*4+r
  float lr[4];
#pragma unroll
  for (int r = 0; r < 4; ++r) lr[r] = __shfl(l, (lane & 48) | (g * 4 + r), 64);
#pragma unroll
  for (int cb = 0; cb < 4; ++cb)
#pragma unroll
    for (int r = 0; r < 4; ++r) {
      long row = rowbase + qt * 128 + wid * 16 + g * 4 + r;
      o[row * 512 + hh * 64 + cb * 16 + cl] = f2bf(oacc[cb][r] / lr[r]);
    }
}

// ---------------- LayerNorm, one wave per 512-row. MODE 0: f32->f32, 1: f32->bf16
template <int MODE>
__global__ __launch_bounds__(256)
void ln_k(const float* __restrict__ in_, const float* __restrict__ gg,
          const float* __restrict__ bb, void* __restrict__ out_)
{
  const long row = (long)blockIdx.x * 4 + (threadIdx.x >> 6);
  const int lane = threadIdx.x & 63;
  float x[8];
  const float* p = in_ + row * 512 + lane * 8;
  *(float4*)(x) = *(const float4*)(p);
  *(float4*)(x + 4) = *(const float4*)(p + 4);
  float s = 0.f;
#pragma unroll
  for (int j = 0; j < 8; ++j) s += x[j];
#pragma unroll
  for (int off = 1; off < 64; off <<= 1) s += __shfl_xor(s, off, 64);
  const float mean = s * (1.0f / 512.0f);
  float vs = 0.f;
#pragma unroll
  for (int j = 0; j < 8; ++j) { float d = x[j] - mean; vs += d * d; }
#pragma unroll
  for (int off = 1; off < 64; off <<= 1) vs += __shfl_xor(vs, off, 64);
  const float rstd = rsqrtf(vs * (1.0f / 512.0f) + 1e-5f);
  if (MODE == 0) {
    float y[8];
#pragma unroll
    for (int j = 0; j < 8; ++j)
      y[j] = (x[j] - mean) * rstd * gg[lane * 8 + j] + bb[lane * 8 + j];
    float* q = (float*)out_ + row * 512 + lane * 8;
    *(float4*)(q) = *(const float4*)(y);
    *(float4*)(q + 4) = *(const float4*)(y + 4);
  } else {
    us8 ov;
#pragma unroll
    for (int j = 0; j < 8; ++j)
      ov[j] = f2bf((x[j] - mean) * rstd * gg[lane * 8 + j] + bb[lane * 8 + j]);
    *(us8*)((u16*)out_ + row * 512 + lane * 8) = ov;
  }
}

// ---------------- input embed: h = E[t] + sum_9 scalars*w_in rows + b_in (fp32) ----------------
__global__ __launch_bounds__(256)
void embed_k(const float* __restrict__ x, const float* __restrict__ par,
             const float* __restrict__ E, const float* __restrict__ w_in,
             const float* __restrict__ b_in, float* __restrict__ h)
{
  const long bt = blockIdx.x;
  const int b = (int)(bt >> 10), t = (int)(bt & 1023);
  float xs[9];
#pragma unroll
  for (int c = 0; c < 3; ++c) xs[c] = x[((long)b * 3 + c) * 1024 + t];
#pragma unroll
  for (int c = 0; c < 6; ++c) xs[3 + c] = par[((long)b * 6 + c) * 1024 + t];
  for (int w = threadIdx.x; w < 512; w += 256) {
    float a = E[(long)t * 512 + w] + b_in[w];
#pragma unroll
    for (int c = 0; c < 9; ++c) a += xs[c] * w_in[c * 512 + w];
    h[bt * 512 + w] = a;
  }
}

// ---------------- fp32 -> bf16 transpose [R,C] -> [C,R] ----------------
__global__ __launch_bounds__(256)
void tr_k(const float* __restrict__ in, u16* __restrict__ out, int R, int C)
{
  __shared__ u16 tile[32][33];
  const int r0 = blockIdx.y * 32, c0 = blockIdx.x * 32;
  const int tx = threadIdx.x & 31, ty = threadIdx.x >> 5;
  for (int rr = ty; rr < 32; rr += 8) tile[rr][tx] = f2bf(in[(long)(r0 + rr) * C + c0 + tx]);
  __syncthreads();
  for (int rr = ty; rr < 32; rr += 8) out[(long)(c0 + rr) * R + r0 + tx] = tile[tx][rr];
}

// ---------------- fp32 -> bf16 cast ----------------
__global__ __launch_bounds__(256)
void cast_k(const float* __restrict__ in, u16* __restrict__ out, long n)
{
  long i = ((long)blockIdx.x * 256 + threadIdx.x) * 4;
  if (i + 3 < n) {
    float4 v = *(const float4*)(in + i);
    out[i] = f2bf(v.x); out[i + 1] = f2bf(v.y); out[i + 2] = f2bf(v.z); out[i + 3] = f2bf(v.w);
  }
}

// ---------------- masked max-pool, stage 1: coalesced per-(b, t-chunk) partial max ----------------
__global__ __launch_bounds__(256)
void pool1_k(const float* __restrict__ hm, const float* __restrict__ mask, float* __restrict__ part)
{
  const int c = blockIdx.x, b = blockIdx.y;
  const int t0 = c * 128;
  const int w0 = threadIdx.x, w1 = threadIdx.x + 256;
  float m0 = -3.0e38f, m1 = -3.0e38f;
  for (int t = 0; t < 128; ++t) {
    const float mv = mask[b * 1024 + t0 + t];
    const float neg = (1.0f - mv) * (-100000.0f);
    const float* row = hm + ((long)b * 1024 + t0 + t) * 512;
    m0 = fmaxf(m0, row[w0] * mv + neg);
    m1 = fmaxf(m1, row[w1] * mv + neg);
  }
  part[((long)b * 8 + c) * 512 + w0] = m0;
  part[((long)b * 8 + c) * 512 + w1] = m1;
}
// ---------------- stage 2: combine 8 chunks ----------------
__global__ __launch_bounds__(256)
void pool2_k(const float* __restrict__ part, float* __restrict__ pooled)
{
  const int b = blockIdx.y;
  const int w = blockIdx.x * 256 + threadIdx.x;
  float m = -3.0e38f;
#pragma unroll
  for (int c = 0; c < 8; ++c) m = fmaxf(m, part[((long)b * 8 + c) * 512 + w]);
  pooled[b * 512 + w] = m;
}

// ---------------- masked transpose to output h [B,512,T] fp32 ----------------
__global__ __launch_bounds__(256)
void tout_k(const float* __restrict__ hm, const float* __restrict__ mask, float* __restrict__ outh)
{
  __shared__ float tile[64][65];
  const int t0 = blockIdx.x * 64, w0 = blockIdx.y * 64, b = blockIdx.z;
  const int tx = threadIdx.x & 63, ty = threadIdx.x >> 6;
  for (int i = ty; i < 64; i += 4)
    tile[i][tx] = hm[((long)b * 1024 + t0 + i) * 512 + w0 + tx];
  __syncthreads();
  const float mv = mask[b * 1024 + t0 + tx];
  for (int i = ty; i < 64; i += 4)
    outh[((long)b * 512 + w0 + i) * 1024 + t0 + tx] = tile[tx][i] * mv;
}

// ---------------- aggregator matmuls: split-K partials + combine ----------------
__global__ __launch_bounds__(256)
void agg1p_k(const float* __restrict__ pooled, const float* __restrict__ wf,
             float* __restrict__ part)
{
  const int b = blockIdx.z, kc = blockIdx.y;
  const int n = blockIdx.x * 256 + threadIdx.x;
  float acc = 0.f;
  const int k0 = kc * 64;
#pragma unroll 8
  for (int k = 0; k < 64; ++k) acc += pooled[b * 512 + k0 + k] * wf[(long)(k0 + k) * 2048 + n];
  part[((long)b * 8 + kc) * 2048 + n] = acc;
}
__global__ __launch_bounds__(256)
void agg1c_k(const float* __restrict__ part, const float* __restrict__ bf_,
             float* __restrict__ z1)
{
  const int b = blockIdx.y;
  const int n = blockIdx.x * 256 + threadIdx.x;
  float acc = 0.f;
#pragma unroll
  for (int c = 0; c < 8; ++c) acc += part[((long)b * 8 + c) * 2048 + n];
  z1[(long)b * 2048 + n] = gelu_f(acc + bf_[n]);
}
__global__ __launch_bounds__(256)
void agg2p_k(const float* __restrict__ z1, const float* __restrict__ wp,
             float* __restrict__ part)
{
  const int b = blockIdx.z, kc = blockIdx.y;
  const int n = blockIdx.x * 256 + threadIdx.x;
  float acc = 0.f;
  const int k0 = kc * 256;
#pragma unroll 8
  for (int k = 0; k < 256; ++k) acc += z1[(long)b * 2048 + k0 + k] * wp[(long)(k0 + k) * 512 + n];
  part[((long)b * 8 + kc) * 512 + n] = acc;
}
__global__ __launch_bounds__(256)
void agg2c_k(const float* __restrict__ part, const float* __restrict__ bp,
             float* __restrict__ zo)
{
  const int b = blockIdx.y;
  const int n = blockIdx.x * 256 + threadIdx.x;
  float acc = 0.f;
#pragma unroll
  for (int c = 0; c < 8; ++c) acc += part[((long)b * 8 + c) * 512 + n];
  zo[b * 512 + n] = acc + bp[n];
}

extern "C" void kernel_launch(void* const* d_in, const int* in_sizes, int n_in,
                              void* d_out, int out_size, void* d_ws, size_t ws_size,
                              hipStream_t stream)
{
  (void)in_sizes; (void)n_in; (void)out_size; (void)ws_size;
  const float* x        = (const float*)d_in[0];
  const float* params   = (const float*)d_in[1];
  const float* mask     = (const float*)d_in[2];
  const float* class_emb= (const float*)d_in[3];
  const float* w_in     = (const float*)d_in[4];
  const float* b_in     = (const float*)d_in[5];
  const float* ln_pre_g = (const float*)d_in[6];
  const float* ln_pre_b = (const float*)d_in[7];
  const float* qkv_w    = (const float*)d_in[8];
  const float* qkv_b    = (const float*)d_in[9];
  const float* attn_pw  = (const float*)d_in[10];
  const float* attn_pb  = (const float*)d_in[11];
  const float* ln1_g    = (const float*)d_in[12];
  const float* ln1_b    = (const float*)d_in[13];
  const float* fc_w     = (const float*)d_in[14];
  const float* fc_b     = (const float*)d_in[15];
  const float* fcp_w    = (const float*)d_in[16];
  const float* fcp_b    = (const float*)d_in[17];
  const float* ln2_g    = (const float*)d_in[18];
  const float* ln2_b    = (const float*)d_in[19];
  const float* ln_post_g= (const float*)d_in[20];
  const float* ln_post_b= (const float*)d_in[21];
  const float* w_out    = (const float*)d_in[22];
  const float* b_out    = (const float*)d_in[23];
  const float* agg_fc_w = (const float*)d_in[24];
  const float* agg_fc_b = (const float*)d_in[25];
  const float* agg_pw   = (const float*)d_in[26];
  const float* agg_pb   = (const float*)d_in[27];

  float* out_f = (float*)d_out;          // z: [0, 16384)
  float* out_h = out_f + 16384;          // h: 64 MiB fp32 region
  u16* sc = (u16*)out_h;                 // bf16 scratch: up to 16384x2048 (64 MiB)

  // ---- workspace layout (~128 MiB) ----
  char* ws = (char*)d_ws;
  float* hf = (float*)ws;       ws += (size_t)32768 * 512 * 4;   // residual fp32 (64 MiB)
  u16* hn = (u16*)ws;           ws += (size_t)32768 * 512 * 2;   // LN / attn-out bf16 (32 MiB)
  float* E = (float*)ws;        ws += (size_t)1024 * 512 * 4;    // class-emb proj (2 MiB)
  u16* ce_b = (u16*)ws;         ws += (size_t)1024 * 1024 * 2;   // class_emb bf16 (2 MiB)
  u16* wt_qkv = (u16*)ws;       ws += (size_t)1536 * 512 * 2;    // per-layer transposes (6.3 MiB)
  u16* wt_pw  = (u16*)ws;       ws += (size_t)512 * 512 * 2;
  u16* wt_fc  = (u16*)ws;       ws += (size_t)2048 * 512 * 2;
  u16* wt_fcp = (u16*)ws;       ws += (size_t)512 * 2048 * 2;
  u16* w_in_t = (u16*)ws;       ws += (size_t)512 * 1024 * 2;
  u16* w_out_t= (u16*)ws;       ws += (size_t)512 * 512 * 2;
  float* pooled = (float*)ws;   ws += (size_t)32 * 512 * 4;
  float* z1     = (float*)ws;   ws += (size_t)32 * 2048 * 4;
  float* part   = (float*)ws;   ws += (size_t)32 * 8 * 512 * 4;  // pool partials (0.5 MiB)
  float* apart1 = (float*)ws;   ws += (size_t)32 * 8 * 2048 * 4; // agg1 partials (2 MiB)
  float* apart2 = (float*)ws;   ws += (size_t)32 * 8 * 512 * 4;  // agg2 partials (0.5 MiB)
  u16* vt       = (u16*)ws;     ws += (size_t)16 * 8 * 64 * 1024 * 2;  // V^T per half (16 MiB)

  // one-time converts + class-emb projection + embed + ln_pre
  cast_k<<<1024, 256, 0, stream>>>(class_emb, ce_b, 1024 * 1024);
  tr_k<<<dim3(16, 32), 256, 0, stream>>>(w_in + 9 * 512, w_in_t, 1024, 512);
  tr_k<<<dim3(16, 16), 256, 0, stream>>>(w_out, w_out_t, 512, 512);
  gemm_bt<0><<<dim3(4, 4), 512, 0, stream>>>(ce_b, w_in_t, nullptr, E, nullptr, nullptr,
                                             1024, 1024, 1024, 512);
  embed_k<<<32768, 256, 0, stream>>>(x, params, E, w_in, b_in, hf);
  ln_k<0><<<8192, 256, 0, stream>>>(hf, ln_pre_g, ln_pre_b, hf);

  for (int l = 0; l < 12; ++l) {
    tr_k<<<dim3(48, 16), 256, 0, stream>>>(qkv_w + (size_t)l * 512 * 1536, wt_qkv, 512, 1536);
    tr_k<<<dim3(16, 16), 256, 0, stream>>>(attn_pw + (size_t)l * 512 * 512, wt_pw, 512, 512);
    tr_k<<<dim3(64, 16), 256, 0, stream>>>(fc_w + (size_t)l * 512 * 2048, wt_fc, 512, 2048);
    tr_k<<<dim3(16, 64), 256, 0, stream>>>(fcp_w + (size_t)l * 2048 * 512, wt_fcp, 2048, 512);

    // LN1 full batch -> hn (bf16)
    ln_k<1><<<8192, 256, 0, stream>>>(hf, ln1_g + l * 512, ln1_b + l * 512, hn);
    // QKV (V written transposed to vt) + attention per batch-half; attn-out overwrites hn half
    for (int half = 0; half < 2; ++half) {
      const size_t ro = (size_t)half * 16384;
      gemm_bt<4><<<dim3(12, 64), 512, 0, stream>>>(hn + ro * 512, wt_qkv, qkv_b + l * 1536,
                                                   nullptr, sc, vt, 512, 512, 512, 1536);
      attn_k<<<1024, 512, 0, stream>>>(sc, vt, hn + ro * 512);
    }
    // attn projection full batch: h += hn @ pw^T + b
    gemm_bt<2><<<dim3(4, 128), 512, 0, stream>>>(hn, wt_pw, attn_pb + l * 512,
                                                 hf, nullptr, nullptr, 512, 512, 512, 512);
    // LN2 full batch -> hn
    ln_k<1><<<8192, 256, 0, stream>>>(hf, ln2_g + l * 512, ln2_b + l * 512, hn);
    // FF per batch-half: mid [16384x2048] bf16 in sc (64 MiB)
    for (int half = 0; half < 2; ++half) {
      const size_t ro = (size_t)half * 16384;
      gemm_bt<3><<<dim3(16, 64), 512, 0, stream>>>(hn + ro * 512, wt_fc, fc_b + l * 2048,
                                                   nullptr, sc, nullptr, 512, 512, 512, 2048);
      gemm_bt<2><<<dim3(4, 64), 512, 0, stream>>>(sc, wt_fcp, fcp_b + l * 512,
                                                  hf + ro * 512, nullptr, nullptr, 2048, 2048, 2048, 512);
    }
  }

  // final LN + out-proj (residual becomes final h), then pool/agg, then h output
  ln_k<1><<<8192, 256, 0, stream>>>(hf, ln_post_g, ln_post_b, hn);
  gemm_bt<0><<<dim3(4, 128), 512, 0, stream>>>(hn, w_out_t, b_out, hf, nullptr, nullptr,
                                               512, 512, 512, 512);
  pool1_k<<<dim3(8, 32), 256, 0, stream>>>(hf, mask, part);
  pool2_k<<<dim3(2, 32), 256, 0, stream>>>(part, pooled);
  agg1p_k<<<dim3(8, 8, 32), 256, 0, stream>>>(pooled, agg_fc_w, apart1);
  agg1c_k<<<dim3(8, 32), 256, 0, stream>>>(apart1, agg_fc_b, z1);
  agg2p_k<<<dim3(2, 8, 32), 256, 0, stream>>>(z1, agg_pw, apart2);
  agg2c_k<<<dim3(2, 32), 256, 0, stream>>>(apart2, agg_pb, out_f);
  tout_k<<<dim3(16, 8, 32), 256, 0, stream>>>(hf, mask, out_h);
}

// Round 16
// 6517.931 us; speedup vs baseline: 2.1149x; 1.0110x over previous
//
#include <hip/hip_runtime.h>
#include <hip/hip_bf16.h>

// PartCodeTransformer forward on MI355X (gfx950).
// I/O fp32; internal bf16 MFMA + fp32 accum/residual.
// Round 16: fc GEMM -> 256x256 tile / 16 waves (exactly one full residency round,
// 32 waves/CU); per-layer weight transposes fused into one trL_k launch.
// T1 XCD swizzle, T2 LDS swizzle, 2-phase dbuf counted-vmcnt, 8-wave attn retained.

typedef unsigned short u16;
typedef unsigned int u32;
typedef __attribute__((ext_vector_type(8))) short bf16x8;
typedef __attribute__((ext_vector_type(8))) unsigned short us8;
typedef __attribute__((ext_vector_type(4))) unsigned short us4;
typedef __attribute__((ext_vector_type(4))) float f32x4;

__device__ __forceinline__ float bf2f(u16 s) {
  union { u32 u; float f; } c; c.u = ((u32)s) << 16; return c.f;
}
__device__ __forceinline__ u16 f2bf(float f) {
  __hip_bfloat16 h = __float2bfloat16(f);   // hardware RNE cvt
  union { __hip_bfloat16 h; u16 u; } c; c.h = h; return c.u;
}
__device__ __forceinline__ float gelu_f(float v) {
  return 0.5f * v * (1.0f + erff(v * 0.7071067811865475f));
}
__device__ __forceinline__ void gl2lds16(const u16* g, u16* l) {
  __builtin_amdgcn_global_load_lds((const __attribute__((address_space(1))) void*)g,
                                   (__attribute__((address_space(3))) void*)l, 16, 0, 0);
}
__device__ __forceinline__ f32x4 mfma16(bf16x8 a, bf16x8 b, f32x4 c) {
  return __builtin_amdgcn_mfma_f32_16x16x32_bf16(a, b, c, 0, 0, 0);
}
// chunk swizzle for 128B rows (attn): permute 16B chunks within the row
__device__ __forceinline__ int swz(int row) { return (row ^ (row >> 3)) & 7; }

// ------------- A[M,K](lda) x Bt[N,K](ldb) GEMM, 256x128 tile, 8 waves, 2-phase dbuf -------------
// LDS swizzle: 64B rows (BK=32 bf16) = 4 chunks of 16B; phys_chunk = log_chunk ^ ((row>>1)&3).
// EPI: 0 f32=v ; 1 bf16=v ; 2 f32+=v ; 3 bf16=gelu(v) ; 4 qkv: Q/K->Cb, V->Vt transposed
template <int EPI>
__global__ __launch_bounds__(512)
void gemm_bt(const u16* __restrict__ A, const u16* __restrict__ Bt,
             const float* __restrict__ bias, float* __restrict__ Cf,
             u16* __restrict__ Cb, u16* __restrict__ Vt, int K, int lda, int ldb, int ldc)
{
  __shared__ __align__(16) u16 As[2][256 * 32];   // 32 KB
  __shared__ __align__(16) u16 Bs[2][128 * 32];   // 16 KB
  const int tid = threadIdx.x;
  const int lane = tid & 63, wid = tid >> 6;
  const int wm = wid & 3, wn = wid >> 2;          // 4 M-waves x 2 N-waves, 64x64 each
  const int nbx = gridDim.x;
  const int nwg = nbx * gridDim.y;
  int lin = blockIdx.y * nbx + blockIdx.x;
  lin = (lin & 7) * (nwg >> 3) + (lin >> 3);
  const long m0 = (long)(lin / nbx) * 256, n0 = (long)(lin % nbx) * 128;

  const int c0 = tid, c1 = tid + 512;
  const int kc0 = (c0 & 3) ^ (((c0 >> 2) >> 1) & 3);
  const int kc1 = (c1 & 3) ^ (((c1 >> 2) >> 1) & 3);
  const int kcb = (tid & 3) ^ (((tid >> 2) >> 1) & 3);
  const u16* aS0 = A + (m0 + (c0 >> 2)) * (long)lda + kc0 * 8;
  const u16* aS1 = A + (m0 + (c1 >> 2)) * (long)lda + kc1 * 8;
  const u16* bS0 = Bt + (n0 + (tid >> 2)) * (long)ldb + kcb * 8;

  f32x4 acc[4][4] = {};
  const int cl4 = lane & 15;
  const int gph = ((lane >> 4) ^ ((cl4 >> 1) & 3)) * 8;  // physical chunk offset (u16)
  const int aro = (wm * 64 + cl4) * 32 + gph;
  const int bro = (wn * 64 + cl4) * 32 + gph;
  const int nt = K >> 5;

#define STAGE_AB(buf, k0_)                          \
  gl2lds16(aS0 + (k0_), As[buf] + c0 * 8);          \
  gl2lds16(aS1 + (k0_), As[buf] + c1 * 8);          \
  gl2lds16(bS0 + (k0_), Bs[buf] + tid * 8);

  STAGE_AB(0, 0);
  for (int t = 0; t < nt; ++t) {
    const int cur = t & 1;
    if (t < nt - 1) {
      STAGE_AB(cur ^ 1, (t + 1) * 32);
      asm volatile("s_waitcnt vmcnt(3)" ::: "memory");
    } else {
      asm volatile("s_waitcnt vmcnt(0)" ::: "memory");
    }
    __builtin_amdgcn_s_barrier();
    bf16x8 af[4], bfr[4];
#pragma unroll
    for (int i = 0; i < 4; ++i) af[i] = *(const bf16x8*)(As[cur] + aro + i * 16 * 32);
#pragma unroll
    for (int j = 0; j < 4; ++j) bfr[j] = *(const bf16x8*)(Bs[cur] + bro + j * 16 * 32);
    __builtin_amdgcn_s_setprio(1);
#pragma unroll
    for (int i = 0; i < 4; ++i)
#pragma unroll
      for (int j = 0; j < 4; ++j)
        acc[i][j] = mfma16(af[i], bfr[j], acc[i][j]);
    __builtin_amdgcn_s_setprio(0);
    __builtin_amdgcn_s_barrier();
  }
#undef STAGE_AB
  const int rg = (lane >> 4) * 4, cl = lane & 15;
#pragma unroll
  for (int i = 0; i < 4; ++i) {
#pragma unroll
    for (int j = 0; j < 4; ++j) {
      const long row = m0 + wm * 64 + i * 16 + rg;
      const long col = n0 + wn * 64 + j * 16 + cl;
      const float bv = bias ? bias[col] : 0.0f;
      if (EPI == 4) {
        const int hh = (int)col / 192, off = (int)col - hh * 192;
        if (off < 128) {
#pragma unroll
          for (int r = 0; r < 4; ++r)
            Cb[(row + r) * ldc + col] = f2bf(acc[i][j][r] + bv);
        } else {
          us4 pk;
#pragma unroll
          for (int r = 0; r < 4; ++r) pk[r] = f2bf(acc[i][j][r] + bv);
          const long bl = row >> 10, t0 = row & 1023;
          *(us4*)(Vt + (((bl * 8 + hh) * 64 + (off - 128)) << 10) + t0) = pk;
        }
      } else {
#pragma unroll
        for (int r = 0; r < 4; ++r) {
          float v = acc[i][j][r] + bv;
          long idx = (row + r) * ldc + col;
          if (EPI == 0) Cf[idx] = v;
          else if (EPI == 1) Cb[idx] = f2bf(v);
          else if (EPI == 2) Cf[idx] += v;
          else Cb[idx] = f2bf(gelu_f(v));
        }
      }
    }
  }
}

// ------------- 256x256 tile, 16 waves (1024 thr), 2-phase dbuf — for fc (EPI=3) -------------
template <int EPI>
__global__ __launch_bounds__(1024)
void gemm_bt2(const u16* __restrict__ A, const u16* __restrict__ Bt,
              const float* __restrict__ bias, float* __restrict__ Cf,
              u16* __restrict__ Cb, int K, int lda, int ldb, int ldc)
{
  __shared__ __align__(16) u16 As[2][256 * 32];   // 32 KB
  __shared__ __align__(16) u16 Bs[2][256 * 32];   // 32 KB
  const int tid = threadIdx.x;
  const int lane = tid & 63, wid = tid >> 6;
  const int wm = wid & 3, wn = wid >> 2;          // 4 M-waves x 4 N-waves, 64x64 each
  const int nbx = gridDim.x;
  const int nwg = nbx * gridDim.y;
  int lin = blockIdx.y * nbx + blockIdx.x;
  lin = (lin & 7) * (nwg >> 3) + (lin >> 3);
  const long m0 = (long)(lin / nbx) * 256, n0 = (long)(lin % nbx) * 256;

  const int kcA = (tid & 3) ^ (((tid >> 2) >> 1) & 3);
  const u16* aS0 = A + (m0 + (tid >> 2)) * (long)lda + kcA * 8;
  const u16* bS0 = Bt + (n0 + (tid >> 2)) * (long)ldb + kcA * 8;

  f32x4 acc[4][4] = {};
  const int cl4 = lane & 15;
  const int gph = ((lane >> 4) ^ ((cl4 >> 1) & 3)) * 8;
  const int aro = (wm * 64 + cl4) * 32 + gph;
  const int bro = (wn * 64 + cl4) * 32 + gph;
  const int nt = K >> 5;

#define STAGE_AB2(buf, k0_)                         \
  gl2lds16(aS0 + (k0_), As[buf] + tid * 8);         \
  gl2lds16(bS0 + (k0_), Bs[buf] + tid * 8);

  STAGE_AB2(0, 0);
  for (int t = 0; t < nt; ++t) {
    const int cur = t & 1;
    if (t < nt - 1) {
      STAGE_AB2(cur ^ 1, (t + 1) * 32);
      asm volatile("s_waitcnt vmcnt(2)" ::: "memory");
    } else {
      asm volatile("s_waitcnt vmcnt(0)" ::: "memory");
    }
    __builtin_amdgcn_s_barrier();
    bf16x8 af[4], bfr[4];
#pragma unroll
    for (int i = 0; i < 4; ++i) af[i] = *(const bf16x8*)(As[cur] + aro + i * 16 * 32);
#pragma unroll
    for (int j = 0; j < 4; ++j) bfr[j] = *(const bf16x8*)(Bs[cur] + bro + j * 16 * 32);
    __builtin_amdgcn_s_setprio(1);
#pragma unroll
    for (int i = 0; i < 4; ++i)
#pragma unroll
      for (int j = 0; j < 4; ++j)
        acc[i][j] = mfma16(af[i], bfr[j], acc[i][j]);
    __builtin_amdgcn_s_setprio(0);
    __builtin_amdgcn_s_barrier();
  }
#undef STAGE_AB2
  const int rg = (lane >> 4) * 4, cl = lane & 15;
#pragma unroll
  for (int i = 0; i < 4; ++i) {
#pragma unroll
    for (int j = 0; j < 4; ++j) {
      const long row = m0 + wm * 64 + i * 16 + rg;
      const long col = n0 + wn * 64 + j * 16 + cl;
      const float bv = bias ? bias[col] : 0.0f;
#pragma unroll
      for (int r = 0; r < 4; ++r) {
        float v = acc[i][j][r] + bv;
        long idx = (row + r) * ldc + col;
        if (EPI == 0) Cf[idx] = v;
        else if (EPI == 1) Cb[idx] = f2bf(v);
        else if (EPI == 2) Cf[idx] += v;
        else Cb[idx] = f2bf(gelu_f(v));
      }
    }
  }
}

// ---------------- flash attention: 8 waves, QBLK=128, swapped QK^T, dbuf K/V ----------------
__global__ __launch_bounds__(512)
void attn_k(const u16* __restrict__ qkv, const u16* __restrict__ vt, u16* __restrict__ o)
{
  __shared__ __align__(16) u16 Qs[128 * 64];
  __shared__ __align__(16) u16 Ks[2][64 * 64];
  __shared__ __align__(16) u16 Vts[2][64 * 64];
  const int tid = threadIdx.x, lane = tid & 63, wid = tid >> 6;
  int lin = blockIdx.x;
  lin = (lin & 7) * 128 + (lin >> 3);
  const int qt = lin & 7, hh = (lin >> 3) & 7, b = lin >> 6;
  const long rowbase = (long)b * 1024;
  const long vbase = (((long)b * 8 + hh) * 64) * 1024;
  const int g = lane >> 4, cl = lane & 15;
  u16* Psw = Qs + wid * 1024;

#pragma unroll
  for (int it = 0; it < 2; ++it) {
    int c = tid + it * 512;
    int row = c >> 3, c8s = (c & 7) ^ swz(row);
    gl2lds16(qkv + (rowbase + qt * 128 + row) * 1536 + hh * 192 + c8s * 8, Qs + c * 8);
  }
#define STAGE_KV(buf, kt_)                                                            \
  {                                                                                   \
    int row = tid >> 3, c8s = (tid & 7) ^ swz(row);                                   \
    gl2lds16(qkv + (rowbase + (kt_) * 64 + row) * 1536 + hh * 192 + 64 + c8s * 8,     \
             Ks[buf] + tid * 8);                                                      \
    gl2lds16(vt + vbase + (long)row * 1024 + (kt_) * 64 + c8s * 8, Vts[buf] + tid * 8); \
  }
  STAGE_KV(0, 0);

  float m = -3.0e38f, l = 0.f;
  f32x4 oacc[4] = {};
  const int Rq = wid * 16 + cl, sq = swz(Rq) << 3;
  const int spw = swz(cl) << 3;
  bf16x8 aq[2];

  for (int kt = 0; kt < 16; ++kt) {
    const int cur = kt & 1;
    if (kt < 15) {
      STAGE_KV(cur ^ 1, kt + 1);
      asm volatile("s_waitcnt vmcnt(2)" ::: "memory");
    } else {
      asm volatile("s_waitcnt vmcnt(0)" ::: "memory");
    }
    __builtin_amdgcn_s_barrier();
    if (kt == 0) {
#pragma unroll
      for (int kb = 0; kb < 2; ++kb)
        aq[kb] = *(const bf16x8*)(Qs + Rq * 64 + ((kb * 32 + g * 8) ^ sq));
    }
    f32x4 s[4] = {};
    __builtin_amdgcn_s_setprio(1);
#pragma unroll
    for (int j = 0; j < 4; ++j) {
      const int Rk = j * 16 + cl, sk = swz(Rk) << 3;
#pragma unroll
      for (int kb = 0; kb < 2; ++kb) {
        bf16x8 bk = *(const bf16x8*)(Ks[cur] + Rk * 64 + ((kb * 32 + g * 8) ^ sk));
        s[j] = mfma16(bk, aq[kb], s[j]);
      }
    }
    __builtin_amdgcn_s_setprio(0);
    float mx = s[0][0];
#pragma unroll
    for (int j = 0; j < 4; ++j)
#pragma unroll
      for (int r = 0; r < 4; ++r) mx = fmaxf(mx, s[j][r]);
    mx *= 0.125f;
    mx = fmaxf(mx, __shfl_xor(mx, 16, 64));
    mx = fmaxf(mx, __shfl_xor(mx, 32, 64));
    if (!__all(mx <= m + 8.f)) {
      const float mnew = fmaxf(m, mx);
      const float al = __expf(m - mnew);
      m = mnew;
      l *= al;
      float alr[4];
#pragma unroll
      for (int r = 0; r < 4; ++r) alr[r] = __shfl(al, (lane & 48) | (g * 4 + r), 64);
#pragma unroll
      for (int cb = 0; cb < 4; ++cb) {
        f32x4 t = oacc[cb];
        t[0] *= alr[0]; t[1] *= alr[1]; t[2] *= alr[2]; t[3] *= alr[3];
        oacc[cb] = t;
      }
    }
    float p[4][4], ts = 0.f;
#pragma unroll
    for (int j = 0; j < 4; ++j)
#pragma unroll
      for (int r = 0; r < 4; ++r) {
        p[j][r] = __expf(s[j][r] * 0.125f - m);
        ts += p[j][r];
      }
    ts += __shfl_xor(ts, 16, 64);
    ts += __shfl_xor(ts, 32, 64);
    l += ts;
#pragma unroll
    for (int j = 0; j < 4; ++j) {
      us4 pk;
      pk[0] = f2bf(p[j][0]); pk[1] = f2bf(p[j][1]);
      pk[2] = f2bf(p[j][2]); pk[3] = f2bf(p[j][3]);
      *(us4*)(&Psw[cl * 64 + ((j * 16 + g * 4) ^ spw)]) = pk;
    }
    asm volatile("s_waitcnt lgkmcnt(0)" ::: "memory");
    bf16x8 pa[2];
#pragma unroll
    for (int kb = 0; kb < 2; ++kb)
      pa[kb] = *(const bf16x8*)(&Psw[cl * 64 + ((kb * 32 + g * 8) ^ spw)]);
    __builtin_amdgcn_s_setprio(1);
#pragma unroll
    for (int kb = 0; kb < 2; ++kb)
#pragma unroll
      for (int cb = 0; cb < 4; ++cb) {
        const int ch = cb * 16 + cl;
        bf16x8 vb = *(const bf16x8*)(Vts[cur] + ch * 64 + ((kb * 32 + g * 8) ^ (swz(ch) << 3)));
        oacc[cb] = mfma16(pa[kb], vb, oacc[cb]);
      }
    __builtin_amdgcn_s_setprio(0);
    __builtin_amdgcn_s_barrier();
  }
#undef STAGE_KV
  float lr[4];
#pragma unroll
  for (int r = 0; r < 4; ++r) lr[r] = __shfl(l, (lane & 48) | (g * 4 + r), 64);
#pragma unroll
  for (int cb = 0; cb < 4; ++cb)
#pragma unroll
    for (int r = 0; r < 4; ++r) {
      long row = rowbase + qt * 128 + wid * 16 + g * 4 + r;
      o[row * 512 + hh * 64 + cb * 16 + cl] = f2bf(oacc[cb][r] / lr[r]);
    }
}

// ---------------- LayerNorm, one wave per 512-row. MODE 0: f32->f32, 1: f32->bf16
template <int MODE>
__global__ __launch_bounds__(256)
void ln_k(const float* __restrict__ in_, const float* __restrict__ gg,
          const float* __restrict__ bb, void* __restrict__ out_)
{
  const long row = (long)blockIdx.x * 4 + (threadIdx.x >> 6);
  const int lane = threadIdx.x & 63;
  float x[8];
  const float* p = in_ + row * 512 + lane * 8;
  *(float4*)(x) = *(const float4*)(p);
  *(float4*)(x + 4) = *(const float4*)(p + 4);
  float s = 0.f;
#pragma unroll
  for (int j = 0; j < 8; ++j) s += x[j];
#pragma unroll
  for (int off = 1; off < 64; off <<= 1) s += __shfl_xor(s, off, 64);
  const float mean = s * (1.0f / 512.0f);
  float vs = 0.f;
#pragma unroll
  for (int j = 0; j < 8; ++j) { float d = x[j] - mean; vs += d * d; }
#pragma unroll
  for (int off = 1; off < 64; off <<= 1) vs += __shfl_xor(vs, off, 64);
  const float rstd = rsqrtf(vs * (1.0f / 512.0f) + 1e-5f);
  if (MODE == 0) {
    float y[8];
#pragma unroll
    for (int j = 0; j < 8; ++j)
      y[j] = (x[j] - mean) * rstd * gg[lane * 8 + j] + bb[lane * 8 + j];
    float* q = (float*)out_ + row * 512 + lane * 8;
    *(float4*)(q) = *(const float4*)(y);
    *(float4*)(q + 4) = *(const float4*)(y + 4);
  } else {
    us8 ov;
#pragma unroll
    for (int j = 0; j < 8; ++j)
      ov[j] = f2bf((x[j] - mean) * rstd * gg[lane * 8 + j] + bb[lane * 8 + j]);
    *(us8*)((u16*)out_ + row * 512 + lane * 8) = ov;
  }
}

// ---------------- input embed: h = E[t] + sum_9 scalars*w_in rows + b_in (fp32) ----------------
__global__ __launch_bounds__(256)
void embed_k(const float* __restrict__ x, const float* __restrict__ par,
             const float* __restrict__ E, const float* __restrict__ w_in,
             const float* __restrict__ b_in, float* __restrict__ h)
{
  const long bt = blockIdx.x;
  const int b = (int)(bt >> 10), t = (int)(bt & 1023);
  float xs[9];
#pragma unroll
  for (int c = 0; c < 3; ++c) xs[c] = x[((long)b * 3 + c) * 1024 + t];
#pragma unroll
  for (int c = 0; c < 6; ++c) xs[3 + c] = par[((long)b * 6 + c) * 1024 + t];
  for (int w = threadIdx.x; w < 512; w += 256) {
    float a = E[(long)t * 512 + w] + b_in[w];
#pragma unroll
    for (int c = 0; c < 9; ++c) a += xs[c] * w_in[c * 512 + w];
    h[bt * 512 + w] = a;
  }
}

// ---------------- fp32 -> bf16 transpose [R,C] -> [C,R] (generic) ----------------
__global__ __launch_bounds__(256)
void tr_k(const float* __restrict__ in, u16* __restrict__ out, int R, int C)
{
  __shared__ u16 tile[32][33];
  const int r0 = blockIdx.y * 32, c0 = blockIdx.x * 32;
  const int tx = threadIdx.x & 31, ty = threadIdx.x >> 5;
  for (int rr = ty; rr < 32; rr += 8) tile[rr][tx] = f2bf(in[(long)(r0 + rr) * C + c0 + tx]);
  __syncthreads();
  for (int rr = ty; rr < 32; rr += 8) out[(long)(c0 + rr) * R + r0 + tx] = tile[tx][rr];
}

// ---------------- fused per-layer weight transposes (qkv, pw, fc, fcp) ----------------
__global__ __launch_bounds__(256)
void trL_k(const float* __restrict__ qkv_w, const float* __restrict__ pw,
           const float* __restrict__ fcw, const float* __restrict__ fcpw,
           u16* __restrict__ o_qkv, u16* __restrict__ o_pw,
           u16* __restrict__ o_fc, u16* __restrict__ o_fcp)
{
  __shared__ u16 tile[32][33];
  int bid = blockIdx.x;
  const float* src; u16* dst; int R, C, bx, by;
  if (bid < 768)       { src = qkv_w; dst = o_qkv; R = 512;  C = 1536; bx = bid % 48; by = bid / 48; }
  else if (bid < 1024) { bid -= 768;  src = pw;   dst = o_pw;  R = 512;  C = 512;  bx = bid % 16; by = bid / 16; }
  else if (bid < 2048) { bid -= 1024; src = fcw;  dst = o_fc;  R = 512;  C = 2048; bx = bid % 64; by = bid / 64; }
  else                 { bid -= 2048; src = fcpw; dst = o_fcp; R = 2048; C = 512;  bx = bid % 16; by = bid / 16; }
  const int r0 = by * 32, c0 = bx * 32;
  const int tx = threadIdx.x & 31, ty = threadIdx.x >> 5;
  for (int rr = ty; rr < 32; rr += 8) tile[rr][tx] = f2bf(src[(long)(r0 + rr) * C + c0 + tx]);
  __syncthreads();
  for (int rr = ty; rr < 32; rr += 8) dst[(long)(c0 + rr) * R + r0 + tx] = tile[tx][rr];
}

// ---------------- fp32 -> bf16 cast ----------------
__global__ __launch_bounds__(256)
void cast_k(const float* __restrict__ in, u16* __restrict__ out, long n)
{
  long i = ((long)blockIdx.x * 256 + threadIdx.x) * 4;
  if (i + 3 < n) {
    float4 v = *(const float4*)(in + i);
    out[i] = f2bf(v.x); out[i + 1] = f2bf(v.y); out[i + 2] = f2bf(v.z); out[i + 3] = f2bf(v.w);
  }
}

// ---------------- masked max-pool, two stages ----------------
__global__ __launch_bounds__(256)
void pool1_k(const float* __restrict__ hm, const float* __restrict__ mask, float* __restrict__ part)
{
  const int c = blockIdx.x, b = blockIdx.y;
  const int t0 = c * 128;
  const int w0 = threadIdx.x, w1 = threadIdx.x + 256;
  float m0 = -3.0e38f, m1 = -3.0e38f;
  for (int t = 0; t < 128; ++t) {
    const float mv = mask[b * 1024 + t0 + t];
    const float neg = (1.0f - mv) * (-100000.0f);
    const float* row = hm + ((long)b * 1024 + t0 + t) * 512;
    m0 = fmaxf(m0, row[w0] * mv + neg);
    m1 = fmaxf(m1, row[w1] * mv + neg);
  }
  part[((long)b * 8 + c) * 512 + w0] = m0;
  part[((long)b * 8 + c) * 512 + w1] = m1;
}
__global__ __launch_bounds__(256)
void pool2_k(const float* __restrict__ part, float* __restrict__ pooled)
{
  const int b = blockIdx.y;
  const int w = blockIdx.x * 256 + threadIdx.x;
  float m = -3.0e38f;
#pragma unroll
  for (int c = 0; c < 8; ++c) m = fmaxf(m, part[((long)b * 8 + c) * 512 + w]);
  pooled[b * 512 + w] = m;
}

// ---------------- masked transpose to output h [B,512,T] fp32 ----------------
__global__ __launch_bounds__(256)
void tout_k(const float* __restrict__ hm, const float* __restrict__ mask, float* __restrict__ outh)
{
  __shared__ float tile[64][65];
  const int t0 = blockIdx.x * 64, w0 = blockIdx.y * 64, b = blockIdx.z;
  const int tx = threadIdx.x & 63, ty = threadIdx.x >> 6;
  for (int i = ty; i < 64; i += 4)
    tile[i][tx] = hm[((long)b * 1024 + t0 + i) * 512 + w0 + tx];
  __syncthreads();
  const float mv = mask[b * 1024 + t0 + tx];
  for (int i = ty; i < 64; i += 4)
    outh[((long)b * 512 + w0 + i) * 1024 + t0 + tx] = tile[tx][i] * mv;
}

// ---------------- aggregator matmuls: split-K partials + combine ----------------
__global__ __launch_bounds__(256)
void agg1p_k(const float* __restrict__ pooled, const float* __restrict__ wf,
             float* __restrict__ part)
{
  const int b = blockIdx.z, kc = blockIdx.y;
  const int n = blockIdx.x * 256 + threadIdx.x;
  float acc = 0.f;
  const int k0 = kc * 64;
#pragma unroll 8
  for (int k = 0; k < 64; ++k) acc += pooled[b * 512 + k0 + k] * wf[(long)(k0 + k) * 2048 + n];
  part[((long)b * 8 + kc) * 2048 + n] = acc;
}
__global__ __launch_bounds__(256)
void agg1c_k(const float* __restrict__ part, const float* __restrict__ bf_,
             float* __restrict__ z1)
{
  const int b = blockIdx.y;
  const int n = blockIdx.x * 256 + threadIdx.x;
  float acc = 0.f;
#pragma unroll
  for (int c = 0; c < 8; ++c) acc += part[((long)b * 8 + c) * 2048 + n];
  z1[(long)b * 2048 + n] = gelu_f(acc + bf_[n]);
}
__global__ __launch_bounds__(256)
void agg2p_k(const float* __restrict__ z1, const float* __restrict__ wp,
             float* __restrict__ part)
{
  const int b = blockIdx.z, kc = blockIdx.y;
  const int n = blockIdx.x * 256 + threadIdx.x;
  float acc = 0.f;
  const int k0 = kc * 256;
#pragma unroll 8
  for (int k = 0; k < 256; ++k) acc += z1[(long)b * 2048 + k0 + k] * wp[(long)(k0 + k) * 512 + n];
  part[((long)b * 8 + kc) * 512 + n] = acc;
}
__global__ __launch_bounds__(256)
void agg2c_k(const float* __restrict__ part, const float* __restrict__ bp,
             float* __restrict__ zo)
{
  const int b = blockIdx.y;
  const int n = blockIdx.x * 256 + threadIdx.x;
  float acc = 0.f;
#pragma unroll
  for (int c = 0; c < 8; ++c) acc += part[((long)b * 8 + c) * 512 + n];
  zo[b * 512 + n] = acc + bp[n];
}

extern "C" void kernel_launch(void* const* d_in, const int* in_sizes, int n_in,
                              void* d_out, int out_size, void* d_ws, size_t ws_size,
                              hipStream_t stream)
{
  (void)in_sizes; (void)n_in; (void)out_size; (void)ws_size;
  const float* x        = (const float*)d_in[0];
  const float* params   = (const float*)d_in[1];
  const float* mask     = (const float*)d_in[2];
  const float* class_emb= (const float*)d_in[3];
  const float* w_in     = (const float*)d_in[4];
  const float* b_in     = (const float*)d_in[5];
  const float* ln_pre_g = (const float*)d_in[6];
  const float* ln_pre_b = (const float*)d_in[7];
  const float* qkv_w    = (const float*)d_in[8];
  const float* qkv_b    = (const float*)d_in[9];
  const float* attn_pw  = (const float*)d_in[10];
  const float* attn_pb  = (const float*)d_in[11];
  const float* ln1_g    = (const float*)d_in[12];
  const float* ln1_b    = (const float*)d_in[13];
  const float* fc_w     = (const float*)d_in[14];
  const float* fc_b     = (const float*)d_in[15];
  const float* fcp_w    = (const float*)d_in[16];
  const float* fcp_b    = (const float*)d_in[17];
  const float* ln2_g    = (const float*)d_in[18];
  const float* ln2_b    = (const float*)d_in[19];
  const float* ln_post_g= (const float*)d_in[20];
  const float* ln_post_b= (const float*)d_in[21];
  const float* w_out    = (const float*)d_in[22];
  const float* b_out    = (const float*)d_in[23];
  const float* agg_fc_w = (const float*)d_in[24];
  const float* agg_fc_b = (const float*)d_in[25];
  const float* agg_pw   = (const float*)d_in[26];
  const float* agg_pb   = (const float*)d_in[27];

  float* out_f = (float*)d_out;          // z: [0, 16384)
  float* out_h = out_f + 16384;          // h: 64 MiB fp32 region
  u16* sc = (u16*)out_h;                 // bf16 scratch: up to 16384x2048 (64 MiB)

  // ---- workspace layout (~128 MiB) ----
  char* ws = (char*)d_ws;
  float* hf = (float*)ws;       ws += (size_t)32768 * 512 * 4;
  u16* hn = (u16*)ws;           ws += (size_t)32768 * 512 * 2;
  float* E = (float*)ws;        ws += (size_t)1024 * 512 * 4;
  u16* ce_b = (u16*)ws;         ws += (size_t)1024 * 1024 * 2;
  u16* wt_qkv = (u16*)ws;       ws += (size_t)1536 * 512 * 2;
  u16* wt_pw  = (u16*)ws;       ws += (size_t)512 * 512 * 2;
  u16* wt_fc  = (u16*)ws;       ws += (size_t)2048 * 512 * 2;
  u16* wt_fcp = (u16*)ws;       ws += (size_t)512 * 2048 * 2;
  u16* w_in_t = (u16*)ws;       ws += (size_t)512 * 1024 * 2;
  u16* w_out_t= (u16*)ws;       ws += (size_t)512 * 512 * 2;
  float* pooled = (float*)ws;   ws += (size_t)32 * 512 * 4;
  float* z1     = (float*)ws;   ws += (size_t)32 * 2048 * 4;
  float* part   = (float*)ws;   ws += (size_t)32 * 8 * 512 * 4;
  float* apart1 = (float*)ws;   ws += (size_t)32 * 8 * 2048 * 4;
  float* apart2 = (float*)ws;   ws += (size_t)32 * 8 * 512 * 4;
  u16* vt       = (u16*)ws;     ws += (size_t)16 * 8 * 64 * 1024 * 2;

  // one-time converts + class-emb projection + embed + ln_pre
  cast_k<<<1024, 256, 0, stream>>>(class_emb, ce_b, 1024 * 1024);
  tr_k<<<dim3(16, 32), 256, 0, stream>>>(w_in + 9 * 512, w_in_t, 1024, 512);
  tr_k<<<dim3(16, 16), 256, 0, stream>>>(w_out, w_out_t, 512, 512);
  gemm_bt<0><<<dim3(4, 4), 512, 0, stream>>>(ce_b, w_in_t, nullptr, E, nullptr, nullptr,
                                             1024, 1024, 1024, 512);
  embed_k<<<32768, 256, 0, stream>>>(x, params, E, w_in, b_in, hf);
  ln_k<0><<<8192, 256, 0, stream>>>(hf, ln_pre_g, ln_pre_b, hf);

  for (int l = 0; l < 12; ++l) {
    trL_k<<<3072, 256, 0, stream>>>(qkv_w + (size_t)l * 512 * 1536,
                                    attn_pw + (size_t)l * 512 * 512,
                                    fc_w + (size_t)l * 512 * 2048,
                                    fcp_w + (size_t)l * 2048 * 512,
                                    wt_qkv, wt_pw, wt_fc, wt_fcp);

    // LN1 full batch -> hn (bf16)
    ln_k<1><<<8192, 256, 0, stream>>>(hf, ln1_g + l * 512, ln1_b + l * 512, hn);
    // QKV (V written transposed to vt) + attention per batch-half; attn-out overwrites hn half
    for (int half = 0; half < 2; ++half) {
      const size_t ro = (size_t)half * 16384;
      gemm_bt<4><<<dim3(12, 64), 512, 0, stream>>>(hn + ro * 512, wt_qkv, qkv_b + l * 1536,
                                                   nullptr, sc, vt, 512, 512, 512, 1536);
      attn_k<<<1024, 512, 0, stream>>>(sc, vt, hn + ro * 512);
    }
    // attn projection full batch: h += hn @ pw^T + b
    gemm_bt<2><<<dim3(4, 128), 512, 0, stream>>>(hn, wt_pw, attn_pb + l * 512,
                                                 hf, nullptr, nullptr, 512, 512, 512, 512);
    // LN2 full batch -> hn
    ln_k<1><<<8192, 256, 0, stream>>>(hf, ln2_g + l * 512, ln2_b + l * 512, hn);
    // FF per batch-half: fc uses 256x256/16-wave (512 blocks = one full round)
    for (int half = 0; half < 2; ++half) {
      const size_t ro = (size_t)half * 16384;
      gemm_bt2<3><<<dim3(8, 64), 1024, 0, stream>>>(hn + ro * 512, wt_fc, fc_b + l * 2048,
                                                    nullptr, sc, 512, 512, 512, 2048);
      gemm_bt<2><<<dim3(4, 64), 512, 0, stream>>>(sc, wt_fcp, fcp_b + l * 512,
                                                  hf + ro * 512, nullptr, nullptr, 2048, 2048, 2048, 512);
    }
  }

  // final LN + out-proj, then pool/agg, then h output
  ln_k<1><<<8192, 256, 0, stream>>>(hf, ln_post_g, ln_post_b, hn);
  gemm_bt<0><<<dim3(4, 128), 512, 0, stream>>>(hn, w_out_t, b_out, hf, nullptr, nullptr,
                                               512, 512, 512, 512);
  pool1_k<<<dim3(8, 32), 256, 0, stream>>>(hf, mask, part);
  pool2_k<<<dim3(2, 32), 256, 0, stream>>>(part, pooled);
  agg1p_k<<<dim3(8, 8, 32), 256, 0, stream>>>(pooled, agg_fc_w, apart1);
  agg1c_k<<<dim3(8, 32), 256, 0, stream>>>(apart1, agg_fc_b, z1);
  agg2p_k<<<dim3(2, 8, 32), 256, 0, stream>>>(z1, agg_pw, apart2);
  agg2c_k<<<dim3(2, 32), 256, 0, stream>>>(apart2, agg_pb, out_f);
  tout_k<<<dim3(16, 8, 32), 256, 0, stream>>>(hf, mask, out_h);
}

// Round 17
// 6435.526 us; speedup vs baseline: 2.1420x; 1.0128x over previous
//
#include <hip/hip_runtime.h>
#include <hip/hip_bf16.h>

// PartCodeTransformer forward on MI355X (gfx950).
// I/O fp32; internal bf16 MFMA + fp32 accum/residual.
// Round 17: attn LDS 48->40KB (Q direct-to-registers, P compacted 16x32/wave with
// kb-split PV) -> 4 blocks/CU, grid 1024 = exactly one residency round. fcp uses
// 128x128 4-wave variant (512 blocks = 2/CU). All prior techniques retained.

typedef unsigned short u16;
typedef unsigned int u32;
typedef __attribute__((ext_vector_type(8))) short bf16x8;
typedef __attribute__((ext_vector_type(8))) unsigned short us8;
typedef __attribute__((ext_vector_type(4))) unsigned short us4;
typedef __attribute__((ext_vector_type(4))) float f32x4;

__device__ __forceinline__ float bf2f(u16 s) {
  union { u32 u; float f; } c; c.u = ((u32)s) << 16; return c.f;
}
__device__ __forceinline__ u16 f2bf(float f) {
  __hip_bfloat16 h = __float2bfloat16(f);   // hardware RNE cvt
  union { __hip_bfloat16 h; u16 u; } c; c.h = h; return c.u;
}
__device__ __forceinline__ float gelu_f(float v) {
  return 0.5f * v * (1.0f + erff(v * 0.7071067811865475f));
}
__device__ __forceinline__ void gl2lds16(const u16* g, u16* l) {
  __builtin_amdgcn_global_load_lds((const __attribute__((address_space(1))) void*)g,
                                   (__attribute__((address_space(3))) void*)l, 16, 0, 0);
}
__device__ __forceinline__ f32x4 mfma16(bf16x8 a, bf16x8 b, f32x4 c) {
  return __builtin_amdgcn_mfma_f32_16x16x32_bf16(a, b, c, 0, 0, 0);
}
// chunk swizzle for 128B rows (attn K/V): permute 16B chunks within the row
__device__ __forceinline__ int swz(int row) { return (row ^ (row >> 3)) & 7; }

// ------------- A[M,K](lda) x Bt[N,K](ldb) GEMM, 256x128 tile, 8 waves, 2-phase dbuf -------------
// LDS swizzle: phys_chunk = log_chunk ^ ((row>>1)&3).
// EPI: 0 f32=v ; 1 bf16=v ; 2 f32+=v ; 3 bf16=gelu(v) ; 4 qkv: Q/K->Cb, V->Vt transposed
template <int EPI>
__global__ __launch_bounds__(512)
void gemm_bt(const u16* __restrict__ A, const u16* __restrict__ Bt,
             const float* __restrict__ bias, float* __restrict__ Cf,
             u16* __restrict__ Cb, u16* __restrict__ Vt, int K, int lda, int ldb, int ldc)
{
  __shared__ __align__(16) u16 As[2][256 * 32];   // 32 KB
  __shared__ __align__(16) u16 Bs[2][128 * 32];   // 16 KB
  const int tid = threadIdx.x;
  const int lane = tid & 63, wid = tid >> 6;
  const int wm = wid & 3, wn = wid >> 2;          // 4 M-waves x 2 N-waves
  const int nbx = gridDim.x;
  const int nwg = nbx * gridDim.y;
  int lin = blockIdx.y * nbx + blockIdx.x;
  lin = (lin & 7) * (nwg >> 3) + (lin >> 3);
  const long m0 = (long)(lin / nbx) * 256, n0 = (long)(lin % nbx) * 128;

  const int c0 = tid, c1 = tid + 512;
  const int kc0 = (c0 & 3) ^ (((c0 >> 2) >> 1) & 3);
  const int kc1 = (c1 & 3) ^ (((c1 >> 2) >> 1) & 3);
  const int kcb = (tid & 3) ^ (((tid >> 2) >> 1) & 3);
  const u16* aS0 = A + (m0 + (c0 >> 2)) * (long)lda + kc0 * 8;
  const u16* aS1 = A + (m0 + (c1 >> 2)) * (long)lda + kc1 * 8;
  const u16* bS0 = Bt + (n0 + (tid >> 2)) * (long)ldb + kcb * 8;

  f32x4 acc[4][4] = {};
  const int cl4 = lane & 15;
  const int gph = ((lane >> 4) ^ ((cl4 >> 1) & 3)) * 8;
  const int aro = (wm * 64 + cl4) * 32 + gph;
  const int bro = (wn * 64 + cl4) * 32 + gph;
  const int nt = K >> 5;

#define STAGE_AB(buf, k0_)                          \
  gl2lds16(aS0 + (k0_), As[buf] + c0 * 8);          \
  gl2lds16(aS1 + (k0_), As[buf] + c1 * 8);          \
  gl2lds16(bS0 + (k0_), Bs[buf] + tid * 8);

  STAGE_AB(0, 0);
  for (int t = 0; t < nt; ++t) {
    const int cur = t & 1;
    if (t < nt - 1) {
      STAGE_AB(cur ^ 1, (t + 1) * 32);
      asm volatile("s_waitcnt vmcnt(3)" ::: "memory");
    } else {
      asm volatile("s_waitcnt vmcnt(0)" ::: "memory");
    }
    __builtin_amdgcn_s_barrier();
    bf16x8 af[4], bfr[4];
#pragma unroll
    for (int i = 0; i < 4; ++i) af[i] = *(const bf16x8*)(As[cur] + aro + i * 16 * 32);
#pragma unroll
    for (int j = 0; j < 4; ++j) bfr[j] = *(const bf16x8*)(Bs[cur] + bro + j * 16 * 32);
    __builtin_amdgcn_s_setprio(1);
#pragma unroll
    for (int i = 0; i < 4; ++i)
#pragma unroll
      for (int j = 0; j < 4; ++j)
        acc[i][j] = mfma16(af[i], bfr[j], acc[i][j]);
    __builtin_amdgcn_s_setprio(0);
    __builtin_amdgcn_s_barrier();
  }
#undef STAGE_AB
  const int rg = (lane >> 4) * 4, cl = lane & 15;
#pragma unroll
  for (int i = 0; i < 4; ++i) {
#pragma unroll
    for (int j = 0; j < 4; ++j) {
      const long row = m0 + wm * 64 + i * 16 + rg;
      const long col = n0 + wn * 64 + j * 16 + cl;
      const float bv = bias ? bias[col] : 0.0f;
      if (EPI == 4) {
        const int hh = (int)col / 192, off = (int)col - hh * 192;
        if (off < 128) {
#pragma unroll
          for (int r = 0; r < 4; ++r)
            Cb[(row + r) * ldc + col] = f2bf(acc[i][j][r] + bv);
        } else {
          us4 pk;
#pragma unroll
          for (int r = 0; r < 4; ++r) pk[r] = f2bf(acc[i][j][r] + bv);
          const long bl = row >> 10, t0 = row & 1023;
          *(us4*)(Vt + (((bl * 8 + hh) * 64 + (off - 128)) << 10) + t0) = pk;
        }
      } else {
#pragma unroll
        for (int r = 0; r < 4; ++r) {
          float v = acc[i][j][r] + bv;
          long idx = (row + r) * ldc + col;
          if (EPI == 0) Cf[idx] = v;
          else if (EPI == 1) Cb[idx] = f2bf(v);
          else if (EPI == 2) Cf[idx] += v;
          else Cb[idx] = f2bf(gelu_f(v));
        }
      }
    }
  }
}

// ------------- 128x128 tile, 4 waves (256 thr), 2-phase dbuf — for fcp (more blocks/CU) -------------
template <int EPI>
__global__ __launch_bounds__(256)
void gemm_bt1(const u16* __restrict__ A, const u16* __restrict__ Bt,
              const float* __restrict__ bias, float* __restrict__ Cf,
              u16* __restrict__ Cb, int K, int lda, int ldb, int ldc)
{
  __shared__ __align__(16) u16 As[2][128 * 32];   // 16 KB
  __shared__ __align__(16) u16 Bs[2][128 * 32];   // 16 KB
  const int tid = threadIdx.x;
  const int lane = tid & 63, wid = tid >> 6;
  const int wm = wid >> 1, wn = wid & 1;          // 2x2 waves, 64x64 each
  const int nbx = gridDim.x;
  const int nwg = nbx * gridDim.y;
  int lin = blockIdx.y * nbx + blockIdx.x;
  lin = (lin & 7) * (nwg >> 3) + (lin >> 3);
  const long m0 = (long)(lin / nbx) * 128, n0 = (long)(lin % nbx) * 128;

  const int c0 = tid, c1 = tid + 256;
  const int kc0 = (c0 & 3) ^ (((c0 >> 2) >> 1) & 3);
  const int kc1 = (c1 & 3) ^ (((c1 >> 2) >> 1) & 3);
  const u16* aS0 = A + (m0 + (c0 >> 2)) * (long)lda + kc0 * 8;
  const u16* aS1 = A + (m0 + (c1 >> 2)) * (long)lda + kc1 * 8;
  const u16* bS0 = Bt + (n0 + (c0 >> 2)) * (long)ldb + kc0 * 8;
  const u16* bS1 = Bt + (n0 + (c1 >> 2)) * (long)ldb + kc1 * 8;

  f32x4 acc[4][4] = {};
  const int cl4 = lane & 15;
  const int gph = ((lane >> 4) ^ ((cl4 >> 1) & 3)) * 8;
  const int aro = (wm * 64 + cl4) * 32 + gph;
  const int bro = (wn * 64 + cl4) * 32 + gph;
  const int nt = K >> 5;

#define STAGE_AB1(buf, k0_)                         \
  gl2lds16(aS0 + (k0_), As[buf] + c0 * 8);          \
  gl2lds16(aS1 + (k0_), As[buf] + c1 * 8);          \
  gl2lds16(bS0 + (k0_), Bs[buf] + c0 * 8);          \
  gl2lds16(bS1 + (k0_), Bs[buf] + c1 * 8);

  STAGE_AB1(0, 0);
  for (int t = 0; t < nt; ++t) {
    const int cur = t & 1;
    if (t < nt - 1) {
      STAGE_AB1(cur ^ 1, (t + 1) * 32);
      asm volatile("s_waitcnt vmcnt(4)" ::: "memory");
    } else {
      asm volatile("s_waitcnt vmcnt(0)" ::: "memory");
    }
    __builtin_amdgcn_s_barrier();
    bf16x8 af[4], bfr[4];
#pragma unroll
    for (int i = 0; i < 4; ++i) af[i] = *(const bf16x8*)(As[cur] + aro + i * 16 * 32);
#pragma unroll
    for (int j = 0; j < 4; ++j) bfr[j] = *(const bf16x8*)(Bs[cur] + bro + j * 16 * 32);
    __builtin_amdgcn_s_setprio(1);
#pragma unroll
    for (int i = 0; i < 4; ++i)
#pragma unroll
      for (int j = 0; j < 4; ++j)
        acc[i][j] = mfma16(af[i], bfr[j], acc[i][j]);
    __builtin_amdgcn_s_setprio(0);
    __builtin_amdgcn_s_barrier();
  }
#undef STAGE_AB1
  const int rg = (lane >> 4) * 4, cl = lane & 15;
#pragma unroll
  for (int i = 0; i < 4; ++i) {
#pragma unroll
    for (int j = 0; j < 4; ++j) {
      const long row = m0 + wm * 64 + i * 16 + rg;
      const long col = n0 + wn * 64 + j * 16 + cl;
      const float bv = bias ? bias[col] : 0.0f;
#pragma unroll
      for (int r = 0; r < 4; ++r) {
        float v = acc[i][j][r] + bv;
        long idx = (row + r) * ldc + col;
        if (EPI == 0) Cf[idx] = v;
        else if (EPI == 1) Cb[idx] = f2bf(v);
        else if (EPI == 2) Cf[idx] += v;
        else Cb[idx] = f2bf(gelu_f(v));
      }
    }
  }
}

// ------------- 256x256 tile, 16 waves (1024 thr), 2-phase dbuf — for fc (EPI=3) -------------
template <int EPI>
__global__ __launch_bounds__(1024)
void gemm_bt2(const u16* __restrict__ A, const u16* __restrict__ Bt,
              const float* __restrict__ bias, float* __restrict__ Cf,
              u16* __restrict__ Cb, int K, int lda, int ldb, int ldc)
{
  __shared__ __align__(16) u16 As[2][256 * 32];   // 32 KB
  __shared__ __align__(16) u16 Bs[2][256 * 32];   // 32 KB
  const int tid = threadIdx.x;
  const int lane = tid & 63, wid = tid >> 6;
  const int wm = wid & 3, wn = wid >> 2;          // 4x4 waves
  const int nbx = gridDim.x;
  const int nwg = nbx * gridDim.y;
  int lin = blockIdx.y * nbx + blockIdx.x;
  lin = (lin & 7) * (nwg >> 3) + (lin >> 3);
  const long m0 = (long)(lin / nbx) * 256, n0 = (long)(lin % nbx) * 256;

  const int kcA = (tid & 3) ^ (((tid >> 2) >> 1) & 3);
  const u16* aS0 = A + (m0 + (tid >> 2)) * (long)lda + kcA * 8;
  const u16* bS0 = Bt + (n0 + (tid >> 2)) * (long)ldb + kcA * 8;

  f32x4 acc[4][4] = {};
  const int cl4 = lane & 15;
  const int gph = ((lane >> 4) ^ ((cl4 >> 1) & 3)) * 8;
  const int aro = (wm * 64 + cl4) * 32 + gph;
  const int bro = (wn * 64 + cl4) * 32 + gph;
  const int nt = K >> 5;

#define STAGE_AB2(buf, k0_)                         \
  gl2lds16(aS0 + (k0_), As[buf] + tid * 8);         \
  gl2lds16(bS0 + (k0_), Bs[buf] + tid * 8);

  STAGE_AB2(0, 0);
  for (int t = 0; t < nt; ++t) {
    const int cur = t & 1;
    if (t < nt - 1) {
      STAGE_AB2(cur ^ 1, (t + 1) * 32);
      asm volatile("s_waitcnt vmcnt(2)" ::: "memory");
    } else {
      asm volatile("s_waitcnt vmcnt(0)" ::: "memory");
    }
    __builtin_amdgcn_s_barrier();
    bf16x8 af[4], bfr[4];
#pragma unroll
    for (int i = 0; i < 4; ++i) af[i] = *(const bf16x8*)(As[cur] + aro + i * 16 * 32);
#pragma unroll
    for (int j = 0; j < 4; ++j) bfr[j] = *(const bf16x8*)(Bs[cur] + bro + j * 16 * 32);
    __builtin_amdgcn_s_setprio(1);
#pragma unroll
    for (int i = 0; i < 4; ++i)
#pragma unroll
      for (int j = 0; j < 4; ++j)
        acc[i][j] = mfma16(af[i], bfr[j], acc[i][j]);
    __builtin_amdgcn_s_setprio(0);
    __builtin_amdgcn_s_barrier();
  }
#undef STAGE_AB2
  const int rg = (lane >> 4) * 4, cl = lane & 15;
#pragma unroll
  for (int i = 0; i < 4; ++i) {
#pragma unroll
    for (int j = 0; j < 4; ++j) {
      const long row = m0 + wm * 64 + i * 16 + rg;
      const long col = n0 + wn * 64 + j * 16 + cl;
      const float bv = bias ? bias[col] : 0.0f;
#pragma unroll
      for (int r = 0; r < 4; ++r) {
        float v = acc[i][j][r] + bv;
        long idx = (row + r) * ldc + col;
        if (EPI == 0) Cf[idx] = v;
        else if (EPI == 1) Cb[idx] = f2bf(v);
        else if (EPI == 2) Cf[idx] += v;
        else Cb[idx] = f2bf(gelu_f(v));
      }
    }
  }
}

// ---------------- flash attention: 8 waves, QBLK=128, 40KB LDS (4 blocks/CU) ----------------
// Q direct-to-registers; P compact per-wave 16x32 with kb-split PV.
__global__ __launch_bounds__(512)
void attn_k(const u16* __restrict__ qkv, const u16* __restrict__ vt, u16* __restrict__ o)
{
  __shared__ __align__(16) u16 Ks[2][64 * 64];   // 16 KB
  __shared__ __align__(16) u16 Vts[2][64 * 64];  // 16 KB
  __shared__ __align__(16) u16 Ps[8][512];       // 8 KB: per-wave 16q x 32k
  const int tid = threadIdx.x, lane = tid & 63, wid = tid >> 6;
  int lin = blockIdx.x;
  lin = (lin & 7) * 128 + (lin >> 3);            // T1 chunked swizzle (1024 blocks)
  const int qt = lin & 7, hh = (lin >> 3) & 7, b = lin >> 6;
  const long rowbase = (long)b * 1024;
  const long vbase = (((long)b * 8 + hh) * 64) * 1024;
  const int g = lane >> 4, cl = lane & 15;
  u16* Psw = Ps[wid];
  const int Rq = wid * 16 + cl;
  const int sw2 = ((cl >> 1) & 3) << 3;          // P swizzle: XOR s on bits 3-4 of u16 idx

  // Q fragments direct from global (issued before staging; landed by first vmcnt(2))
  bf16x8 aq[2];
  {
    const u16* qp = qkv + (rowbase + qt * 128 + Rq) * 1536 + hh * 192 + g * 8;
    aq[0] = *(const bf16x8*)(qp);
    aq[1] = *(const bf16x8*)(qp + 32);
  }
#define STAGE_KV(buf, kt_)                                                            \
  {                                                                                   \
    int row = tid >> 3, c8s = (tid & 7) ^ swz(row);                                   \
    gl2lds16(qkv + (rowbase + (kt_) * 64 + row) * 1536 + hh * 192 + 64 + c8s * 8,     \
             Ks[buf] + tid * 8);                                                      \
    gl2lds16(vt + vbase + (long)row * 1024 + (kt_) * 64 + c8s * 8, Vts[buf] + tid * 8); \
  }
  STAGE_KV(0, 0);

  float m = -3.0e38f, l = 0.f;
  f32x4 oacc[4] = {};

  for (int kt = 0; kt < 16; ++kt) {
    const int cur = kt & 1;
    if (kt < 15) {
      STAGE_KV(cur ^ 1, kt + 1);
      asm volatile("s_waitcnt vmcnt(2)" ::: "memory");  // aq+stage(kt) landed; stage(kt+1) in flight
    } else {
      asm volatile("s_waitcnt vmcnt(0)" ::: "memory");
    }
    __builtin_amdgcn_s_barrier();                       // all waves' stage(kt) landed
    // QK^T swapped: s[j] = S^T[k = j*16 + g*4 + r][q = cl]
    f32x4 s[4] = {};
    __builtin_amdgcn_s_setprio(1);
#pragma unroll
    for (int j = 0; j < 4; ++j) {
      const int Rk = j * 16 + cl, sk = swz(Rk) << 3;
#pragma unroll
      for (int kb = 0; kb < 2; ++kb) {
        bf16x8 bk = *(const bf16x8*)(Ks[cur] + Rk * 64 + ((kb * 32 + g * 8) ^ sk));
        s[j] = mfma16(bk, aq[kb], s[j]);
      }
    }
    __builtin_amdgcn_s_setprio(0);
    // lane-local softmax for q = cl over 16 k-values (+2-step cross-g reduce)
    float mx = s[0][0];
#pragma unroll
    for (int j = 0; j < 4; ++j)
#pragma unroll
      for (int r = 0; r < 4; ++r) mx = fmaxf(mx, s[j][r]);
    mx *= 0.125f;
    mx = fmaxf(mx, __shfl_xor(mx, 16, 64));
    mx = fmaxf(mx, __shfl_xor(mx, 32, 64));
    // defer-max (T13): rescale only when some row's max grew past THR=8
    if (!__all(mx <= m + 8.f)) {
      const float mnew = fmaxf(m, mx);
      const float al = __expf(m - mnew);
      m = mnew;
      l *= al;
      float alr[4];
#pragma unroll
      for (int r = 0; r < 4; ++r) alr[r] = __shfl(al, (lane & 48) | (g * 4 + r), 64);
#pragma unroll
      for (int cb = 0; cb < 4; ++cb) {
        f32x4 t = oacc[cb];
        t[0] *= alr[0]; t[1] *= alr[1]; t[2] *= alr[2]; t[3] *= alr[3];
        oacc[cb] = t;
      }
    }
    float p[4][4], ts = 0.f;
#pragma unroll
    for (int j = 0; j < 4; ++j)
#pragma unroll
      for (int r = 0; r < 4; ++r) {
        p[j][r] = __expf(s[j][r] * 0.125f - m);
        ts += p[j][r];
      }
    ts += __shfl_xor(ts, 16, 64);
    ts += __shfl_xor(ts, 32, 64);
    l += ts;
    // PV in two kb rounds through the compact per-wave P buffer
#pragma unroll
    for (int kb = 0; kb < 2; ++kb) {
#pragma unroll
      for (int jj = 0; jj < 2; ++jj) {
        us4 pk;
        pk[0] = f2bf(p[2 * kb + jj][0]); pk[1] = f2bf(p[2 * kb + jj][1]);
        pk[2] = f2bf(p[2 * kb + jj][2]); pk[3] = f2bf(p[2 * kb + jj][3]);
        *(us4*)(&Psw[cl * 32 + ((jj * 16 + g * 4) ^ sw2)]) = pk;
      }
      asm volatile("s_waitcnt lgkmcnt(0)" ::: "memory");  // within-wave P write->read ordering
      bf16x8 pa = *(const bf16x8*)(&Psw[cl * 32 + ((g * 8) ^ sw2)]);
      __builtin_amdgcn_s_setprio(1);
#pragma unroll
      for (int cb = 0; cb < 4; ++cb) {
        const int ch = cb * 16 + cl;
        bf16x8 vb = *(const bf16x8*)(Vts[cur] + ch * 64 + ((kb * 32 + g * 8) ^ (swz(ch) << 3)));
        oacc[cb] = mfma16(pa, vb, oacc[cb]);
      }
      __builtin_amdgcn_s_setprio(0);
    }
    __builtin_amdgcn_s_barrier();                       // compute(kt) done; next STAGE may overwrite
  }
#undef STAGE_KV
  // final l for oacc rows q = g*4+r
  float lr[4];
#pragma unroll
  for (int r = 0; r < 4; ++r) lr[r] = __shfl(l, (lane & 48) | (g * 4 + r), 64);
#pragma unroll
  for (int cb = 0; cb < 4; ++cb)
#pragma unroll
    for (int r = 0; r < 4; ++r) {
      long row = rowbase + qt * 128 + wid * 16 + g * 4 + r;
      o[row * 512 + hh * 64 + cb * 16 + cl] = f2bf(oacc[cb][r] / lr[r]);
    }
}

// ---------------- LayerNorm, one wave per 512-row. MODE 0: f32->f32, 1: f32->bf16
template <int MODE>
__global__ __launch_bounds__(256)
void ln_k(const float* __restrict__ in_, const float* __restrict__ gg,
          const float* __restrict__ bb, void* __restrict__ out_)
{
  const long row = (long)blockIdx.x * 4 + (threadIdx.x >> 6);
  const int lane = threadIdx.x & 63;
  float x[8];
  const float* p = in_ + row * 512 + lane * 8;
  *(float4*)(x) = *(const float4*)(p);
  *(float4*)(x + 4) = *(const float4*)(p + 4);
  float s = 0.f;
#pragma unroll
  for (int j = 0; j < 8; ++j) s += x[j];
#pragma unroll
  for (int off = 1; off < 64; off <<= 1) s += __shfl_xor(s, off, 64);
  const float mean = s * (1.0f / 512.0f);
  float vs = 0.f;
#pragma unroll
  for (int j = 0; j < 8; ++j) { float d = x[j] - mean; vs += d * d; }
#pragma unroll
  for (int off = 1; off < 64; off <<= 1) vs += __shfl_xor(vs, off, 64);
  const float rstd = rsqrtf(vs * (1.0f / 512.0f) + 1e-5f);
  if (MODE == 0) {
    float y[8];
#pragma unroll
    for (int j = 0; j < 8; ++j)
      y[j] = (x[j] - mean) * rstd * gg[lane * 8 + j] + bb[lane * 8 + j];
    float* q = (float*)out_ + row * 512 + lane * 8;
    *(float4*)(q) = *(const float4*)(y);
    *(float4*)(q + 4) = *(const float4*)(y + 4);
  } else {
    us8 ov;
#pragma unroll
    for (int j = 0; j < 8; ++j)
      ov[j] = f2bf((x[j] - mean) * rstd * gg[lane * 8 + j] + bb[lane * 8 + j]);
    *(us8*)((u16*)out_ + row * 512 + lane * 8) = ov;
  }
}

// ---------------- input embed: h = E[t] + sum_9 scalars*w_in rows + b_in (fp32) ----------------
__global__ __launch_bounds__(256)
void embed_k(const float* __restrict__ x, const float* __restrict__ par,
             const float* __restrict__ E, const float* __restrict__ w_in,
             const float* __restrict__ b_in, float* __restrict__ h)
{
  const long bt = blockIdx.x;
  const int b = (int)(bt >> 10), t = (int)(bt & 1023);
  float xs[9];
#pragma unroll
  for (int c = 0; c < 3; ++c) xs[c] = x[((long)b * 3 + c) * 1024 + t];
#pragma unroll
  for (int c = 0; c < 6; ++c) xs[3 + c] = par[((long)b * 6 + c) * 1024 + t];
  for (int w = threadIdx.x; w < 512; w += 256) {
    float a = E[(long)t * 512 + w] + b_in[w];
#pragma unroll
    for (int c = 0; c < 9; ++c) a += xs[c] * w_in[c * 512 + w];
    h[bt * 512 + w] = a;
  }
}

// ---------------- fp32 -> bf16 transpose [R,C] -> [C,R] (generic) ----------------
__global__ __launch_bounds__(256)
void tr_k(const float* __restrict__ in, u16* __restrict__ out, int R, int C)
{
  __shared__ u16 tile[32][33];
  const int r0 = blockIdx.y * 32, c0 = blockIdx.x * 32;
  const int tx = threadIdx.x & 31, ty = threadIdx.x >> 5;
  for (int rr = ty; rr < 32; rr += 8) tile[rr][tx] = f2bf(in[(long)(r0 + rr) * C + c0 + tx]);
  __syncthreads();
  for (int rr = ty; rr < 32; rr += 8) out[(long)(c0 + rr) * R + r0 + tx] = tile[tx][rr];
}

// ---------------- fused per-layer weight transposes (qkv, pw, fc, fcp) ----------------
__global__ __launch_bounds__(256)
void trL_k(const float* __restrict__ qkv_w, const float* __restrict__ pw,
           const float* __restrict__ fcw, const float* __restrict__ fcpw,
           u16* __restrict__ o_qkv, u16* __restrict__ o_pw,
           u16* __restrict__ o_fc, u16* __restrict__ o_fcp)
{
  __shared__ u16 tile[32][33];
  int bid = blockIdx.x;
  const float* src; u16* dst; int R, C, bx, by;
  if (bid < 768)       { src = qkv_w; dst = o_qkv; R = 512;  C = 1536; bx = bid % 48; by = bid / 48; }
  else if (bid < 1024) { bid -= 768;  src = pw;   dst = o_pw;  R = 512;  C = 512;  bx = bid % 16; by = bid / 16; }
  else if (bid < 2048) { bid -= 1024; src = fcw;  dst = o_fc;  R = 512;  C = 2048; bx = bid % 64; by = bid / 64; }
  else                 { bid -= 2048; src = fcpw; dst = o_fcp; R = 2048; C = 512;  bx = bid % 16; by = bid / 16; }
  const int r0 = by * 32, c0 = bx * 32;
  const int tx = threadIdx.x & 31, ty = threadIdx.x >> 5;
  for (int rr = ty; rr < 32; rr += 8) tile[rr][tx] = f2bf(src[(long)(r0 + rr) * C + c0 + tx]);
  __syncthreads();
  for (int rr = ty; rr < 32; rr += 8) dst[(long)(c0 + rr) * R + r0 + tx] = tile[tx][rr];
}

// ---------------- fp32 -> bf16 cast ----------------
__global__ __launch_bounds__(256)
void cast_k(const float* __restrict__ in, u16* __restrict__ out, long n)
{
  long i = ((long)blockIdx.x * 256 + threadIdx.x) * 4;
  if (i + 3 < n) {
    float4 v = *(const float4*)(in + i);
    out[i] = f2bf(v.x); out[i + 1] = f2bf(v.y); out[i + 2] = f2bf(v.z); out[i + 3] = f2bf(v.w);
  }
}

// ---------------- masked max-pool, two stages ----------------
__global__ __launch_bounds__(256)
void pool1_k(const float* __restrict__ hm, const float* __restrict__ mask, float* __restrict__ part)
{
  const int c = blockIdx.x, b = blockIdx.y;
  const int t0 = c * 128;
  const int w0 = threadIdx.x, w1 = threadIdx.x + 256;
  float m0 = -3.0e38f, m1 = -3.0e38f;
  for (int t = 0; t < 128; ++t) {
    const float mv = mask[b * 1024 + t0 + t];
    const float neg = (1.0f - mv) * (-100000.0f);
    const float* row = hm + ((long)b * 1024 + t0 + t) * 512;
    m0 = fmaxf(m0, row[w0] * mv + neg);
    m1 = fmaxf(m1, row[w1] * mv + neg);
  }
  part[((long)b * 8 + c) * 512 + w0] = m0;
  part[((long)b * 8 + c) * 512 + w1] = m1;
}
__global__ __launch_bounds__(256)
void pool2_k(const float* __restrict__ part, float* __restrict__ pooled)
{
  const int b = blockIdx.y;
  const int w = blockIdx.x * 256 + threadIdx.x;
  float m = -3.0e38f;
#pragma unroll
  for (int c = 0; c < 8; ++c) m = fmaxf(m, part[((long)b * 8 + c) * 512 + w]);
  pooled[b * 512 + w] = m;
}

// ---------------- masked transpose to output h [B,512,T] fp32 ----------------
__global__ __launch_bounds__(256)
void tout_k(const float* __restrict__ hm, const float* __restrict__ mask, float* __restrict__ outh)
{
  __shared__ float tile[64][65];
  const int t0 = blockIdx.x * 64, w0 = blockIdx.y * 64, b = blockIdx.z;
  const int tx = threadIdx.x & 63, ty = threadIdx.x >> 6;
  for (int i = ty; i < 64; i += 4)
    tile[i][tx] = hm[((long)b * 1024 + t0 + i) * 512 + w0 + tx];
  __syncthreads();
  const float mv = mask[b * 1024 + t0 + tx];
  for (int i = ty; i < 64; i += 4)
    outh[((long)b * 512 + w0 + i) * 1024 + t0 + tx] = tile[tx][i] * mv;
}

// ---------------- aggregator matmuls: split-K partials + combine ----------------
__global__ __launch_bounds__(256)
void agg1p_k(const float* __restrict__ pooled, const float* __restrict__ wf,
             float* __restrict__ part)
{
  const int b = blockIdx.z, kc = blockIdx.y;
  const int n = blockIdx.x * 256 + threadIdx.x;
  float acc = 0.f;
  const int k0 = kc * 64;
#pragma unroll 8
  for (int k = 0; k < 64; ++k) acc += pooled[b * 512 + k0 + k] * wf[(long)(k0 + k) * 2048 + n];
  part[((long)b * 8 + kc) * 2048 + n] = acc;
}
__global__ __launch_bounds__(256)
void agg1c_k(const float* __restrict__ part, const float* __restrict__ bf_,
             float* __restrict__ z1)
{
  const int b = blockIdx.y;
  const int n = blockIdx.x * 256 + threadIdx.x;
  float acc = 0.f;
#pragma unroll
  for (int c = 0; c < 8; ++c) acc += part[((long)b * 8 + c) * 2048 + n];
  z1[(long)b * 2048 + n] = gelu_f(acc + bf_[n]);
}
__global__ __launch_bounds__(256)
void agg2p_k(const float* __restrict__ z1, const float* __restrict__ wp,
             float* __restrict__ part)
{
  const int b = blockIdx.z, kc = blockIdx.y;
  const int n = blockIdx.x * 256 + threadIdx.x;
  float acc = 0.f;
  const int k0 = kc * 256;
#pragma unroll 8
  for (int k = 0; k < 256; ++k) acc += z1[(long)b * 2048 + k0 + k] * wp[(long)(k0 + k) * 512 + n];
  part[((long)b * 8 + kc) * 512 + n] = acc;
}
__global__ __launch_bounds__(256)
void agg2c_k(const float* __restrict__ part, const float* __restrict__ bp,
             float* __restrict__ zo)
{
  const int b = blockIdx.y;
  const int n = blockIdx.x * 256 + threadIdx.x;
  float acc = 0.f;
#pragma unroll
  for (int c = 0; c < 8; ++c) acc += part[((long)b * 8 + c) * 512 + n];
  zo[b * 512 + n] = acc + bp[n];
}

extern "C" void kernel_launch(void* const* d_in, const int* in_sizes, int n_in,
                              void* d_out, int out_size, void* d_ws, size_t ws_size,
                              hipStream_t stream)
{
  (void)in_sizes; (void)n_in; (void)out_size; (void)ws_size;
  const float* x        = (const float*)d_in[0];
  const float* params   = (const float*)d_in[1];
  const float* mask     = (const float*)d_in[2];
  const float* class_emb= (const float*)d_in[3];
  const float* w_in     = (const float*)d_in[4];
  const float* b_in     = (const float*)d_in[5];
  const float* ln_pre_g = (const float*)d_in[6];
  const float* ln_pre_b = (const float*)d_in[7];
  const float* qkv_w    = (const float*)d_in[8];
  const float* qkv_b    = (const float*)d_in[9];
  const float* attn_pw  = (const float*)d_in[10];
  const float* attn_pb  = (const float*)d_in[11];
  const float* ln1_g    = (const float*)d_in[12];
  const float* ln1_b    = (const float*)d_in[13];
  const float* fc_w     = (const float*)d_in[14];
  const float* fc_b     = (const float*)d_in[15];
  const float* fcp_w    = (const float*)d_in[16];
  const float* fcp_b    = (const float*)d_in[17];
  const float* ln2_g    = (const float*)d_in[18];
  const float* ln2_b    = (const float*)d_in[19];
  const float* ln_post_g= (const float*)d_in[20];
  const float* ln_post_b= (const float*)d_in[21];
  const float* w_out    = (const float*)d_in[22];
  const float* b_out    = (const float*)d_in[23];
  const float* agg_fc_w = (const float*)d_in[24];
  const float* agg_fc_b = (const float*)d_in[25];
  const float* agg_pw   = (const float*)d_in[26];
  const float* agg_pb   = (const float*)d_in[27];

  float* out_f = (float*)d_out;          // z: [0, 16384)
  float* out_h = out_f + 16384;          // h: 64 MiB fp32 region
  u16* sc = (u16*)out_h;                 // bf16 scratch: up to 16384x2048 (64 MiB)

  // ---- workspace layout (~128 MiB) ----
  char* ws = (char*)d_ws;
  float* hf = (float*)ws;       ws += (size_t)32768 * 512 * 4;
  u16* hn = (u16*)ws;           ws += (size_t)32768 * 512 * 2;
  float* E = (float*)ws;        ws += (size_t)1024 * 512 * 4;
  u16* ce_b = (u16*)ws;         ws += (size_t)1024 * 1024 * 2;
  u16* wt_qkv = (u16*)ws;       ws += (size_t)1536 * 512 * 2;
  u16* wt_pw  = (u16*)ws;       ws += (size_t)512 * 512 * 2;
  u16* wt_fc  = (u16*)ws;       ws += (size_t)2048 * 512 * 2;
  u16* wt_fcp = (u16*)ws;       ws += (size_t)512 * 2048 * 2;
  u16* w_in_t = (u16*)ws;       ws += (size_t)512 * 1024 * 2;
  u16* w_out_t= (u16*)ws;       ws += (size_t)512 * 512 * 2;
  float* pooled = (float*)ws;   ws += (size_t)32 * 512 * 4;
  float* z1     = (float*)ws;   ws += (size_t)32 * 2048 * 4;
  float* part   = (float*)ws;   ws += (size_t)32 * 8 * 512 * 4;
  float* apart1 = (float*)ws;   ws += (size_t)32 * 8 * 2048 * 4;
  float* apart2 = (float*)ws;   ws += (size_t)32 * 8 * 512 * 4;
  u16* vt       = (u16*)ws;     ws += (size_t)16 * 8 * 64 * 1024 * 2;

  // one-time converts + class-emb projection + embed + ln_pre
  cast_k<<<1024, 256, 0, stream>>>(class_emb, ce_b, 1024 * 1024);
  tr_k<<<dim3(16, 32), 256, 0, stream>>>(w_in + 9 * 512, w_in_t, 1024, 512);
  tr_k<<<dim3(16, 16), 256, 0, stream>>>(w_out, w_out_t, 512, 512);
  gemm_bt<0><<<dim3(4, 4), 512, 0, stream>>>(ce_b, w_in_t, nullptr, E, nullptr, nullptr,
                                             1024, 1024, 1024, 512);
  embed_k<<<32768, 256, 0, stream>>>(x, params, E, w_in, b_in, hf);
  ln_k<0><<<8192, 256, 0, stream>>>(hf, ln_pre_g, ln_pre_b, hf);

  for (int l = 0; l < 12; ++l) {
    trL_k<<<3072, 256, 0, stream>>>(qkv_w + (size_t)l * 512 * 1536,
                                    attn_pw + (size_t)l * 512 * 512,
                                    fc_w + (size_t)l * 512 * 2048,
                                    fcp_w + (size_t)l * 2048 * 512,
                                    wt_qkv, wt_pw, wt_fc, wt_fcp);

    // LN1 full batch -> hn (bf16)
    ln_k<1><<<8192, 256, 0, stream>>>(hf, ln1_g + l * 512, ln1_b + l * 512, hn);
    // QKV (V written transposed to vt) + attention per batch-half; attn-out overwrites hn half
    for (int half = 0; half < 2; ++half) {
      const size_t ro = (size_t)half * 16384;
      gemm_bt<4><<<dim3(12, 64), 512, 0, stream>>>(hn + ro * 512, wt_qkv, qkv_b + l * 1536,
                                                   nullptr, sc, vt, 512, 512, 512, 1536);
      attn_k<<<1024, 512, 0, stream>>>(sc, vt, hn + ro * 512);
    }
    // attn projection full batch: h += hn @ pw^T + b
    gemm_bt<2><<<dim3(4, 128), 512, 0, stream>>>(hn, wt_pw, attn_pb + l * 512,
                                                 hf, nullptr, nullptr, 512, 512, 512, 512);
    // LN2 full batch -> hn
    ln_k<1><<<8192, 256, 0, stream>>>(hf, ln2_g + l * 512, ln2_b + l * 512, hn);
    // FF per batch-half: fc 256x256/16-wave; fcp 128x128/4-wave (512 blocks = 2/CU)
    for (int half = 0; half < 2; ++half) {
      const size_t ro = (size_t)half * 16384;
      gemm_bt2<3><<<dim3(8, 64), 1024, 0, stream>>>(hn + ro * 512, wt_fc, fc_b + l * 2048,
                                                    nullptr, sc, 512, 512, 512, 2048);
      gemm_bt1<2><<<dim3(4, 128), 256, 0, stream>>>(sc, wt_fcp, fcp_b + l * 512,
                                                    hf + ro * 512, nullptr, 2048, 2048, 2048, 512);
    }
  }

  // final LN + out-proj, then pool/agg, then h output
  ln_k<1><<<8192, 256, 0, stream>>>(hf, ln_post_g, ln_post_b, hn);
  gemm_bt<0><<<dim3(4, 128), 512, 0, stream>>>(hn, w_out_t, b_out, hf, nullptr, nullptr,
                                               512, 512, 512, 512);
  pool1_k<<<dim3(8, 32), 256, 0, stream>>>(hf, mask, part);
  pool2_k<<<dim3(2, 32), 256, 0, stream>>>(part, pooled);
  agg1p_k<<<dim3(8, 8, 32), 256, 0, stream>>>(pooled, agg_fc_w, apart1);
  agg1c_k<<<dim3(8, 32), 256, 0, stream>>>(apart1, agg_fc_b, z1);
  agg2p_k<<<dim3(2, 8, 32), 256, 0, stream>>>(z1, agg_pw, apart2);
  agg2c_k<<<dim3(2, 32), 256, 0, stream>>>(apart2, agg_pb, out_f);
  tout_k<<<dim3(16, 8, 32), 256, 0, stream>>>(hf, mask, out_h);
}